// Round 6
// baseline (548.993 us; speedup 1.0000x reference)
//
#include <hip/hip_runtime.h>

#define NN 20000
#define EE 320000
#define EF 340000   /* EE + NN self loops */
#define EDIM 22

typedef short bf16x8 __attribute__((ext_vector_type(8)));
typedef float f32x4 __attribute__((ext_vector_type(4)));

__device__ __forceinline__ float b2f(ushort u) {
  union { unsigned u; float f; } v;
  v.u = ((unsigned)u) << 16;
  return v.f;
}
__device__ __forceinline__ float blo(unsigned u) {
  union { unsigned x; float f; } v; v.x = u << 16; return v.f;
}
__device__ __forceinline__ float bhi(unsigned u) {
  union { unsigned x; float f; } v; v.x = u & 0xffff0000u; return v.f;
}
__device__ __forceinline__ ushort f2b(float f) {
  union { float f; unsigned u; } v;
  v.f = f;
  unsigned u = v.u;
  return (ushort)((u + 0x7fffu + ((u >> 16) & 1u)) >> 16);  // RNE
}
__device__ __forceinline__ float lrelu(float a) { return a > 0.f ? a : 0.2f * a; }

// ---------------------------------------------------------------------------
// Graph setup: CSR by dst (counting sort), mean edge_attr for self loops
// ---------------------------------------------------------------------------

__global__ void count_deg_kernel(const int* __restrict__ dst, int* __restrict__ cnt) {
  int e = blockIdx.x * blockDim.x + threadIdx.x;
  if (e < EE) atomicAdd(&cnt[dst[e]], 1);
}

__global__ void scan_kernel(const int* __restrict__ cnt, int* __restrict__ off,
                            int* __restrict__ cursor) {
  __shared__ int wsum[16];
  __shared__ int carry_s;
  const int tid = threadIdx.x, lane = tid & 63, w = tid >> 6;
  if (tid == 0) carry_s = 0;
  __syncthreads();
  for (int base = 0; base < NN; base += 1024) {
    int i = base + tid;
    int v = (i < NN) ? (cnt[i] + 1) : 0;
    int x = v;
#pragma unroll
    for (int s = 1; s < 64; s <<= 1) {
      int t = __shfl_up(x, s);
      if (lane >= s) x += t;
    }
    if (lane == 63) wsum[w] = x;
    __syncthreads();
    if (w == 0) {
      int ws = (lane < 16) ? wsum[lane] : 0;
#pragma unroll
      for (int s = 1; s < 16; s <<= 1) {
        int t = __shfl_up(ws, s);
        if (lane >= s) ws += t;
      }
      if (lane < 16) wsum[lane] = ws;
    }
    __syncthreads();
    int wbase = (w == 0) ? 0 : wsum[w - 1];
    int total = wsum[15];
    int excl = carry_s + wbase + x - v;
    if (i < NN) { off[i] = excl; cursor[i] = excl; }
    __syncthreads();
    if (tid == 0) carry_s += total;
    __syncthreads();
  }
  if (threadIdx.x == 0) off[NN] = carry_s;
}

__global__ void scatter_kernel(const int* __restrict__ src, const int* __restrict__ dst,
                               int* __restrict__ cursor, int* __restrict__ csr_src,
                               int* __restrict__ csr_dst, int* __restrict__ csr_eid) {
  int e = blockIdx.x * blockDim.x + threadIdx.x;
  if (e >= EF) return;
  int s, d;
  if (e < EE) { s = src[e]; d = dst[e]; } else { s = e - EE; d = s; }
  int pos = atomicAdd(&cursor[d], 1);
  csr_src[pos] = s;
  csr_dst[pos] = d;
  csr_eid[pos] = e;
}

__global__ void mean_ea_kernel(const int* __restrict__ off, const int* __restrict__ csr_eid,
                               const int* __restrict__ cnt, const float* __restrict__ edge_attr,
                               float* __restrict__ mean_ea) {
  int t = blockIdx.x * blockDim.x + threadIdx.x;
  if (t >= NN * EDIM) return;
  int n = t / EDIM, d = t % EDIM;
  int s = off[n], e = off[n + 1];
  float sum = 0.f;
  for (int j = s; j < e; ++j) {
    int eid = csr_eid[j];
    if (eid < EE) sum += edge_attr[(size_t)eid * EDIM + d];
  }
  mean_ea[t] = sum / fmaxf((float)cnt[n], 1.f);
}

// ---------------------------------------------------------------------------
// dtype conversions
// ---------------------------------------------------------------------------

__global__ void cvt_x_kernel(const float* __restrict__ x, ushort* __restrict__ ab) {
  int t = blockIdx.x * blockDim.x + threadIdx.x;
  if (t >= NN * 32) return;
  int n = t >> 5, c = t & 31;
  ab[t] = (c < 16) ? f2b(x[n * 16 + c]) : (ushort)0;
}

__global__ void cvt_w_kernel(const float* __restrict__ W, ushort* __restrict__ Wt,
                             int K, int Kp, int HC) {
  int t = blockIdx.x * blockDim.x + threadIdx.x;
  if (t >= HC * Kp) return;
  int nc = t / Kp, k = t % Kp;
  Wt[t] = (k < K) ? f2b(W[(size_t)k * HC + nc]) : (ushort)0;
}

// ---------------------------------------------------------------------------
// bf16 MFMA GEMM: wave = 16 rows x NFRAG*16 cols. B (weights) L1/L2-resident.
// ---------------------------------------------------------------------------
template <int NFRAG>
__global__ __launch_bounds__(256) void mfma_gemm_kernel(
    const ushort* __restrict__ A, const ushort* __restrict__ Bt,
    ushort* __restrict__ C, int M, int K, int Nc) {
  const int lane = threadIdx.x & 63;
  const int wid = threadIdx.x >> 6;
  const int bm = blockIdx.y * 64 + wid * 16;
  const int bn = blockIdx.x * (NFRAG * 16);
  const int r = lane & 15;
  const int kg = lane >> 4;

  f32x4 acc[NFRAG] = {};
  const int arow = bm + r;
  const bool aval = arow < M;
  const ushort* aptr = A + (size_t)arow * K + kg * 8;
  const ushort* bptr = Bt + (size_t)(bn + r) * K + kg * 8;

  for (int k0 = 0; k0 < K; k0 += 32) {
    bf16x8 af = {};
    if (aval) af = *(const bf16x8*)(aptr + k0);
#pragma unroll
    for (int nf = 0; nf < NFRAG; ++nf) {
      bf16x8 bfr = *(const bf16x8*)(bptr + (size_t)nf * 16 * K + k0);
      acc[nf] = __builtin_amdgcn_mfma_f32_16x16x32_bf16(af, bfr, acc[nf], 0, 0, 0);
    }
  }
#pragma unroll
  for (int nf = 0; nf < NFRAG; ++nf) {
#pragma unroll
    for (int reg = 0; reg < 4; ++reg) {
      int row = bm + kg * 4 + reg;
      if (row < M) C[(size_t)row * Nc + bn + nf * 16 + r] = f2b(acc[nf][reg]);
    }
  }
}

// ---------------------------------------------------------------------------
// a_s / a_d from bf16 h
// ---------------------------------------------------------------------------
__global__ void asd_kernel(const ushort* __restrict__ h, const float* __restrict__ atts,
                           const float* __restrict__ attd, float* __restrict__ a_s,
                           float* __restrict__ a_d, int H, int C) {
  int t = blockIdx.x * blockDim.x + threadIdx.x;
  if (t >= NN * H) return;
  int n = t / H, hh = t % H;
  const ushort* row = h + (size_t)n * H * C + (size_t)hh * C;
  float s = 0.f, d = 0.f;
  for (int c = 0; c < C; c += 2) {
    unsigned u = *(const unsigned*)(row + c);
    float v0 = blo(u), v1 = bhi(u);
    s += v0 * atts[hh * C + c] + v1 * atts[hh * C + c + 1];
    d += v0 * attd[hh * C + c] + v1 * attd[hh * C + c + 1];
  }
  a_s[t] = s;
  a_d[t] = d;
}

__global__ void wecomb_kernel(const float* __restrict__ We, const float* __restrict__ atte,
                              float* __restrict__ wec, int H, int C) {
  int t = blockIdx.x * blockDim.x + threadIdx.x;
  if (t >= EDIM * H) return;
  int d = t / H, hh = t % H;
  float v = 0.f;
  for (int c = 0; c < C; ++c) v += We[(size_t)d * H * C + hh * C + c] * atte[hh * C + c];
  wec[t] = v;
}

// alpha[j,h] = leaky_relu(a_e(j) + a_s[src(j)] + a_d[dst(j)]), CSR order
__global__ void ase_kernel(const int* __restrict__ csr_eid, const int* __restrict__ csr_src,
                           const int* __restrict__ csr_dst,
                           const float* __restrict__ edge_attr, const float* __restrict__ mean_ea,
                           const float* __restrict__ wec, const float* __restrict__ a_s,
                           const float* __restrict__ a_d, float* __restrict__ alpha, int H) {
  int t = blockIdx.x * blockDim.x + threadIdx.x;
  if (t >= EF * H) return;
  int j = t / H, hh = t % H;
  int eid = csr_eid[j];
  const float* ea = (eid < EE) ? &edge_attr[(size_t)eid * EDIM]
                               : &mean_ea[(size_t)(eid - EE) * EDIM];
  float v = 0.f;
#pragma unroll
  for (int d = 0; d < EDIM; ++d) v += ea[d] * wec[d * H + hh];
  v += a_s[csr_src[j] * H + hh] + a_d[csr_dst[j] * H + hh];
  alpha[t] = lrelu(v);
}

// ---------------------------------------------------------------------------
// Fused aggregation, whole-row waves. Wave = one node, lane owns FPL features.
// Edges tiled by 64; per tile each lane computes ONE edge's H softmax weights
// (exp deduped 16x) into LDS; gather loop reads weights via 2 ds_read/edge.
// ---------------------------------------------------------------------------
template <int H, int C>
__global__ __launch_bounds__(256) void aggregate_kernel(
    const float* __restrict__ alpha, const ushort* __restrict__ hb,
    const int* __restrict__ off, const int* __restrict__ csr_src,
    const float* __restrict__ bias, ushort* __restrict__ xb) {
  constexpr int HC = H * C;
  constexpr int FPL = HC / 64;   // 4 (HC=256) or 12 (HC=768)
  constexpr int NV = FPL / 4;
  __shared__ float wlds_all[4][64 * H];
  const int wv = threadIdx.x >> 6;
  const int lane = threadIdx.x & 63;
  const int n = blockIdx.x * 4 + wv;
  if (n >= NN) return;
  float* wl = wlds_all[wv];
  const int start = off[n], end = off[n + 1];

  // ---- pass 1a: segment max over alpha (lane-parallel) ----
  float mx[H];
#pragma unroll
  for (int h = 0; h < H; ++h) mx[h] = -1e30f;
  for (int j = start + lane; j < end; j += 64) {
    const float4* ap = (const float4*)(alpha + (size_t)j * H);
#pragma unroll
    for (int v = 0; v < H / 4; ++v) {
      float4 a4 = ap[v];
      mx[v * 4 + 0] = fmaxf(mx[v * 4 + 0], a4.x);
      mx[v * 4 + 1] = fmaxf(mx[v * 4 + 1], a4.y);
      mx[v * 4 + 2] = fmaxf(mx[v * 4 + 2], a4.z);
      mx[v * 4 + 3] = fmaxf(mx[v * 4 + 3], a4.w);
    }
  }
#pragma unroll
  for (int s = 32; s > 0; s >>= 1)
#pragma unroll
    for (int h = 0; h < H; ++h) mx[h] = fmaxf(mx[h], __shfl_xor(mx[h], s));

  // ---- pass 1b: denominator ----
  float sm[H];
#pragma unroll
  for (int h = 0; h < H; ++h) sm[h] = 0.f;
  for (int j = start + lane; j < end; j += 64) {
    const float4* ap = (const float4*)(alpha + (size_t)j * H);
#pragma unroll
    for (int v = 0; v < H / 4; ++v) {
      float4 a4 = ap[v];
      sm[v * 4 + 0] += __expf(a4.x - mx[v * 4 + 0]);
      sm[v * 4 + 1] += __expf(a4.y - mx[v * 4 + 1]);
      sm[v * 4 + 2] += __expf(a4.z - mx[v * 4 + 2]);
      sm[v * 4 + 3] += __expf(a4.w - mx[v * 4 + 3]);
    }
  }
#pragma unroll
  for (int s = 32; s > 0; s >>= 1)
#pragma unroll
    for (int h = 0; h < H; ++h) sm[h] += __shfl_xor(sm[h], s);
  float rd[H];
#pragma unroll
  for (int h = 0; h < H; ++h) rd[h] = 1.f / sm[h];

  // ---- lane feature slice ----
  const int f0 = lane * FPL;
  const int hA = f0 / C;
  const int hB = (f0 + FPL - 1) / C;
  const int split = (hA + 1) * C - f0;  // #features using head hA (multiple of 4)
  const ushort* hrow = hb + f0;
  float acc[FPL] = {};

  // ---- pass 2: tiled weighted gather ----
  for (int t0 = start; t0 < end; t0 += 64) {
    const int m = min(64, end - t0);
    if (lane < m) {
      const float* ap = alpha + (size_t)(t0 + lane) * H;
#pragma unroll
      for (int v = 0; v < H / 4; ++v) {
        float4 a4 = *(const float4*)(ap + v * 4);
        float4 w4;
        w4.x = __expf(a4.x - mx[v * 4 + 0]) * rd[v * 4 + 0];
        w4.y = __expf(a4.y - mx[v * 4 + 1]) * rd[v * 4 + 1];
        w4.z = __expf(a4.z - mx[v * 4 + 2]) * rd[v * 4 + 2];
        w4.w = __expf(a4.w - mx[v * 4 + 3]) * rd[v * 4 + 3];
        *(float4*)(wl + lane * H + v * 4) = w4;
      }
    }
#pragma unroll 2
    for (int e = 0; e < m; ++e) {
      const int j = t0 + e;
      const int s0 = csr_src[j];
      const float wA = wl[e * H + hA];
      const float wB = wl[e * H + hB];
      const ushort* hp = hrow + (size_t)s0 * HC;
#pragma unroll
      for (int v = 0; v < NV; ++v) {
        const float wg = (v * 4 < split) ? wA : wB;
        uint2 u = *(const uint2*)(hp + v * 4);
        acc[v * 4 + 0] += wg * blo(u.x);
        acc[v * 4 + 1] += wg * bhi(u.x);
        acc[v * 4 + 2] += wg * blo(u.y);
        acc[v * 4 + 3] += wg * bhi(u.y);
      }
    }
  }

  // ---- bias + relu + bf16 store ----
  ushort o[FPL];
#pragma unroll
  for (int i = 0; i < FPL; ++i) o[i] = f2b(fmaxf(acc[i] + bias[f0 + i], 0.f));
#pragma unroll
  for (int v = 0; v < NV; ++v) {
    uint2 pk;
    pk.x = (unsigned)o[v * 4 + 0] | ((unsigned)o[v * 4 + 1] << 16);
    pk.y = (unsigned)o[v * 4 + 2] | ((unsigned)o[v * 4 + 3] << 16);
    *(uint2*)(xb + (size_t)n * HC + f0 + v * 4) = pk;
  }
}

// ---------------------------------------------------------------------------
// Final head: sigmoid(concat(x1,x2,x3) @ Wf + bf), bf16 inputs. 1 wave/node.
// ---------------------------------------------------------------------------
__global__ void final_kernel(const ushort* __restrict__ x1b, const ushort* __restrict__ x2b,
                             const ushort* __restrict__ x3b, const float* __restrict__ Wf,
                             const float* __restrict__ bf, float* __restrict__ out) {
  const int wave = (int)((blockIdx.x * blockDim.x + threadIdx.x) >> 6);
  const int lane = threadIdx.x & 63;
  if (wave >= NN) return;
  float acc = 0.f;
#pragma unroll
  for (int q = 0; q < 5; ++q) {
    int f0 = (q * 64 + lane) * 4;
    const ushort* sp;
    if (f0 < 256)      sp = x1b + (size_t)wave * 256 + f0;
    else if (f0 < 512) sp = x2b + (size_t)wave * 256 + (f0 - 256);
    else               sp = x3b + (size_t)wave * 768 + (f0 - 512);
    uint2 u = *(const uint2*)sp;
    float4 wv = *(const float4*)(Wf + f0);
    acc += blo(u.x) * wv.x + bhi(u.x) * wv.y + blo(u.y) * wv.z + bhi(u.y) * wv.w;
  }
#pragma unroll
  for (int s = 32; s > 0; s >>= 1) acc += __shfl_xor(acc, s);
  if (lane == 0) out[wave] = 1.f / (1.f + __expf(-(acc + bf[0])));
}

// ---------------------------------------------------------------------------

extern "C" void kernel_launch(void* const* d_in, const int* in_sizes, int n_in,
                              void* d_out, int out_size, void* d_ws, size_t ws_size,
                              hipStream_t stream) {
  const float* x     = (const float*)d_in[0];
  const int*   eidx  = (const int*)d_in[1];
  const float* eattr = (const float*)d_in[2];
  const float* W[3]   = {(const float*)d_in[3],  (const float*)d_in[9],  (const float*)d_in[15]};
  const float* ats[3] = {(const float*)d_in[4],  (const float*)d_in[10], (const float*)d_in[16]};
  const float* atd[3] = {(const float*)d_in[5],  (const float*)d_in[11], (const float*)d_in[17]};
  const float* We[3]  = {(const float*)d_in[6],  (const float*)d_in[12], (const float*)d_in[18]};
  const float* ate[3] = {(const float*)d_in[7],  (const float*)d_in[13], (const float*)d_in[19]};
  const float* bb[3]  = {(const float*)d_in[8],  (const float*)d_in[14], (const float*)d_in[20]};
  const float* Wf = (const float*)d_in[21];
  const float* bf = (const float*)d_in[22];
  float* out = (float*)d_out;

  const int* src = eidx;
  const int* dst = eidx + EE;

  char* p = (char*)d_ws;
  auto carve = [&](size_t bytes) -> char* {
    char* q = p;
    p += (bytes + 255) & ~(size_t)255;
    return q;
  };
  ushort* x1b   = (ushort*)carve((size_t)NN * 256 * 2);
  ushort* x2b   = (ushort*)carve((size_t)NN * 256 * 2);
  ushort* x3b   = (ushort*)carve((size_t)NN * 768 * 2);
  ushort* hbuf  = (ushort*)carve((size_t)NN * 768 * 2);
  ushort* abf1  = (ushort*)carve((size_t)NN * 32 * 2);
  ushort* wt1   = (ushort*)carve((size_t)256 * 32 * 2);
  ushort* wt2   = (ushort*)carve((size_t)256 * 256 * 2);
  ushort* wt3   = (ushort*)carve((size_t)768 * 256 * 2);
  float*  a_s   = (float*)carve((size_t)NN * 12 * 4);
  float*  a_d   = (float*)carve((size_t)NN * 12 * 4);
  float*  alpha = (float*)carve((size_t)EF * 12 * 4);
  float*  mea   = (float*)carve((size_t)NN * EDIM * 4);
  float*  wec   = (float*)carve((size_t)EDIM * 12 * 4);
  int* cnt      = (int*)carve((size_t)NN * 4);
  int* off      = (int*)carve((size_t)(NN + 1) * 4);
  int* cursor   = (int*)carve((size_t)NN * 4);
  int* csr_src  = (int*)carve((size_t)EF * 4);
  int* csr_dst  = (int*)carve((size_t)EF * 4);
  int* csr_eid  = (int*)carve((size_t)EF * 4);

  // ---- graph structure ----
  hipMemsetAsync(cnt, 0, (size_t)NN * 4, stream);
  count_deg_kernel<<<(EE + 255) / 256, 256, 0, stream>>>(dst, cnt);
  scan_kernel<<<1, 1024, 0, stream>>>(cnt, off, cursor);
  scatter_kernel<<<(EF + 255) / 256, 256, 0, stream>>>(src, dst, cursor, csr_src, csr_dst,
                                                       csr_eid);
  mean_ea_kernel<<<(NN * EDIM + 255) / 256, 256, 0, stream>>>(off, csr_eid, cnt, eattr, mea);

  // ---- dtype prep ----
  cvt_x_kernel<<<(NN * 32 + 255) / 256, 256, 0, stream>>>(x, abf1);
  cvt_w_kernel<<<(256 * 32 + 255) / 256, 256, 0, stream>>>(W[0], wt1, 16, 32, 256);
  cvt_w_kernel<<<(256 * 256 + 255) / 256, 256, 0, stream>>>(W[1], wt2, 256, 256, 256);
  cvt_w_kernel<<<(768 * 256 + 255) / 256, 256, 0, stream>>>(W[2], wt3, 256, 256, 768);

  const int Hs[3] = {8, 8, 12};
  const int Cs[3] = {32, 32, 64};
  const int Kp[3] = {32, 256, 256};
  const ushort* Ain[3] = {abf1, x1b, x2b};
  const ushort* Wt[3] = {wt1, wt2, wt3};
  ushort* xoutb[3] = {x1b, x2b, x3b};

  for (int L = 0; L < 3; ++L) {
    const int H = Hs[L], C = Cs[L], HC = H * C;
    // h = A @ Wt^T (bf16 MFMA). L3: NFRAG=12 -> A re-read 4x instead of 12x.
    if (L < 2) {
      dim3 g(HC / 64, (NN + 63) / 64);
      mfma_gemm_kernel<4><<<g, 256, 0, stream>>>(Ain[L], Wt[L], hbuf, NN, Kp[L], HC);
    } else {
      dim3 g(HC / 192, (NN + 63) / 64);
      mfma_gemm_kernel<12><<<g, 256, 0, stream>>>(Ain[L], Wt[L], hbuf, NN, Kp[L], HC);
    }
    // attention scalars -> fused alpha (leaky included)
    asd_kernel<<<(NN * H + 255) / 256, 256, 0, stream>>>(hbuf, ats[L], atd[L], a_s, a_d, H, C);
    wecomb_kernel<<<(EDIM * H + 255) / 256, 256, 0, stream>>>(We[L], ate[L], wec, H, C);
    ase_kernel<<<(EF * H + 255) / 256, 256, 0, stream>>>(csr_eid, csr_src, csr_dst, eattr,
                                                         mea, wec, a_s, a_d, alpha, H);
    // fused softmax + whole-row gather (LDS-staged weights)
    int blocks = (NN + 3) / 4;
    if (H == 8)
      aggregate_kernel<8, 32><<<blocks, 256, 0, stream>>>(alpha, hbuf, off, csr_src,
                                                          bb[L], xoutb[L]);
    else
      aggregate_kernel<12, 64><<<blocks, 256, 0, stream>>>(alpha, hbuf, off, csr_src,
                                                           bb[L], xoutb[L]);
  }

  final_kernel<<<(NN * 64 + 255) / 256, 256, 0, stream>>>(x1b, x2b, x3b, Wf, bf, out);
}

// Round 7
// 534.640 us; speedup vs baseline: 1.0268x; 1.0268x over previous
//
#include <hip/hip_runtime.h>

#define NN 20000
#define EE 320000
#define EF 340000   /* EE + NN self loops */
#define EDIM 22

typedef short bf16x8 __attribute__((ext_vector_type(8)));
typedef float f32x4 __attribute__((ext_vector_type(4)));

__device__ __forceinline__ float blo(unsigned u) {
  union { unsigned x; float f; } v; v.x = u << 16; return v.f;
}
__device__ __forceinline__ float bhi(unsigned u) {
  union { unsigned x; float f; } v; v.x = u & 0xffff0000u; return v.f;
}
__device__ __forceinline__ ushort f2b(float f) {
  union { float f; unsigned u; } v;
  v.f = f;
  unsigned u = v.u;
  return (ushort)((u + 0x7fffu + ((u >> 16) & 1u)) >> 16);  // RNE
}
__device__ __forceinline__ float lrelu(float a) { return a > 0.f ? a : 0.2f * a; }

// ---------------------------------------------------------------------------
// Graph setup: CSR by dst (counting sort), mean edge_attr for self loops
// ---------------------------------------------------------------------------

__global__ void count_deg_kernel(const int* __restrict__ dst, int* __restrict__ cnt) {
  int e = blockIdx.x * blockDim.x + threadIdx.x;
  if (e < EE) atomicAdd(&cnt[dst[e]], 1);
}

__global__ void scan_kernel(const int* __restrict__ cnt, int* __restrict__ off,
                            int* __restrict__ cursor) {
  __shared__ int wsum[16];
  __shared__ int carry_s;
  const int tid = threadIdx.x, lane = tid & 63, w = tid >> 6;
  if (tid == 0) carry_s = 0;
  __syncthreads();
  for (int base = 0; base < NN; base += 1024) {
    int i = base + tid;
    int v = (i < NN) ? (cnt[i] + 1) : 0;
    int x = v;
#pragma unroll
    for (int s = 1; s < 64; s <<= 1) {
      int t = __shfl_up(x, s);
      if (lane >= s) x += t;
    }
    if (lane == 63) wsum[w] = x;
    __syncthreads();
    if (w == 0) {
      int ws = (lane < 16) ? wsum[lane] : 0;
#pragma unroll
      for (int s = 1; s < 16; s <<= 1) {
        int t = __shfl_up(ws, s);
        if (lane >= s) ws += t;
      }
      if (lane < 16) wsum[lane] = ws;
    }
    __syncthreads();
    int wbase = (w == 0) ? 0 : wsum[w - 1];
    int total = wsum[15];
    int excl = carry_s + wbase + x - v;
    if (i < NN) { off[i] = excl; cursor[i] = excl; }
    __syncthreads();
    if (tid == 0) carry_s += total;
    __syncthreads();
  }
  if (threadIdx.x == 0) off[NN] = carry_s;
}

__global__ void scatter_kernel(const int* __restrict__ src, const int* __restrict__ dst,
                               int* __restrict__ cursor, int* __restrict__ csr_src,
                               int* __restrict__ csr_dst, int* __restrict__ csr_eid) {
  int e = blockIdx.x * blockDim.x + threadIdx.x;
  if (e >= EF) return;
  int s, d;
  if (e < EE) { s = src[e]; d = dst[e]; } else { s = e - EE; d = s; }
  int pos = atomicAdd(&cursor[d], 1);
  csr_src[pos] = s;
  csr_dst[pos] = d;
  csr_eid[pos] = e;
}

__global__ void mean_ea_kernel(const int* __restrict__ off, const int* __restrict__ csr_eid,
                               const int* __restrict__ cnt, const float* __restrict__ edge_attr,
                               float* __restrict__ mean_ea) {
  int t = blockIdx.x * blockDim.x + threadIdx.x;
  if (t >= NN * EDIM) return;
  int n = t / EDIM, d = t % EDIM;
  int s = off[n], e = off[n + 1];
  float sum = 0.f;
  for (int j = s; j < e; ++j) {
    int eid = csr_eid[j];
    if (eid < EE) sum += edge_attr[(size_t)eid * EDIM + d];
  }
  mean_ea[t] = sum / fmaxf((float)cnt[n], 1.f);
}

// ---------------------------------------------------------------------------
// dtype conversions
// ---------------------------------------------------------------------------

__global__ void cvt_x_kernel(const float* __restrict__ x, ushort* __restrict__ ab) {
  int t = blockIdx.x * blockDim.x + threadIdx.x;
  if (t >= NN * 32) return;
  int n = t >> 5, c = t & 31;
  ab[t] = (c < 16) ? f2b(x[n * 16 + c]) : (ushort)0;
}

__global__ void cvt_w_kernel(const float* __restrict__ W, ushort* __restrict__ Wt,
                             int K, int Kp, int HC) {
  int t = blockIdx.x * blockDim.x + threadIdx.x;
  if (t >= HC * Kp) return;
  int nc = t / Kp, k = t % Kp;
  Wt[t] = (k < K) ? f2b(W[(size_t)k * HC + nc]) : (ushort)0;
}

// ---------------------------------------------------------------------------
// bf16 MFMA GEMM (round-2/5 proven shape): wave = 16 rows x 64 cols, NFRAG=4.
// ---------------------------------------------------------------------------
__global__ __launch_bounds__(256) void mfma_gemm_kernel(
    const ushort* __restrict__ A, const ushort* __restrict__ Bt,
    ushort* __restrict__ C, int M, int K, int Nc) {
  const int lane = threadIdx.x & 63;
  const int wid = threadIdx.x >> 6;
  const int bm = blockIdx.y * 64 + wid * 16;
  const int bn = blockIdx.x * 64;
  const int r = lane & 15;
  const int kg = lane >> 4;

  f32x4 acc[4] = {};
  const int arow = bm + r;
  const bool aval = arow < M;
  const ushort* aptr = A + (size_t)arow * K + kg * 8;
  const ushort* bptr = Bt + (size_t)(bn + r) * K + kg * 8;

  for (int k0 = 0; k0 < K; k0 += 32) {
    bf16x8 af = {};
    if (aval) af = *(const bf16x8*)(aptr + k0);
#pragma unroll
    for (int nf = 0; nf < 4; ++nf) {
      bf16x8 bfr = *(const bf16x8*)(bptr + (size_t)nf * 16 * K + k0);
      acc[nf] = __builtin_amdgcn_mfma_f32_16x16x32_bf16(af, bfr, acc[nf], 0, 0, 0);
    }
  }
#pragma unroll
  for (int nf = 0; nf < 4; ++nf) {
#pragma unroll
    for (int reg = 0; reg < 4; ++reg) {
      int row = bm + kg * 4 + reg;
      if (row < M) C[(size_t)row * Nc + bn + nf * 16 + r] = f2b(acc[nf][reg]);
    }
  }
}

// ---------------------------------------------------------------------------
// a_s / a_d from bf16 h
// ---------------------------------------------------------------------------
__global__ void asd_kernel(const ushort* __restrict__ h, const float* __restrict__ atts,
                           const float* __restrict__ attd, float* __restrict__ a_s,
                           float* __restrict__ a_d, int H, int C) {
  int t = blockIdx.x * blockDim.x + threadIdx.x;
  if (t >= NN * H) return;
  int n = t / H, hh = t % H;
  const ushort* row = h + (size_t)n * H * C + (size_t)hh * C;
  float s = 0.f, d = 0.f;
  for (int c = 0; c < C; c += 2) {
    unsigned u = *(const unsigned*)(row + c);
    float v0 = blo(u), v1 = bhi(u);
    s += v0 * atts[hh * C + c] + v1 * atts[hh * C + c + 1];
    d += v0 * attd[hh * C + c] + v1 * attd[hh * C + c + 1];
  }
  a_s[t] = s;
  a_d[t] = d;
}

__global__ void wecomb_kernel(const float* __restrict__ We, const float* __restrict__ atte,
                              float* __restrict__ wec, int H, int C) {
  int t = blockIdx.x * blockDim.x + threadIdx.x;
  if (t >= EDIM * H) return;
  int d = t / H, hh = t % H;
  float v = 0.f;
  for (int c = 0; c < C; ++c) v += We[(size_t)d * H * C + hh * C + c] * atte[hh * C + c];
  wec[t] = v;
}

// alpha[j,h] = leaky_relu(a_e(j) + a_s[src(j)] + a_d[dst(j)]), CSR order
__global__ void ase_kernel(const int* __restrict__ csr_eid, const int* __restrict__ csr_src,
                           const int* __restrict__ csr_dst,
                           const float* __restrict__ edge_attr, const float* __restrict__ mean_ea,
                           const float* __restrict__ wec, const float* __restrict__ a_s,
                           const float* __restrict__ a_d, float* __restrict__ alpha, int H) {
  int t = blockIdx.x * blockDim.x + threadIdx.x;
  if (t >= EF * H) return;
  int j = t / H, hh = t % H;
  int eid = csr_eid[j];
  const float* ea = (eid < EE) ? &edge_attr[(size_t)eid * EDIM]
                               : &mean_ea[(size_t)(eid - EE) * EDIM];
  float v = 0.f;
#pragma unroll
  for (int d = 0; d < EDIM; ++d) v += ea[d] * wec[d * H + hh];
  v += a_s[csr_src[j] * H + hh] + a_d[csr_dst[j] * H + hh];
  alpha[t] = lrelu(v);
}

// ---------------------------------------------------------------------------
// Fused aggregation: wave = (node, 256-feature chunk = HPC heads).
// Stats lane-parallel over the chunk's heads; per 64-edge tile lane e writes
// its edge's HPC softmax weights to LDS (exp deduped 16x); gather is depth-4
// pipelined: 4x {csr_src, ds-weight, uint2 h-load} in flight.
// ---------------------------------------------------------------------------
template <int H, int C, int NCH>
__global__ __launch_bounds__(256) void aggregate_kernel(
    const float* __restrict__ alpha, const ushort* __restrict__ hb,
    const int* __restrict__ off, const int* __restrict__ csr_src,
    const float* __restrict__ bias, ushort* __restrict__ xb) {
  constexpr int HC = H * C;
  constexpr int CHUNK = HC / NCH;   // 256
  constexpr int HPC = H / NCH;      // heads per chunk (8 or 4)
  constexpr int FPL = CHUNK / 64;   // 4 features per lane (divides C)
  __shared__ float wlds_all[4][64 * HPC];
  const int t = (int)((blockIdx.x * blockDim.x + threadIdx.x) >> 6);
  const int wv = threadIdx.x >> 6;
  const int lane = threadIdx.x & 63;
  const int n = t / NCH, ch = t - n * NCH;
  if (n >= NN) return;
  float* wl = wlds_all[wv];
  const int start = off[n], end = off[n + 1];
  const int h0 = ch * HPC;

  // ---- pass 1a: segment max (lane-parallel over edges) ----
  float mx[HPC];
#pragma unroll
  for (int qq = 0; qq < HPC; ++qq) mx[qq] = -1e30f;
  for (int j = start + lane; j < end; j += 64) {
    const float* ap = alpha + (size_t)j * H + h0;
#pragma unroll
    for (int v = 0; v < HPC / 4; ++v) {
      float4 a4 = *(const float4*)(ap + v * 4);
      mx[v * 4 + 0] = fmaxf(mx[v * 4 + 0], a4.x);
      mx[v * 4 + 1] = fmaxf(mx[v * 4 + 1], a4.y);
      mx[v * 4 + 2] = fmaxf(mx[v * 4 + 2], a4.z);
      mx[v * 4 + 3] = fmaxf(mx[v * 4 + 3], a4.w);
    }
  }
#pragma unroll
  for (int s = 32; s > 0; s >>= 1)
#pragma unroll
    for (int qq = 0; qq < HPC; ++qq) mx[qq] = fmaxf(mx[qq], __shfl_xor(mx[qq], s));

  // ---- pass 1b: denominator ----
  float sm[HPC];
#pragma unroll
  for (int qq = 0; qq < HPC; ++qq) sm[qq] = 0.f;
  for (int j = start + lane; j < end; j += 64) {
    const float* ap = alpha + (size_t)j * H + h0;
#pragma unroll
    for (int v = 0; v < HPC / 4; ++v) {
      float4 a4 = *(const float4*)(ap + v * 4);
      sm[v * 4 + 0] += __expf(a4.x - mx[v * 4 + 0]);
      sm[v * 4 + 1] += __expf(a4.y - mx[v * 4 + 1]);
      sm[v * 4 + 2] += __expf(a4.z - mx[v * 4 + 2]);
      sm[v * 4 + 3] += __expf(a4.w - mx[v * 4 + 3]);
    }
  }
#pragma unroll
  for (int s = 32; s > 0; s >>= 1)
#pragma unroll
    for (int qq = 0; qq < HPC; ++qq) sm[qq] += __shfl_xor(sm[qq], s);
  float rd[HPC];
#pragma unroll
  for (int qq = 0; qq < HPC; ++qq) rd[qq] = 1.f / sm[qq];

  // ---- lane feature slice (within one head; FPL divides C) ----
  const int q = (lane * FPL) / C;        // head within chunk
  const int f0 = ch * CHUNK + lane * FPL;
  const ushort* hrow = hb + f0;
  float acc[FPL] = {};

  // ---- pass 2: tiled, depth-4 pipelined weighted gather ----
  for (int t0 = start; t0 < end; t0 += 64) {
    const int m = min(64, end - t0);
    if (lane < m) {
      const float* ap = alpha + (size_t)(t0 + lane) * H + h0;
#pragma unroll
      for (int v = 0; v < HPC / 4; ++v) {
        float4 a4 = *(const float4*)(ap + v * 4);
        float4 w4;
        w4.x = __expf(a4.x - mx[v * 4 + 0]) * rd[v * 4 + 0];
        w4.y = __expf(a4.y - mx[v * 4 + 1]) * rd[v * 4 + 1];
        w4.z = __expf(a4.z - mx[v * 4 + 2]) * rd[v * 4 + 2];
        w4.w = __expf(a4.w - mx[v * 4 + 3]) * rd[v * 4 + 3];
        *(float4*)(wl + lane * HPC + v * 4) = w4;
      }
    }
    int e = 0;
    for (; e + 4 <= m; e += 4) {
      const int j = t0 + e;
      int s0 = csr_src[j], s1 = csr_src[j + 1], s2 = csr_src[j + 2], s3 = csr_src[j + 3];
      float w0 = wl[(e + 0) * HPC + q];
      float w1 = wl[(e + 1) * HPC + q];
      float w2 = wl[(e + 2) * HPC + q];
      float w3 = wl[(e + 3) * HPC + q];
      uint2 u0 = *(const uint2*)(hrow + (size_t)s0 * HC);
      uint2 u1 = *(const uint2*)(hrow + (size_t)s1 * HC);
      uint2 u2 = *(const uint2*)(hrow + (size_t)s2 * HC);
      uint2 u3 = *(const uint2*)(hrow + (size_t)s3 * HC);
      acc[0] += w0 * blo(u0.x) + w1 * blo(u1.x) + w2 * blo(u2.x) + w3 * blo(u3.x);
      acc[1] += w0 * bhi(u0.x) + w1 * bhi(u1.x) + w2 * bhi(u2.x) + w3 * bhi(u3.x);
      acc[2] += w0 * blo(u0.y) + w1 * blo(u1.y) + w2 * blo(u2.y) + w3 * blo(u3.y);
      acc[3] += w0 * bhi(u0.y) + w1 * bhi(u1.y) + w2 * bhi(u2.y) + w3 * bhi(u3.y);
    }
    for (; e < m; ++e) {
      const int j = t0 + e;
      int s0 = csr_src[j];
      float w0 = wl[e * HPC + q];
      uint2 u0 = *(const uint2*)(hrow + (size_t)s0 * HC);
      acc[0] += w0 * blo(u0.x);
      acc[1] += w0 * bhi(u0.x);
      acc[2] += w0 * blo(u0.y);
      acc[3] += w0 * bhi(u0.y);
    }
  }

  // ---- bias + relu + bf16 store ----
  ushort o[FPL];
#pragma unroll
  for (int i = 0; i < FPL; ++i) o[i] = f2b(fmaxf(acc[i] + bias[f0 + i], 0.f));
  uint2 pk;
  pk.x = (unsigned)o[0] | ((unsigned)o[1] << 16);
  pk.y = (unsigned)o[2] | ((unsigned)o[3] << 16);
  *(uint2*)(xb + (size_t)n * HC + f0) = pk;
}

// ---------------------------------------------------------------------------
// Final head: sigmoid(concat(x1,x2,x3) @ Wf + bf), bf16 inputs. 1 wave/node.
// ---------------------------------------------------------------------------
__global__ void final_kernel(const ushort* __restrict__ x1b, const ushort* __restrict__ x2b,
                             const ushort* __restrict__ x3b, const float* __restrict__ Wf,
                             const float* __restrict__ bf, float* __restrict__ out) {
  const int wave = (int)((blockIdx.x * blockDim.x + threadIdx.x) >> 6);
  const int lane = threadIdx.x & 63;
  if (wave >= NN) return;
  float acc = 0.f;
#pragma unroll
  for (int q = 0; q < 5; ++q) {
    int f0 = (q * 64 + lane) * 4;
    const ushort* sp;
    if (f0 < 256)      sp = x1b + (size_t)wave * 256 + f0;
    else if (f0 < 512) sp = x2b + (size_t)wave * 256 + (f0 - 256);
    else               sp = x3b + (size_t)wave * 768 + (f0 - 512);
    uint2 u = *(const uint2*)sp;
    float4 wv = *(const float4*)(Wf + f0);
    acc += blo(u.x) * wv.x + bhi(u.x) * wv.y + blo(u.y) * wv.z + bhi(u.y) * wv.w;
  }
#pragma unroll
  for (int s = 32; s > 0; s >>= 1) acc += __shfl_xor(acc, s);
  if (lane == 0) out[wave] = 1.f / (1.f + __expf(-(acc + bf[0])));
}

// ---------------------------------------------------------------------------

extern "C" void kernel_launch(void* const* d_in, const int* in_sizes, int n_in,
                              void* d_out, int out_size, void* d_ws, size_t ws_size,
                              hipStream_t stream) {
  const float* x     = (const float*)d_in[0];
  const int*   eidx  = (const int*)d_in[1];
  const float* eattr = (const float*)d_in[2];
  const float* W[3]   = {(const float*)d_in[3],  (const float*)d_in[9],  (const float*)d_in[15]};
  const float* ats[3] = {(const float*)d_in[4],  (const float*)d_in[10], (const float*)d_in[16]};
  const float* atd[3] = {(const float*)d_in[5],  (const float*)d_in[11], (const float*)d_in[17]};
  const float* We[3]  = {(const float*)d_in[6],  (const float*)d_in[12], (const float*)d_in[18]};
  const float* ate[3] = {(const float*)d_in[7],  (const float*)d_in[13], (const float*)d_in[19]};
  const float* bb[3]  = {(const float*)d_in[8],  (const float*)d_in[14], (const float*)d_in[20]};
  const float* Wf = (const float*)d_in[21];
  const float* bf = (const float*)d_in[22];
  float* out = (float*)d_out;

  const int* src = eidx;
  const int* dst = eidx + EE;

  char* p = (char*)d_ws;
  auto carve = [&](size_t bytes) -> char* {
    char* q = p;
    p += (bytes + 255) & ~(size_t)255;
    return q;
  };
  ushort* x1b   = (ushort*)carve((size_t)NN * 256 * 2);
  ushort* x2b   = (ushort*)carve((size_t)NN * 256 * 2);
  ushort* x3b   = (ushort*)carve((size_t)NN * 768 * 2);
  ushort* hbuf  = (ushort*)carve((size_t)NN * 768 * 2);
  ushort* abf1  = (ushort*)carve((size_t)NN * 32 * 2);
  ushort* wt1   = (ushort*)carve((size_t)256 * 32 * 2);
  ushort* wt2   = (ushort*)carve((size_t)256 * 256 * 2);
  ushort* wt3   = (ushort*)carve((size_t)768 * 256 * 2);
  float*  a_s   = (float*)carve((size_t)NN * 12 * 4);
  float*  a_d   = (float*)carve((size_t)NN * 12 * 4);
  float*  alpha = (float*)carve((size_t)EF * 12 * 4);
  float*  mea   = (float*)carve((size_t)NN * EDIM * 4);
  float*  wec   = (float*)carve((size_t)EDIM * 12 * 4);
  int* cnt      = (int*)carve((size_t)NN * 4);
  int* off      = (int*)carve((size_t)(NN + 1) * 4);
  int* cursor   = (int*)carve((size_t)NN * 4);
  int* csr_src  = (int*)carve((size_t)EF * 4);
  int* csr_dst  = (int*)carve((size_t)EF * 4);
  int* csr_eid  = (int*)carve((size_t)EF * 4);

  // ---- graph structure ----
  hipMemsetAsync(cnt, 0, (size_t)NN * 4, stream);
  count_deg_kernel<<<(EE + 255) / 256, 256, 0, stream>>>(dst, cnt);
  scan_kernel<<<1, 1024, 0, stream>>>(cnt, off, cursor);
  scatter_kernel<<<(EF + 255) / 256, 256, 0, stream>>>(src, dst, cursor, csr_src, csr_dst,
                                                       csr_eid);
  mean_ea_kernel<<<(NN * EDIM + 255) / 256, 256, 0, stream>>>(off, csr_eid, cnt, eattr, mea);

  // ---- dtype prep ----
  cvt_x_kernel<<<(NN * 32 + 255) / 256, 256, 0, stream>>>(x, abf1);
  cvt_w_kernel<<<(256 * 32 + 255) / 256, 256, 0, stream>>>(W[0], wt1, 16, 32, 256);
  cvt_w_kernel<<<(256 * 256 + 255) / 256, 256, 0, stream>>>(W[1], wt2, 256, 256, 256);
  cvt_w_kernel<<<(768 * 256 + 255) / 256, 256, 0, stream>>>(W[2], wt3, 256, 256, 768);

  const int Hs[3] = {8, 8, 12};
  const int Cs[3] = {32, 32, 64};
  const int Kp[3] = {32, 256, 256};
  const ushort* Ain[3] = {abf1, x1b, x2b};
  const ushort* Wt[3] = {wt1, wt2, wt3};
  ushort* xoutb[3] = {x1b, x2b, x3b};

  for (int L = 0; L < 3; ++L) {
    const int H = Hs[L], C = Cs[L], HC = H * C;
    // h = A @ Wt^T (bf16 MFMA), round-5 proven grid
    dim3 g(HC / 64, (NN + 63) / 64);
    mfma_gemm_kernel<<<g, 256, 0, stream>>>(Ain[L], Wt[L], hbuf, NN, Kp[L], HC);
    // attention scalars -> fused alpha (leaky included)
    asd_kernel<<<(NN * H + 255) / 256, 256, 0, stream>>>(hbuf, ats[L], atd[L], a_s, a_d, H, C);
    wecomb_kernel<<<(EDIM * H + 255) / 256, 256, 0, stream>>>(We[L], ate[L], wec, H, C);
    ase_kernel<<<(EF * H + 255) / 256, 256, 0, stream>>>(csr_eid, csr_src, csr_dst, eattr,
                                                         mea, wec, a_s, a_d, alpha, H);
    // fused softmax + chunked depth-4 gather with LDS weight dedup
    if (H == 8) {
      int blocks = (NN * 1 + 3) / 4;  // 1 chunk/node, 4 waves/block
      aggregate_kernel<8, 32, 1><<<blocks, 256, 0, stream>>>(alpha, hbuf, off, csr_src,
                                                             bb[L], xoutb[L]);
    } else {
      int blocks = (NN * 3 + 3) / 4;  // 3 chunks/node
      aggregate_kernel<12, 64, 3><<<blocks, 256, 0, stream>>>(alpha, hbuf, off, csr_src,
                                                              bb[L], xoutb[L]);
    }
  }

  final_kernel<<<(NN * 64 + 255) / 256, 256, 0, stream>>>(x1b, x2b, x3b, Wf, bf, out);
}

// Round 8
// 496.833 us; speedup vs baseline: 1.1050x; 1.0761x over previous
//
#include <hip/hip_runtime.h>

#define NN 20000
#define EE 320000
#define EF 340000   /* EE + NN self loops */
#define EDIM 22
#define NBLK ((NN + 255) / 256)   /* 79 scan blocks */

typedef short bf16x8 __attribute__((ext_vector_type(8)));
typedef float f32x4 __attribute__((ext_vector_type(4)));

__device__ __forceinline__ float blo(unsigned u) {
  union { unsigned x; float f; } v; v.x = u << 16; return v.f;
}
__device__ __forceinline__ float bhi(unsigned u) {
  union { unsigned x; float f; } v; v.x = u & 0xffff0000u; return v.f;
}
__device__ __forceinline__ ushort f2b(float f) {
  union { float f; unsigned u; } v;
  v.f = f;
  unsigned u = v.u;
  return (ushort)((u + 0x7fffu + ((u >> 16) & 1u)) >> 16);  // RNE
}
__device__ __forceinline__ float lrelu(float a) { return a > 0.f ? a : 0.2f * a; }

// ---------------------------------------------------------------------------
// Graph setup: CSR by dst (counting sort), mean edge_attr for self loops
// ---------------------------------------------------------------------------

__global__ void count_deg_kernel(const int* __restrict__ dst, int* __restrict__ cnt) {
  int e = blockIdx.x * blockDim.x + threadIdx.x;
  if (e < EE) atomicAdd(&cnt[dst[e]], 1);
}

// hierarchical scan of (cnt[i]+1): stage 1 — per-256-block exclusive scan
__global__ void scan1_kernel(const int* __restrict__ cnt, int* __restrict__ off,
                             int* __restrict__ btot) {
  __shared__ int wsum[4];
  const int b = blockIdx.x, tid = threadIdx.x;
  const int lane = tid & 63, w = tid >> 6;
  const int i = b * 256 + tid;
  int v = (i < NN) ? (cnt[i] + 1) : 0;
  int x = v;
#pragma unroll
  for (int s = 1; s < 64; s <<= 1) {
    int t = __shfl_up(x, s);
    if (lane >= s) x += t;
  }
  if (lane == 63) wsum[w] = x;
  __syncthreads();
  if (tid == 0) {
    int a = 0;
#pragma unroll
    for (int k = 0; k < 4; ++k) { int t = wsum[k]; wsum[k] = a; a += t; }
  }
  __syncthreads();
  int excl = wsum[w] + x - v;
  if (i < NN) off[i] = excl;
  if (tid == 255) btot[b] = wsum[3] + x;  // block total (x inclusive at last lane)
}

// stage 2 — exclusive scan of the 79 block totals (one 128-thread block)
__global__ void scan2_kernel(int* __restrict__ btot) {
  __shared__ int s0;
  const int tid = threadIdx.x, lane = tid & 63, w = tid >> 6;
  int v = (tid < NBLK) ? btot[tid] : 0;
  int x = v;
#pragma unroll
  for (int s = 1; s < 64; s <<= 1) {
    int t = __shfl_up(x, s);
    if (lane >= s) x += t;
  }
  if (w == 0 && lane == 63) s0 = x;
  __syncthreads();
  int excl = x - v + (w ? s0 : 0);
  if (tid < NBLK) btot[tid] = excl;
}

// stage 3 — apply block offsets, init cursor, write off[NN]
__global__ void scan3_kernel(int* __restrict__ off, const int* __restrict__ btot,
                             int* __restrict__ cursor) {
  const int i = blockIdx.x * blockDim.x + threadIdx.x;
  if (i < NN) {
    int o = off[i] + btot[i >> 8];
    off[i] = o;
    cursor[i] = o;
  }
  if (i == 0) off[NN] = EF;  // total = EE + NN by construction
}

__global__ void scatter_kernel(const int* __restrict__ src, const int* __restrict__ dst,
                               int* __restrict__ cursor, int* __restrict__ csr_src,
                               int* __restrict__ csr_dst, int* __restrict__ csr_eid) {
  int e = blockIdx.x * blockDim.x + threadIdx.x;
  if (e >= EF) return;
  int s, d;
  if (e < EE) { s = src[e]; d = dst[e]; } else { s = e - EE; d = s; }
  int pos = atomicAdd(&cursor[d], 1);
  csr_src[pos] = s;
  csr_dst[pos] = d;
  csr_eid[pos] = e;
}

// mean edge_attr per node, wave-parallel: lane = edge slot, vectorized row load,
// shuffle-tree reduce (replaces the 17-deep dependent chain per thread).
__global__ __launch_bounds__(256) void mean_ea_kernel(
    const int* __restrict__ off, const int* __restrict__ csr_eid,
    const float* __restrict__ edge_attr, float* __restrict__ mean_ea) {
  const int n = (int)((blockIdx.x * blockDim.x + threadIdx.x) >> 6);
  const int lane = threadIdx.x & 63;
  if (n >= NN) return;
  const int start = off[n], end = off[n + 1];
  float a[24];
#pragma unroll
  for (int d = 0; d < 24; ++d) a[d] = 0.f;
  for (int j = start + lane; j < end; j += 64) {
    int eid = csr_eid[j];
    if (eid < EE) {
      const float* ea = edge_attr + (size_t)eid * EDIM;
      float4 q0 = *(const float4*)(ea + 0);
      float4 q1 = *(const float4*)(ea + 4);
      float4 q2 = *(const float4*)(ea + 8);
      float4 q3 = *(const float4*)(ea + 12);
      float4 q4 = *(const float4*)(ea + 16);
      float2 q5 = *(const float2*)(ea + 20);
      a[0] += q0.x; a[1] += q0.y; a[2] += q0.z; a[3] += q0.w;
      a[4] += q1.x; a[5] += q1.y; a[6] += q1.z; a[7] += q1.w;
      a[8] += q2.x; a[9] += q2.y; a[10] += q2.z; a[11] += q2.w;
      a[12] += q3.x; a[13] += q3.y; a[14] += q3.z; a[15] += q3.w;
      a[16] += q4.x; a[17] += q4.y; a[18] += q4.z; a[19] += q4.w;
      a[20] += q5.x; a[21] += q5.y;
    }
  }
#pragma unroll
  for (int s = 32; s > 0; s >>= 1)
#pragma unroll
    for (int d = 0; d < EDIM; ++d) a[d] += __shfl_xor(a[d], s);
  if (lane == 0) {
    const float den = 1.f / fmaxf((float)(end - start - 1), 1.f);  // deg = list-1 (self loop)
    float* mp = mean_ea + (size_t)n * EDIM;
#pragma unroll
    for (int d = 0; d < EDIM; ++d) mp[d] = a[d] * den;
  }
}

// ---------------------------------------------------------------------------
// dtype conversions
// ---------------------------------------------------------------------------

__global__ void cvt_x_kernel(const float* __restrict__ x, ushort* __restrict__ ab) {
  int t = blockIdx.x * blockDim.x + threadIdx.x;
  if (t >= NN * 32) return;
  int n = t >> 5, c = t & 31;
  ab[t] = (c < 16) ? f2b(x[n * 16 + c]) : (ushort)0;
}

// fused: W1/W2/W3 transpose->bf16 + wecomb for all 3 layers (one launch)
__global__ void prep_weights_kernel(
    const float* __restrict__ W1, const float* __restrict__ W2, const float* __restrict__ W3,
    ushort* __restrict__ wt1, ushort* __restrict__ wt2, ushort* __restrict__ wt3,
    const float* __restrict__ We1, const float* __restrict__ ate1, float* __restrict__ wec1,
    const float* __restrict__ We2, const float* __restrict__ ate2, float* __restrict__ wec2,
    const float* __restrict__ We3, const float* __restrict__ ate3, float* __restrict__ wec3) {
  int t = blockIdx.x * blockDim.x + threadIdx.x;
  // segment sizes
  const int S0 = 256 * 32, S1 = 256 * 256, S2 = 768 * 256;
  const int S3 = EDIM * 8, S4 = EDIM * 8, S5 = EDIM * 12;
  if (t < S0) {
    int nc = t >> 5, k = t & 31;
    wt1[t] = (k < 16) ? f2b(W1[(size_t)k * 256 + nc]) : (ushort)0;
    return;
  }
  t -= S0;
  if (t < S1) {
    int nc = t >> 8, k = t & 255;
    wt2[t] = f2b(W2[(size_t)k * 256 + nc]);
    return;
  }
  t -= S1;
  if (t < S2) {
    int nc = t >> 8, k = t & 255;
    wt3[t] = f2b(W3[(size_t)k * 768 + nc]);
    return;
  }
  t -= S2;
  if (t < S3) {
    int d = t / 8, h = t % 8;
    float v = 0.f;
    for (int c = 0; c < 32; ++c) v += We1[(size_t)d * 256 + h * 32 + c] * ate1[h * 32 + c];
    wec1[t] = v;
    return;
  }
  t -= S3;
  if (t < S4) {
    int d = t / 8, h = t % 8;
    float v = 0.f;
    for (int c = 0; c < 32; ++c) v += We2[(size_t)d * 256 + h * 32 + c] * ate2[h * 32 + c];
    wec2[t] = v;
    return;
  }
  t -= S4;
  if (t < S5) {
    int d = t / 12, h = t % 12;
    float v = 0.f;
    for (int c = 0; c < 64; ++c) v += We3[(size_t)d * 768 + h * 64 + c] * ate3[h * 64 + c];
    wec3[t] = v;
  }
}

// ---------------------------------------------------------------------------
// bf16 MFMA GEMM (round-2/5 proven shape): wave = 16 rows x 64 cols, NFRAG=4.
// ---------------------------------------------------------------------------
__global__ __launch_bounds__(256) void mfma_gemm_kernel(
    const ushort* __restrict__ A, const ushort* __restrict__ Bt,
    ushort* __restrict__ C, int M, int K, int Nc) {
  const int lane = threadIdx.x & 63;
  const int wid = threadIdx.x >> 6;
  const int bm = blockIdx.y * 64 + wid * 16;
  const int bn = blockIdx.x * 64;
  const int r = lane & 15;
  const int kg = lane >> 4;

  f32x4 acc[4] = {};
  const int arow = bm + r;
  const bool aval = arow < M;
  const ushort* aptr = A + (size_t)arow * K + kg * 8;
  const ushort* bptr = Bt + (size_t)(bn + r) * K + kg * 8;

  for (int k0 = 0; k0 < K; k0 += 32) {
    bf16x8 af = {};
    if (aval) af = *(const bf16x8*)(aptr + k0);
#pragma unroll
    for (int nf = 0; nf < 4; ++nf) {
      bf16x8 bfr = *(const bf16x8*)(bptr + (size_t)nf * 16 * K + k0);
      acc[nf] = __builtin_amdgcn_mfma_f32_16x16x32_bf16(af, bfr, acc[nf], 0, 0, 0);
    }
  }
#pragma unroll
  for (int nf = 0; nf < 4; ++nf) {
#pragma unroll
    for (int reg = 0; reg < 4; ++reg) {
      int row = bm + kg * 4 + reg;
      if (row < M) C[(size_t)row * Nc + bn + nf * 16 + r] = f2b(acc[nf][reg]);
    }
  }
}

// ---------------------------------------------------------------------------
// a_s / a_d from bf16 h
// ---------------------------------------------------------------------------
__global__ void asd_kernel(const ushort* __restrict__ h, const float* __restrict__ atts,
                           const float* __restrict__ attd, float* __restrict__ a_s,
                           float* __restrict__ a_d, int H, int C) {
  int t = blockIdx.x * blockDim.x + threadIdx.x;
  if (t >= NN * H) return;
  int n = t / H, hh = t % H;
  const ushort* row = h + (size_t)n * H * C + (size_t)hh * C;
  float s = 0.f, d = 0.f;
  for (int c = 0; c < C; c += 2) {
    unsigned u = *(const unsigned*)(row + c);
    float v0 = blo(u), v1 = bhi(u);
    s += v0 * atts[hh * C + c] + v1 * atts[hh * C + c + 1];
    d += v0 * attd[hh * C + c] + v1 * attd[hh * C + c + 1];
  }
  a_s[t] = s;
  a_d[t] = d;
}

// alpha[j,h] = leaky_relu(a_e(j) + a_s[src(j)] + a_d[dst(j)]), CSR order
__global__ void ase_kernel(const int* __restrict__ csr_eid, const int* __restrict__ csr_src,
                           const int* __restrict__ csr_dst,
                           const float* __restrict__ edge_attr, const float* __restrict__ mean_ea,
                           const float* __restrict__ wec, const float* __restrict__ a_s,
                           const float* __restrict__ a_d, float* __restrict__ alpha, int H) {
  int t = blockIdx.x * blockDim.x + threadIdx.x;
  if (t >= EF * H) return;
  int j = t / H, hh = t % H;
  int eid = csr_eid[j];
  const float* ea = (eid < EE) ? &edge_attr[(size_t)eid * EDIM]
                               : &mean_ea[(size_t)(eid - EE) * EDIM];
  float v = 0.f;
#pragma unroll
  for (int d = 0; d < EDIM; ++d) v += ea[d] * wec[d * H + hh];
  v += a_s[csr_src[j] * H + hh] + a_d[csr_dst[j] * H + hh];
  alpha[t] = lrelu(v);
}

// ---------------------------------------------------------------------------
// Fused aggregation (round-7, frozen): wave = (node, 256-feature chunk).
// ---------------------------------------------------------------------------
template <int H, int C, int NCH>
__global__ __launch_bounds__(256) void aggregate_kernel(
    const float* __restrict__ alpha, const ushort* __restrict__ hb,
    const int* __restrict__ off, const int* __restrict__ csr_src,
    const float* __restrict__ bias, ushort* __restrict__ xb) {
  constexpr int HC = H * C;
  constexpr int CHUNK = HC / NCH;   // 256
  constexpr int HPC = H / NCH;      // heads per chunk (8 or 4)
  constexpr int FPL = CHUNK / 64;   // 4 features per lane (divides C)
  __shared__ float wlds_all[4][64 * HPC];
  const int t = (int)((blockIdx.x * blockDim.x + threadIdx.x) >> 6);
  const int wv = threadIdx.x >> 6;
  const int lane = threadIdx.x & 63;
  const int n = t / NCH, ch = t - n * NCH;
  if (n >= NN) return;
  float* wl = wlds_all[wv];
  const int start = off[n], end = off[n + 1];
  const int h0 = ch * HPC;

  float mx[HPC];
#pragma unroll
  for (int qq = 0; qq < HPC; ++qq) mx[qq] = -1e30f;
  for (int j = start + lane; j < end; j += 64) {
    const float* ap = alpha + (size_t)j * H + h0;
#pragma unroll
    for (int v = 0; v < HPC / 4; ++v) {
      float4 a4 = *(const float4*)(ap + v * 4);
      mx[v * 4 + 0] = fmaxf(mx[v * 4 + 0], a4.x);
      mx[v * 4 + 1] = fmaxf(mx[v * 4 + 1], a4.y);
      mx[v * 4 + 2] = fmaxf(mx[v * 4 + 2], a4.z);
      mx[v * 4 + 3] = fmaxf(mx[v * 4 + 3], a4.w);
    }
  }
#pragma unroll
  for (int s = 32; s > 0; s >>= 1)
#pragma unroll
    for (int qq = 0; qq < HPC; ++qq) mx[qq] = fmaxf(mx[qq], __shfl_xor(mx[qq], s));

  float sm[HPC];
#pragma unroll
  for (int qq = 0; qq < HPC; ++qq) sm[qq] = 0.f;
  for (int j = start + lane; j < end; j += 64) {
    const float* ap = alpha + (size_t)j * H + h0;
#pragma unroll
    for (int v = 0; v < HPC / 4; ++v) {
      float4 a4 = *(const float4*)(ap + v * 4);
      sm[v * 4 + 0] += __expf(a4.x - mx[v * 4 + 0]);
      sm[v * 4 + 1] += __expf(a4.y - mx[v * 4 + 1]);
      sm[v * 4 + 2] += __expf(a4.z - mx[v * 4 + 2]);
      sm[v * 4 + 3] += __expf(a4.w - mx[v * 4 + 3]);
    }
  }
#pragma unroll
  for (int s = 32; s > 0; s >>= 1)
#pragma unroll
    for (int qq = 0; qq < HPC; ++qq) sm[qq] += __shfl_xor(sm[qq], s);
  float rd[HPC];
#pragma unroll
  for (int qq = 0; qq < HPC; ++qq) rd[qq] = 1.f / sm[qq];

  const int q = (lane * FPL) / C;
  const int f0 = ch * CHUNK + lane * FPL;
  const ushort* hrow = hb + f0;
  float acc[FPL] = {};

  for (int t0 = start; t0 < end; t0 += 64) {
    const int m = min(64, end - t0);
    if (lane < m) {
      const float* ap = alpha + (size_t)(t0 + lane) * H + h0;
#pragma unroll
      for (int v = 0; v < HPC / 4; ++v) {
        float4 a4 = *(const float4*)(ap + v * 4);
        float4 w4;
        w4.x = __expf(a4.x - mx[v * 4 + 0]) * rd[v * 4 + 0];
        w4.y = __expf(a4.y - mx[v * 4 + 1]) * rd[v * 4 + 1];
        w4.z = __expf(a4.z - mx[v * 4 + 2]) * rd[v * 4 + 2];
        w4.w = __expf(a4.w - mx[v * 4 + 3]) * rd[v * 4 + 3];
        *(float4*)(wl + lane * HPC + v * 4) = w4;
      }
    }
    int e = 0;
    for (; e + 4 <= m; e += 4) {
      const int j = t0 + e;
      int s0 = csr_src[j], s1 = csr_src[j + 1], s2 = csr_src[j + 2], s3 = csr_src[j + 3];
      float w0 = wl[(e + 0) * HPC + q];
      float w1 = wl[(e + 1) * HPC + q];
      float w2 = wl[(e + 2) * HPC + q];
      float w3 = wl[(e + 3) * HPC + q];
      uint2 u0 = *(const uint2*)(hrow + (size_t)s0 * HC);
      uint2 u1 = *(const uint2*)(hrow + (size_t)s1 * HC);
      uint2 u2 = *(const uint2*)(hrow + (size_t)s2 * HC);
      uint2 u3 = *(const uint2*)(hrow + (size_t)s3 * HC);
      acc[0] += w0 * blo(u0.x) + w1 * blo(u1.x) + w2 * blo(u2.x) + w3 * blo(u3.x);
      acc[1] += w0 * bhi(u0.x) + w1 * bhi(u1.x) + w2 * bhi(u2.x) + w3 * bhi(u3.x);
      acc[2] += w0 * blo(u0.y) + w1 * blo(u1.y) + w2 * blo(u2.y) + w3 * blo(u3.y);
      acc[3] += w0 * bhi(u0.y) + w1 * bhi(u1.y) + w2 * bhi(u2.y) + w3 * bhi(u3.y);
    }
    for (; e < m; ++e) {
      const int j = t0 + e;
      int s0 = csr_src[j];
      float w0 = wl[e * HPC + q];
      uint2 u0 = *(const uint2*)(hrow + (size_t)s0 * HC);
      acc[0] += w0 * blo(u0.x);
      acc[1] += w0 * bhi(u0.x);
      acc[2] += w0 * blo(u0.y);
      acc[3] += w0 * bhi(u0.y);
    }
  }

  ushort o[FPL];
#pragma unroll
  for (int i = 0; i < FPL; ++i) o[i] = f2b(fmaxf(acc[i] + bias[f0 + i], 0.f));
  uint2 pk;
  pk.x = (unsigned)o[0] | ((unsigned)o[1] << 16);
  pk.y = (unsigned)o[2] | ((unsigned)o[3] << 16);
  *(uint2*)(xb + (size_t)n * HC + f0) = pk;
}

// ---------------------------------------------------------------------------
// Final head: sigmoid(concat(x1,x2,x3) @ Wf + bf), bf16 inputs. 1 wave/node.
// ---------------------------------------------------------------------------
__global__ void final_kernel(const ushort* __restrict__ x1b, const ushort* __restrict__ x2b,
                             const ushort* __restrict__ x3b, const float* __restrict__ Wf,
                             const float* __restrict__ bf, float* __restrict__ out) {
  const int wave = (int)((blockIdx.x * blockDim.x + threadIdx.x) >> 6);
  const int lane = threadIdx.x & 63;
  if (wave >= NN) return;
  float acc = 0.f;
#pragma unroll
  for (int q = 0; q < 5; ++q) {
    int f0 = (q * 64 + lane) * 4;
    const ushort* sp;
    if (f0 < 256)      sp = x1b + (size_t)wave * 256 + f0;
    else if (f0 < 512) sp = x2b + (size_t)wave * 256 + (f0 - 256);
    else               sp = x3b + (size_t)wave * 768 + (f0 - 512);
    uint2 u = *(const uint2*)sp;
    float4 wv = *(const float4*)(Wf + f0);
    acc += blo(u.x) * wv.x + bhi(u.x) * wv.y + blo(u.y) * wv.z + bhi(u.y) * wv.w;
  }
#pragma unroll
  for (int s = 32; s > 0; s >>= 1) acc += __shfl_xor(acc, s);
  if (lane == 0) out[wave] = 1.f / (1.f + __expf(-(acc + bf[0])));
}

// ---------------------------------------------------------------------------

extern "C" void kernel_launch(void* const* d_in, const int* in_sizes, int n_in,
                              void* d_out, int out_size, void* d_ws, size_t ws_size,
                              hipStream_t stream) {
  const float* x     = (const float*)d_in[0];
  const int*   eidx  = (const int*)d_in[1];
  const float* eattr = (const float*)d_in[2];
  const float* W[3]   = {(const float*)d_in[3],  (const float*)d_in[9],  (const float*)d_in[15]};
  const float* ats[3] = {(const float*)d_in[4],  (const float*)d_in[10], (const float*)d_in[16]};
  const float* atd[3] = {(const float*)d_in[5],  (const float*)d_in[11], (const float*)d_in[17]};
  const float* We[3]  = {(const float*)d_in[6],  (const float*)d_in[12], (const float*)d_in[18]};
  const float* ate[3] = {(const float*)d_in[7],  (const float*)d_in[13], (const float*)d_in[19]};
  const float* bb[3]  = {(const float*)d_in[8],  (const float*)d_in[14], (const float*)d_in[20]};
  const float* Wf = (const float*)d_in[21];
  const float* bf = (const float*)d_in[22];
  float* out = (float*)d_out;

  const int* src = eidx;
  const int* dst = eidx + EE;

  char* p = (char*)d_ws;
  auto carve = [&](size_t bytes) -> char* {
    char* q = p;
    p += (bytes + 255) & ~(size_t)255;
    return q;
  };
  ushort* x1b   = (ushort*)carve((size_t)NN * 256 * 2);
  ushort* x2b   = (ushort*)carve((size_t)NN * 256 * 2);
  ushort* x3b   = (ushort*)carve((size_t)NN * 768 * 2);
  ushort* hbuf  = (ushort*)carve((size_t)NN * 768 * 2);
  ushort* abf1  = (ushort*)carve((size_t)NN * 32 * 2);
  ushort* wt1   = (ushort*)carve((size_t)256 * 32 * 2);
  ushort* wt2   = (ushort*)carve((size_t)256 * 256 * 2);
  ushort* wt3   = (ushort*)carve((size_t)768 * 256 * 2);
  float*  a_s   = (float*)carve((size_t)NN * 12 * 4);
  float*  a_d   = (float*)carve((size_t)NN * 12 * 4);
  float*  alpha = (float*)carve((size_t)EF * 12 * 4);
  float*  mea   = (float*)carve((size_t)NN * EDIM * 4);
  float*  wec1  = (float*)carve((size_t)EDIM * 8 * 4);
  float*  wec2  = (float*)carve((size_t)EDIM * 8 * 4);
  float*  wec3  = (float*)carve((size_t)EDIM * 12 * 4);
  int* cnt      = (int*)carve((size_t)NN * 4);
  int* off      = (int*)carve((size_t)(NN + 1) * 4);
  int* btot     = (int*)carve((size_t)NBLK * 4);
  int* cursor   = (int*)carve((size_t)NN * 4);
  int* csr_src  = (int*)carve((size_t)EF * 4);
  int* csr_dst  = (int*)carve((size_t)EF * 4);
  int* csr_eid  = (int*)carve((size_t)EF * 4);

  // ---- graph structure (hierarchical scan + wave-parallel mean_ea) ----
  hipMemsetAsync(cnt, 0, (size_t)NN * 4, stream);
  count_deg_kernel<<<(EE + 255) / 256, 256, 0, stream>>>(dst, cnt);
  scan1_kernel<<<NBLK, 256, 0, stream>>>(cnt, off, btot);
  scan2_kernel<<<1, 128, 0, stream>>>(btot);
  scan3_kernel<<<NBLK, 256, 0, stream>>>(off, btot, cursor);
  scatter_kernel<<<(EF + 255) / 256, 256, 0, stream>>>(src, dst, cursor, csr_src, csr_dst,
                                                       csr_eid);
  mean_ea_kernel<<<(NN * 64 + 255) / 256, 256, 0, stream>>>(off, csr_eid, eattr, mea);

  // ---- dtype prep (fused) ----
  cvt_x_kernel<<<(NN * 32 + 255) / 256, 256, 0, stream>>>(x, abf1);
  {
    const int total = 256 * 32 + 256 * 256 + 768 * 256 + EDIM * 8 + EDIM * 8 + EDIM * 12;
    prep_weights_kernel<<<(total + 255) / 256, 256, 0, stream>>>(
        W[0], W[1], W[2], wt1, wt2, wt3,
        We[0], ate[0], wec1, We[1], ate[1], wec2, We[2], ate[2], wec3);
  }

  const int Hs[3] = {8, 8, 12};
  const int Cs[3] = {32, 32, 64};
  const int Kp[3] = {32, 256, 256};
  const ushort* Ain[3] = {abf1, x1b, x2b};
  const ushort* Wt[3] = {wt1, wt2, wt3};
  float* wecL[3] = {wec1, wec2, wec3};
  ushort* xoutb[3] = {x1b, x2b, x3b};

  for (int L = 0; L < 3; ++L) {
    const int H = Hs[L], C = Cs[L], HC = H * C;
    dim3 g(HC / 64, (NN + 63) / 64);
    mfma_gemm_kernel<<<g, 256, 0, stream>>>(Ain[L], Wt[L], hbuf, NN, Kp[L], HC);
    asd_kernel<<<(NN * H + 255) / 256, 256, 0, stream>>>(hbuf, ats[L], atd[L], a_s, a_d, H, C);
    ase_kernel<<<(EF * H + 255) / 256, 256, 0, stream>>>(csr_eid, csr_src, csr_dst, eattr,
                                                         mea, wecL[L], a_s, a_d, alpha, H);
    if (H == 8) {
      int blocks = (NN * 1 + 3) / 4;
      aggregate_kernel<8, 32, 1><<<blocks, 256, 0, stream>>>(alpha, hbuf, off, csr_src,
                                                             bb[L], xoutb[L]);
    } else {
      int blocks = (NN * 3 + 3) / 4;
      aggregate_kernel<12, 64, 3><<<blocks, 256, 0, stream>>>(alpha, hbuf, off, csr_src,
                                                              bb[L], xoutb[L]);
    }
  }

  final_kernel<<<(NN * 64 + 255) / 256, 256, 0, stream>>>(x1b, x2b, x3b, Wf, bf, out);
}

// Round 9
// 486.279 us; speedup vs baseline: 1.1290x; 1.0217x over previous
//
#include <hip/hip_runtime.h>

#define NN 20000
#define EE 320000
#define EF 340000   /* EE + NN self loops */
#define EDIM 22
#define NBLK ((NN + 255) / 256)   /* 79 scan blocks */

typedef short bf16x8 __attribute__((ext_vector_type(8)));
typedef float f32x4 __attribute__((ext_vector_type(4)));

__device__ __forceinline__ float blo(unsigned u) {
  union { unsigned x; float f; } v; v.x = u << 16; return v.f;
}
__device__ __forceinline__ float bhi(unsigned u) {
  union { unsigned x; float f; } v; v.x = u & 0xffff0000u; return v.f;
}
__device__ __forceinline__ ushort f2b(float f) {
  union { float f; unsigned u; } v;
  v.f = f;
  unsigned u = v.u;
  return (ushort)((u + 0x7fffu + ((u >> 16) & 1u)) >> 16);  // RNE
}
__device__ __forceinline__ float lrelu(float a) { return a > 0.f ? a : 0.2f * a; }

// ---------------------------------------------------------------------------
// Graph setup: CSR by dst (counting sort), mean edge_attr for self loops
// ---------------------------------------------------------------------------

__global__ void count_deg_kernel(const int* __restrict__ dst, int* __restrict__ cnt) {
  int e = blockIdx.x * blockDim.x + threadIdx.x;
  if (e < EE) atomicAdd(&cnt[dst[e]], 1);
}

__global__ void scan1_kernel(const int* __restrict__ cnt, int* __restrict__ off,
                             int* __restrict__ btot) {
  __shared__ int wsum[4];
  const int b = blockIdx.x, tid = threadIdx.x;
  const int lane = tid & 63, w = tid >> 6;
  const int i = b * 256 + tid;
  int v = (i < NN) ? (cnt[i] + 1) : 0;
  int x = v;
#pragma unroll
  for (int s = 1; s < 64; s <<= 1) {
    int t = __shfl_up(x, s);
    if (lane >= s) x += t;
  }
  if (lane == 63) wsum[w] = x;
  __syncthreads();
  if (tid == 0) {
    int a = 0;
#pragma unroll
    for (int k = 0; k < 4; ++k) { int t = wsum[k]; wsum[k] = a; a += t; }
  }
  __syncthreads();
  int excl = wsum[w] + x - v;
  if (i < NN) off[i] = excl;
  if (tid == 255) btot[b] = wsum[3] + x;
}

__global__ void scan2_kernel(int* __restrict__ btot) {
  __shared__ int s0;
  const int tid = threadIdx.x, lane = tid & 63, w = tid >> 6;
  int v = (tid < NBLK) ? btot[tid] : 0;
  int x = v;
#pragma unroll
  for (int s = 1; s < 64; s <<= 1) {
    int t = __shfl_up(x, s);
    if (lane >= s) x += t;
  }
  if (w == 0 && lane == 63) s0 = x;
  __syncthreads();
  int excl = x - v + (w ? s0 : 0);
  if (tid < NBLK) btot[tid] = excl;
}

__global__ void scan3_kernel(int* __restrict__ off, const int* __restrict__ btot,
                             int* __restrict__ cursor) {
  const int i = blockIdx.x * blockDim.x + threadIdx.x;
  if (i < NN) {
    int o = off[i] + btot[i >> 8];
    off[i] = o;
    cursor[i] = o;
  }
  if (i == 0) off[NN] = EF;
}

__global__ void scatter_kernel(const int* __restrict__ src, const int* __restrict__ dst,
                               int* __restrict__ cursor, int* __restrict__ csr_src,
                               int* __restrict__ csr_dst, int* __restrict__ csr_eid) {
  int e = blockIdx.x * blockDim.x + threadIdx.x;
  if (e >= EF) return;
  int s, d;
  if (e < EE) { s = src[e]; d = dst[e]; } else { s = e - EE; d = s; }
  int pos = atomicAdd(&cursor[d], 1);
  csr_src[pos] = s;
  csr_dst[pos] = d;
  csr_eid[pos] = e;
}

__global__ __launch_bounds__(256) void mean_ea_kernel(
    const int* __restrict__ off, const int* __restrict__ csr_eid,
    const float* __restrict__ edge_attr, float* __restrict__ mean_ea) {
  const int n = (int)((blockIdx.x * blockDim.x + threadIdx.x) >> 6);
  const int lane = threadIdx.x & 63;
  if (n >= NN) return;
  const int start = off[n], end = off[n + 1];
  float a[24];
#pragma unroll
  for (int d = 0; d < 24; ++d) a[d] = 0.f;
  for (int j = start + lane; j < end; j += 64) {
    int eid = csr_eid[j];
    if (eid < EE) {
      const float* ea = edge_attr + (size_t)eid * EDIM;
      float4 q0 = *(const float4*)(ea + 0);
      float4 q1 = *(const float4*)(ea + 4);
      float4 q2 = *(const float4*)(ea + 8);
      float4 q3 = *(const float4*)(ea + 12);
      float4 q4 = *(const float4*)(ea + 16);
      float2 q5 = *(const float2*)(ea + 20);
      a[0] += q0.x; a[1] += q0.y; a[2] += q0.z; a[3] += q0.w;
      a[4] += q1.x; a[5] += q1.y; a[6] += q1.z; a[7] += q1.w;
      a[8] += q2.x; a[9] += q2.y; a[10] += q2.z; a[11] += q2.w;
      a[12] += q3.x; a[13] += q3.y; a[14] += q3.z; a[15] += q3.w;
      a[16] += q4.x; a[17] += q4.y; a[18] += q4.z; a[19] += q4.w;
      a[20] += q5.x; a[21] += q5.y;
    }
  }
#pragma unroll
  for (int s = 32; s > 0; s >>= 1)
#pragma unroll
    for (int d = 0; d < EDIM; ++d) a[d] += __shfl_xor(a[d], s);
  if (lane == 0) {
    const float den = 1.f / fmaxf((float)(end - start - 1), 1.f);
    float* mp = mean_ea + (size_t)n * EDIM;
#pragma unroll
    for (int d = 0; d < EDIM; ++d) mp[d] = a[d] * den;
  }
}

// ---------------------------------------------------------------------------
// dtype conversions
// ---------------------------------------------------------------------------

__global__ void cvt_x_kernel(const float* __restrict__ x, ushort* __restrict__ ab) {
  int t = blockIdx.x * blockDim.x + threadIdx.x;
  if (t >= NN * 32) return;
  int n = t >> 5, c = t & 31;
  ab[t] = (c < 16) ? f2b(x[n * 16 + c]) : (ushort)0;
}

__global__ void prep_weights_kernel(
    const float* __restrict__ W1, const float* __restrict__ W2, const float* __restrict__ W3,
    ushort* __restrict__ wt1, ushort* __restrict__ wt2, ushort* __restrict__ wt3,
    const float* __restrict__ We1, const float* __restrict__ ate1, float* __restrict__ wec1,
    const float* __restrict__ We2, const float* __restrict__ ate2, float* __restrict__ wec2,
    const float* __restrict__ We3, const float* __restrict__ ate3, float* __restrict__ wec3) {
  int t = blockIdx.x * blockDim.x + threadIdx.x;
  const int S0 = 256 * 32, S1 = 256 * 256, S2 = 768 * 256;
  const int S3 = EDIM * 8, S4 = EDIM * 8, S5 = EDIM * 12;
  if (t < S0) {
    int nc = t >> 5, k = t & 31;
    wt1[t] = (k < 16) ? f2b(W1[(size_t)k * 256 + nc]) : (ushort)0;
    return;
  }
  t -= S0;
  if (t < S1) {
    int nc = t >> 8, k = t & 255;
    wt2[t] = f2b(W2[(size_t)k * 256 + nc]);
    return;
  }
  t -= S1;
  if (t < S2) {
    int nc = t >> 8, k = t & 255;
    wt3[t] = f2b(W3[(size_t)k * 768 + nc]);
    return;
  }
  t -= S2;
  if (t < S3) {
    int d = t / 8, h = t % 8;
    float v = 0.f;
    for (int c = 0; c < 32; ++c) v += We1[(size_t)d * 256 + h * 32 + c] * ate1[h * 32 + c];
    wec1[t] = v;
    return;
  }
  t -= S3;
  if (t < S4) {
    int d = t / 8, h = t % 8;
    float v = 0.f;
    for (int c = 0; c < 32; ++c) v += We2[(size_t)d * 256 + h * 32 + c] * ate2[h * 32 + c];
    wec2[t] = v;
    return;
  }
  t -= S4;
  if (t < S5) {
    int d = t / 12, h = t % 12;
    float v = 0.f;
    for (int c = 0; c < 64; ++c) v += We3[(size_t)d * 768 + h * 64 + c] * ate3[h * 64 + c];
    wec3[t] = v;
  }
}

// ---------------------------------------------------------------------------
// bf16 MFMA GEMM: wave = 16 rows x NFRAG*16 cols. NFRAG=4 (L1/L2), 8 (L3:
// halves A re-reads, 12x -> 6x, while keeping 1878 blocks for occupancy).
// ---------------------------------------------------------------------------
template <int NFRAG>
__global__ __launch_bounds__(256) void mfma_gemm_kernel(
    const ushort* __restrict__ A, const ushort* __restrict__ Bt,
    ushort* __restrict__ C, int M, int K, int Nc) {
  const int lane = threadIdx.x & 63;
  const int wid = threadIdx.x >> 6;
  const int bm = blockIdx.y * 64 + wid * 16;
  const int bn = blockIdx.x * (NFRAG * 16);
  const int r = lane & 15;
  const int kg = lane >> 4;

  f32x4 acc[NFRAG] = {};
  const int arow = bm + r;
  const bool aval = arow < M;
  const ushort* aptr = A + (size_t)arow * K + kg * 8;
  const ushort* bptr = Bt + (size_t)(bn + r) * K + kg * 8;

  for (int k0 = 0; k0 < K; k0 += 32) {
    bf16x8 af = {};
    if (aval) af = *(const bf16x8*)(aptr + k0);
#pragma unroll
    for (int nf = 0; nf < NFRAG; ++nf) {
      bf16x8 bfr = *(const bf16x8*)(bptr + (size_t)nf * 16 * K + k0);
      acc[nf] = __builtin_amdgcn_mfma_f32_16x16x32_bf16(af, bfr, acc[nf], 0, 0, 0);
    }
  }
#pragma unroll
  for (int nf = 0; nf < NFRAG; ++nf) {
#pragma unroll
    for (int reg = 0; reg < 4; ++reg) {
      int row = bm + kg * 4 + reg;
      if (row < M) C[(size_t)row * Nc + bn + nf * 16 + r] = f2b(acc[nf][reg]);
    }
  }
}

// ---------------------------------------------------------------------------
// a_s / a_d from bf16 h
// ---------------------------------------------------------------------------
__global__ void asd_kernel(const ushort* __restrict__ h, const float* __restrict__ atts,
                           const float* __restrict__ attd, float* __restrict__ a_s,
                           float* __restrict__ a_d, int H, int C) {
  int t = blockIdx.x * blockDim.x + threadIdx.x;
  if (t >= NN * H) return;
  int n = t / H, hh = t % H;
  const ushort* row = h + (size_t)n * H * C + (size_t)hh * C;
  float s = 0.f, d = 0.f;
  for (int c = 0; c < C; c += 2) {
    unsigned u = *(const unsigned*)(row + c);
    float v0 = blo(u), v1 = bhi(u);
    s += v0 * atts[hh * C + c] + v1 * atts[hh * C + c + 1];
    d += v0 * attd[hh * C + c] + v1 * attd[hh * C + c + 1];
  }
  a_s[t] = s;
  a_d[t] = d;
}

// alpha[j,h] = leaky_relu(a_e(j) + a_s[src(j)] + a_d[dst(j)]), CSR order
__global__ void ase_kernel(const int* __restrict__ csr_eid, const int* __restrict__ csr_src,
                           const int* __restrict__ csr_dst,
                           const float* __restrict__ edge_attr, const float* __restrict__ mean_ea,
                           const float* __restrict__ wec, const float* __restrict__ a_s,
                           const float* __restrict__ a_d, float* __restrict__ alpha, int H) {
  int t = blockIdx.x * blockDim.x + threadIdx.x;
  if (t >= EF * H) return;
  int j = t / H, hh = t % H;
  int eid = csr_eid[j];
  const float* ea = (eid < EE) ? &edge_attr[(size_t)eid * EDIM]
                               : &mean_ea[(size_t)(eid - EE) * EDIM];
  float v = 0.f;
#pragma unroll
  for (int d = 0; d < EDIM; ++d) v += ea[d] * wec[d * H + hh];
  v += a_s[csr_src[j] * H + hh] + a_d[csr_dst[j] * H + hh];
  alpha[t] = lrelu(v);
}

// ---------------------------------------------------------------------------
// Single-pass fused aggregation: wave = (node, 256-feature chunk).
// No max-subtraction (alpha is lrelu-bounded, exp(alpha) exact in f32 —
// identical to reference's shifted softmax). Per 64-edge tile, lane e
// computes exp(alpha) for its edge's HPC heads -> LDS + accumulates denom
// partials; gather accumulates UNNORMALIZED acc; one shuffle-reduce of the
// denominator at the end, divide in epilogue. alpha read once (was 3x).
// ---------------------------------------------------------------------------
template <int H, int C, int NCH>
__global__ __launch_bounds__(256) void aggregate_kernel(
    const float* __restrict__ alpha, const ushort* __restrict__ hb,
    const int* __restrict__ off, const int* __restrict__ csr_src,
    const float* __restrict__ bias, ushort* __restrict__ xb) {
  constexpr int HC = H * C;
  constexpr int CHUNK = HC / NCH;   // 256
  constexpr int HPC = H / NCH;      // heads per chunk (8 or 4)
  constexpr int FPL = CHUNK / 64;   // 4 features per lane (divides C)
  __shared__ float wlds_all[4][64 * HPC];
  const int t = (int)((blockIdx.x * blockDim.x + threadIdx.x) >> 6);
  const int wv = threadIdx.x >> 6;
  const int lane = threadIdx.x & 63;
  const int n = t / NCH, ch = t - n * NCH;
  if (n >= NN) return;
  float* wl = wlds_all[wv];
  const int start = off[n], end = off[n + 1];
  const int h0 = ch * HPC;

  const int q = (lane * FPL) / C;        // lane's head within chunk
  const int f0 = ch * CHUNK + lane * FPL;
  const ushort* hrow = hb + f0;
  float acc[FPL] = {};
  float dn[HPC];
#pragma unroll
  for (int qq = 0; qq < HPC; ++qq) dn[qq] = 0.f;

  for (int t0 = start; t0 < end; t0 += 64) {
    const int m = min(64, end - t0);
    if (lane < m) {
      const float* ap = alpha + (size_t)(t0 + lane) * H + h0;
#pragma unroll
      for (int v = 0; v < HPC / 4; ++v) {
        float4 a4 = *(const float4*)(ap + v * 4);
        float4 w4;
        w4.x = __expf(a4.x);
        w4.y = __expf(a4.y);
        w4.z = __expf(a4.z);
        w4.w = __expf(a4.w);
        dn[v * 4 + 0] += w4.x;
        dn[v * 4 + 1] += w4.y;
        dn[v * 4 + 2] += w4.z;
        dn[v * 4 + 3] += w4.w;
        *(float4*)(wl + lane * HPC + v * 4) = w4;
      }
    }
    int e = 0;
    for (; e + 4 <= m; e += 4) {
      const int j = t0 + e;
      int s0 = csr_src[j], s1 = csr_src[j + 1], s2 = csr_src[j + 2], s3 = csr_src[j + 3];
      float w0 = wl[(e + 0) * HPC + q];
      float w1 = wl[(e + 1) * HPC + q];
      float w2 = wl[(e + 2) * HPC + q];
      float w3 = wl[(e + 3) * HPC + q];
      uint2 u0 = *(const uint2*)(hrow + (size_t)s0 * HC);
      uint2 u1 = *(const uint2*)(hrow + (size_t)s1 * HC);
      uint2 u2 = *(const uint2*)(hrow + (size_t)s2 * HC);
      uint2 u3 = *(const uint2*)(hrow + (size_t)s3 * HC);
      acc[0] += w0 * blo(u0.x) + w1 * blo(u1.x) + w2 * blo(u2.x) + w3 * blo(u3.x);
      acc[1] += w0 * bhi(u0.x) + w1 * bhi(u1.x) + w2 * bhi(u2.x) + w3 * bhi(u3.x);
      acc[2] += w0 * blo(u0.y) + w1 * blo(u1.y) + w2 * blo(u2.y) + w3 * blo(u3.y);
      acc[3] += w0 * bhi(u0.y) + w1 * bhi(u1.y) + w2 * bhi(u2.y) + w3 * bhi(u3.y);
    }
    for (; e < m; ++e) {
      const int j = t0 + e;
      int s0 = csr_src[j];
      float w0 = wl[e * HPC + q];
      uint2 u0 = *(const uint2*)(hrow + (size_t)s0 * HC);
      acc[0] += w0 * blo(u0.x);
      acc[1] += w0 * bhi(u0.x);
      acc[2] += w0 * blo(u0.y);
      acc[3] += w0 * bhi(u0.y);
    }
  }

  // denominator: shuffle-reduce per head, then normalize lane's slice
#pragma unroll
  for (int s = 32; s > 0; s >>= 1)
#pragma unroll
    for (int qq = 0; qq < HPC; ++qq) dn[qq] += __shfl_xor(dn[qq], s);
  const float my_rd = 1.f / dn[q];

  ushort o[FPL];
#pragma unroll
  for (int i = 0; i < FPL; ++i) o[i] = f2b(fmaxf(acc[i] * my_rd + bias[f0 + i], 0.f));
  uint2 pk;
  pk.x = (unsigned)o[0] | ((unsigned)o[1] << 16);
  pk.y = (unsigned)o[2] | ((unsigned)o[3] << 16);
  *(uint2*)(xb + (size_t)n * HC + f0) = pk;
}

// ---------------------------------------------------------------------------
// Final head: sigmoid(concat(x1,x2,x3) @ Wf + bf), bf16 inputs. 1 wave/node.
// ---------------------------------------------------------------------------
__global__ void final_kernel(const ushort* __restrict__ x1b, const ushort* __restrict__ x2b,
                             const ushort* __restrict__ x3b, const float* __restrict__ Wf,
                             const float* __restrict__ bf, float* __restrict__ out) {
  const int wave = (int)((blockIdx.x * blockDim.x + threadIdx.x) >> 6);
  const int lane = threadIdx.x & 63;
  if (wave >= NN) return;
  float acc = 0.f;
#pragma unroll
  for (int q = 0; q < 5; ++q) {
    int f0 = (q * 64 + lane) * 4;
    const ushort* sp;
    if (f0 < 256)      sp = x1b + (size_t)wave * 256 + f0;
    else if (f0 < 512) sp = x2b + (size_t)wave * 256 + (f0 - 256);
    else               sp = x3b + (size_t)wave * 768 + (f0 - 512);
    uint2 u = *(const uint2*)sp;
    float4 wv = *(const float4*)(Wf + f0);
    acc += blo(u.x) * wv.x + bhi(u.x) * wv.y + blo(u.y) * wv.z + bhi(u.y) * wv.w;
  }
#pragma unroll
  for (int s = 32; s > 0; s >>= 1) acc += __shfl_xor(acc, s);
  if (lane == 0) out[wave] = 1.f / (1.f + __expf(-(acc + bf[0])));
}

// ---------------------------------------------------------------------------

extern "C" void kernel_launch(void* const* d_in, const int* in_sizes, int n_in,
                              void* d_out, int out_size, void* d_ws, size_t ws_size,
                              hipStream_t stream) {
  const float* x     = (const float*)d_in[0];
  const int*   eidx  = (const int*)d_in[1];
  const float* eattr = (const float*)d_in[2];
  const float* W[3]   = {(const float*)d_in[3],  (const float*)d_in[9],  (const float*)d_in[15]};
  const float* ats[3] = {(const float*)d_in[4],  (const float*)d_in[10], (const float*)d_in[16]};
  const float* atd[3] = {(const float*)d_in[5],  (const float*)d_in[11], (const float*)d_in[17]};
  const float* We[3]  = {(const float*)d_in[6],  (const float*)d_in[12], (const float*)d_in[18]};
  const float* ate[3] = {(const float*)d_in[7],  (const float*)d_in[13], (const float*)d_in[19]};
  const float* bb[3]  = {(const float*)d_in[8],  (const float*)d_in[14], (const float*)d_in[20]};
  const float* Wf = (const float*)d_in[21];
  const float* bf = (const float*)d_in[22];
  float* out = (float*)d_out;

  const int* src = eidx;
  const int* dst = eidx + EE;

  char* p = (char*)d_ws;
  auto carve = [&](size_t bytes) -> char* {
    char* q = p;
    p += (bytes + 255) & ~(size_t)255;
    return q;
  };
  ushort* x1b   = (ushort*)carve((size_t)NN * 256 * 2);
  ushort* x2b   = (ushort*)carve((size_t)NN * 256 * 2);
  ushort* x3b   = (ushort*)carve((size_t)NN * 768 * 2);
  ushort* hbuf  = (ushort*)carve((size_t)NN * 768 * 2);
  ushort* abf1  = (ushort*)carve((size_t)NN * 32 * 2);
  ushort* wt1   = (ushort*)carve((size_t)256 * 32 * 2);
  ushort* wt2   = (ushort*)carve((size_t)256 * 256 * 2);
  ushort* wt3   = (ushort*)carve((size_t)768 * 256 * 2);
  float*  a_s   = (float*)carve((size_t)NN * 12 * 4);
  float*  a_d   = (float*)carve((size_t)NN * 12 * 4);
  float*  alpha = (float*)carve((size_t)EF * 12 * 4);
  float*  mea   = (float*)carve((size_t)NN * EDIM * 4);
  float*  wec1  = (float*)carve((size_t)EDIM * 8 * 4);
  float*  wec2  = (float*)carve((size_t)EDIM * 8 * 4);
  float*  wec3  = (float*)carve((size_t)EDIM * 12 * 4);
  int* cnt      = (int*)carve((size_t)NN * 4);
  int* off      = (int*)carve((size_t)(NN + 1) * 4);
  int* btot     = (int*)carve((size_t)NBLK * 4);
  int* cursor   = (int*)carve((size_t)NN * 4);
  int* csr_src  = (int*)carve((size_t)EF * 4);
  int* csr_dst  = (int*)carve((size_t)EF * 4);
  int* csr_eid  = (int*)carve((size_t)EF * 4);

  // ---- graph structure ----
  hipMemsetAsync(cnt, 0, (size_t)NN * 4, stream);
  count_deg_kernel<<<(EE + 255) / 256, 256, 0, stream>>>(dst, cnt);
  scan1_kernel<<<NBLK, 256, 0, stream>>>(cnt, off, btot);
  scan2_kernel<<<1, 128, 0, stream>>>(btot);
  scan3_kernel<<<NBLK, 256, 0, stream>>>(off, btot, cursor);
  scatter_kernel<<<(EF + 255) / 256, 256, 0, stream>>>(src, dst, cursor, csr_src, csr_dst,
                                                       csr_eid);
  mean_ea_kernel<<<(NN * 64 + 255) / 256, 256, 0, stream>>>(off, csr_eid, eattr, mea);

  // ---- dtype prep (fused) ----
  cvt_x_kernel<<<(NN * 32 + 255) / 256, 256, 0, stream>>>(x, abf1);
  {
    const int total = 256 * 32 + 256 * 256 + 768 * 256 + EDIM * 8 + EDIM * 8 + EDIM * 12;
    prep_weights_kernel<<<(total + 255) / 256, 256, 0, stream>>>(
        W[0], W[1], W[2], wt1, wt2, wt3,
        We[0], ate[0], wec1, We[1], ate[1], wec2, We[2], ate[2], wec3);
  }

  const int Hs[3] = {8, 8, 12};
  const int Cs[3] = {32, 32, 64};
  const int Kp[3] = {32, 256, 256};
  const ushort* Ain[3] = {abf1, x1b, x2b};
  const ushort* Wt[3] = {wt1, wt2, wt3};
  float* wecL[3] = {wec1, wec2, wec3};
  ushort* xoutb[3] = {x1b, x2b, x3b};

  for (int L = 0; L < 3; ++L) {
    const int H = Hs[L], C = Cs[L], HC = H * C;
    if (L < 2) {
      dim3 g(HC / 64, (NN + 63) / 64);
      mfma_gemm_kernel<4><<<g, 256, 0, stream>>>(Ain[L], Wt[L], hbuf, NN, Kp[L], HC);
    } else {
      dim3 g(HC / 128, (NN + 63) / 64);   // 6 x 313: A re-read 6x (was 12x)
      mfma_gemm_kernel<8><<<g, 256, 0, stream>>>(Ain[L], Wt[L], hbuf, NN, Kp[L], HC);
    }
    asd_kernel<<<(NN * H + 255) / 256, 256, 0, stream>>>(hbuf, ats[L], atd[L], a_s, a_d, H, C);
    ase_kernel<<<(EF * H + 255) / 256, 256, 0, stream>>>(csr_eid, csr_src, csr_dst, eattr,
                                                         mea, wecL[L], a_s, a_d, alpha, H);
    if (H == 8) {
      int blocks = (NN * 1 + 3) / 4;
      aggregate_kernel<8, 32, 1><<<blocks, 256, 0, stream>>>(alpha, hbuf, off, csr_src,
                                                             bb[L], xoutb[L]);
    } else {
      int blocks = (NN * 3 + 3) / 4;
      aggregate_kernel<12, 64, 3><<<blocks, 256, 0, stream>>>(alpha, hbuf, off, csr_src,
                                                              bb[L], xoutb[L]);
    }
  }

  final_kernel<<<(NN * 64 + 255) / 256, 256, 0, stream>>>(x1b, x2b, x3b, Wf, bf, out);
}

// Round 10
// 422.366 us; speedup vs baseline: 1.2998x; 1.1513x over previous
//
#include <hip/hip_runtime.h>

#define NN 20000
#define EE 320000
#define EF 340000   /* EE + NN self loops */
#define EDIM 22
#define NBLK ((NN + 255) / 256)   /* 79 scan blocks */

typedef short bf16x8 __attribute__((ext_vector_type(8)));
typedef float f32x4 __attribute__((ext_vector_type(4)));

__device__ __forceinline__ float blo(unsigned u) {
  union { unsigned x; float f; } v; v.x = u << 16; return v.f;
}
__device__ __forceinline__ float bhi(unsigned u) {
  union { unsigned x; float f; } v; v.x = u & 0xffff0000u; return v.f;
}
__device__ __forceinline__ ushort f2b(float f) {
  union { float f; unsigned u; } v;
  v.f = f;
  unsigned u = v.u;
  return (ushort)((u + 0x7fffu + ((u >> 16) & 1u)) >> 16);  // RNE
}
__device__ __forceinline__ float lrelu(float a) { return a > 0.f ? a : 0.2f * a; }

// ---------------------------------------------------------------------------
// Graph setup: CSR by dst (counting sort), mean edge_attr for self loops
// ---------------------------------------------------------------------------

__global__ void count_deg_kernel(const int* __restrict__ dst, int* __restrict__ cnt) {
  int e = blockIdx.x * blockDim.x + threadIdx.x;
  if (e < EE) atomicAdd(&cnt[dst[e]], 1);
}

__global__ void scan1_kernel(const int* __restrict__ cnt, int* __restrict__ off,
                             int* __restrict__ btot) {
  __shared__ int wsum[4];
  const int b = blockIdx.x, tid = threadIdx.x;
  const int lane = tid & 63, w = tid >> 6;
  const int i = b * 256 + tid;
  int v = (i < NN) ? (cnt[i] + 1) : 0;
  int x = v;
#pragma unroll
  for (int s = 1; s < 64; s <<= 1) {
    int t = __shfl_up(x, s);
    if (lane >= s) x += t;
  }
  if (lane == 63) wsum[w] = x;
  __syncthreads();
  if (tid == 0) {
    int a = 0;
#pragma unroll
    for (int k = 0; k < 4; ++k) { int t = wsum[k]; wsum[k] = a; a += t; }
  }
  __syncthreads();
  int excl = wsum[w] + x - v;
  if (i < NN) off[i] = excl;
  if (tid == 255) btot[b] = wsum[3] + x;
}

__global__ void scan2_kernel(int* __restrict__ btot) {
  __shared__ int s0;
  const int tid = threadIdx.x, lane = tid & 63, w = tid >> 6;
  int v = (tid < NBLK) ? btot[tid] : 0;
  int x = v;
#pragma unroll
  for (int s = 1; s < 64; s <<= 1) {
    int t = __shfl_up(x, s);
    if (lane >= s) x += t;
  }
  if (w == 0 && lane == 63) s0 = x;
  __syncthreads();
  int excl = x - v + (w ? s0 : 0);
  if (tid < NBLK) btot[tid] = excl;
}

__global__ void scan3_kernel(int* __restrict__ off, const int* __restrict__ btot,
                             int* __restrict__ cursor) {
  const int i = blockIdx.x * blockDim.x + threadIdx.x;
  if (i < NN) {
    int o = off[i] + btot[i >> 8];
    off[i] = o;
    cursor[i] = o;
  }
  if (i == 0) off[NN] = EF;
}

__global__ void scatter_kernel(const int* __restrict__ src, const int* __restrict__ dst,
                               int* __restrict__ cursor, int* __restrict__ csr_src,
                               int* __restrict__ csr_dst, int* __restrict__ csr_eid) {
  int e = blockIdx.x * blockDim.x + threadIdx.x;
  if (e >= EF) return;
  int s, d;
  if (e < EE) { s = src[e]; d = dst[e]; } else { s = e - EE; d = s; }
  int pos = atomicAdd(&cursor[d], 1);
  csr_src[pos] = s;
  csr_dst[pos] = d;
  csr_eid[pos] = e;
}

__global__ __launch_bounds__(256) void mean_ea_kernel(
    const int* __restrict__ off, const int* __restrict__ csr_eid,
    const float* __restrict__ edge_attr, float* __restrict__ mean_ea) {
  const int n = (int)((blockIdx.x * blockDim.x + threadIdx.x) >> 6);
  const int lane = threadIdx.x & 63;
  if (n >= NN) return;
  const int start = off[n], end = off[n + 1];
  float a[24];
#pragma unroll
  for (int d = 0; d < 24; ++d) a[d] = 0.f;
  for (int j = start + lane; j < end; j += 64) {
    int eid = csr_eid[j];
    if (eid < EE) {
      const float* ea = edge_attr + (size_t)eid * EDIM;
      float4 q0 = *(const float4*)(ea + 0);
      float4 q1 = *(const float4*)(ea + 4);
      float4 q2 = *(const float4*)(ea + 8);
      float4 q3 = *(const float4*)(ea + 12);
      float4 q4 = *(const float4*)(ea + 16);
      float2 q5 = *(const float2*)(ea + 20);
      a[0] += q0.x; a[1] += q0.y; a[2] += q0.z; a[3] += q0.w;
      a[4] += q1.x; a[5] += q1.y; a[6] += q1.z; a[7] += q1.w;
      a[8] += q2.x; a[9] += q2.y; a[10] += q2.z; a[11] += q2.w;
      a[12] += q3.x; a[13] += q3.y; a[14] += q3.z; a[15] += q3.w;
      a[16] += q4.x; a[17] += q4.y; a[18] += q4.z; a[19] += q4.w;
      a[20] += q5.x; a[21] += q5.y;
    }
  }
#pragma unroll
  for (int s = 32; s > 0; s >>= 1)
#pragma unroll
    for (int d = 0; d < EDIM; ++d) a[d] += __shfl_xor(a[d], s);
  if (lane == 0) {
    const float den = 1.f / fmaxf((float)(end - start - 1), 1.f);
    float* mp = mean_ea + (size_t)n * EDIM;
#pragma unroll
    for (int d = 0; d < EDIM; ++d) mp[d] = a[d] * den;
  }
}

// ---------------------------------------------------------------------------
// dtype conversions
// ---------------------------------------------------------------------------

__global__ void cvt_x_kernel(const float* __restrict__ x, ushort* __restrict__ ab) {
  int t = blockIdx.x * blockDim.x + threadIdx.x;
  if (t >= NN * 32) return;
  int n = t >> 5, c = t & 31;
  ab[t] = (c < 16) ? f2b(x[n * 16 + c]) : (ushort)0;
}

__global__ void prep_weights_kernel(
    const float* __restrict__ W1, const float* __restrict__ W2, const float* __restrict__ W3,
    ushort* __restrict__ wt1, ushort* __restrict__ wt2, ushort* __restrict__ wt3,
    const float* __restrict__ We1, const float* __restrict__ ate1, float* __restrict__ wec1,
    const float* __restrict__ We2, const float* __restrict__ ate2, float* __restrict__ wec2,
    const float* __restrict__ We3, const float* __restrict__ ate3, float* __restrict__ wec3) {
  int t = blockIdx.x * blockDim.x + threadIdx.x;
  const int S0 = 256 * 32, S1 = 256 * 256, S2 = 768 * 256;
  const int S3 = EDIM * 8, S4 = EDIM * 8, S5 = EDIM * 12;
  if (t < S0) {
    int nc = t >> 5, k = t & 31;
    wt1[t] = (k < 16) ? f2b(W1[(size_t)k * 256 + nc]) : (ushort)0;
    return;
  }
  t -= S0;
  if (t < S1) {
    int nc = t >> 8, k = t & 255;
    wt2[t] = f2b(W2[(size_t)k * 256 + nc]);
    return;
  }
  t -= S1;
  if (t < S2) {
    int nc = t >> 8, k = t & 255;
    wt3[t] = f2b(W3[(size_t)k * 768 + nc]);
    return;
  }
  t -= S2;
  if (t < S3) {
    int d = t / 8, h = t % 8;
    float v = 0.f;
    for (int c = 0; c < 32; ++c) v += We1[(size_t)d * 256 + h * 32 + c] * ate1[h * 32 + c];
    wec1[t] = v;
    return;
  }
  t -= S3;
  if (t < S4) {
    int d = t / 8, h = t % 8;
    float v = 0.f;
    for (int c = 0; c < 32; ++c) v += We2[(size_t)d * 256 + h * 32 + c] * ate2[h * 32 + c];
    wec2[t] = v;
    return;
  }
  t -= S4;
  if (t < S5) {
    int d = t / 12, h = t % 12;
    float v = 0.f;
    for (int c = 0; c < 64; ++c) v += We3[(size_t)d * 768 + h * 64 + c] * ate3[h * 64 + c];
    wec3[t] = v;
  }
}

// ---------------------------------------------------------------------------
// bf16 MFMA GEMM with LDS-resident B panel.
// Block = 4 waves, BM=128 (wave: 32 rows), BN=64, full K in LDS (no dbuf).
// B panel [64 cols][K] staged once, 16B chunks XOR-swizzled (c ^= col&SWZ)
// so fragment ds_reads are ~conflict-free. A read direct from global
// (coalesced 16B/lane, 2 indep loads per k-step); 8 MFMA per k-step.
// ---------------------------------------------------------------------------
template <int K>
__global__ __launch_bounds__(256) void gemm_lds_kernel(
    const ushort* __restrict__ A, const ushort* __restrict__ Bt,
    ushort* __restrict__ C, int M, int Nc) {
  constexpr int CPC = K / 8;                       // 16B chunks per column
  constexpr int SWZ = (CPC - 1) < 7 ? (CPC - 1) : 7;
  __shared__ __align__(16) ushort Blds[64 * K];
  const int tid = threadIdx.x;
  const int lane = tid & 63;
  const int wid = tid >> 6;
  const int bn = blockIdx.x * 64;
  const int bm = blockIdx.y * 128 + wid * 32;
  const int r = lane & 15;
  const int kg = lane >> 4;

  // ---- stage B panel (reads coalesced; LDS writes swizzled) ----
#pragma unroll
  for (int it = 0; it < (64 * CPC) / 256; ++it) {
    int idx = it * 256 + tid;
    int col = idx / CPC;
    int c = idx % CPC;
    const uint4 v = *(const uint4*)(Bt + (size_t)(bn + col) * K + c * 8);
    *(uint4*)(&Blds[(col * CPC + (c ^ (col & SWZ))) * 8]) = v;
  }
  __syncthreads();

  const int row0 = bm + r, row1 = bm + 16 + r;
  const bool v0 = row0 < M, v1 = row1 < M;
  const ushort* ap0 = A + (size_t)row0 * K + kg * 8;
  const ushort* ap1 = A + (size_t)row1 * K + kg * 8;

  f32x4 acc[2][4] = {};
#pragma unroll
  for (int k0 = 0; k0 < K; k0 += 32) {
    bf16x8 a0 = {}, a1 = {};
    if (v0) a0 = *(const bf16x8*)(ap0 + k0);
    if (v1) a1 = *(const bf16x8*)(ap1 + k0);
    const int cbase = k0 / 8 + kg;
#pragma unroll
    for (int nf = 0; nf < 4; ++nf) {
      const int col = nf * 16 + r;
      bf16x8 bfr = *(const bf16x8*)(&Blds[(col * CPC + (cbase ^ (col & SWZ))) * 8]);
      acc[0][nf] = __builtin_amdgcn_mfma_f32_16x16x32_bf16(a0, bfr, acc[0][nf], 0, 0, 0);
      acc[1][nf] = __builtin_amdgcn_mfma_f32_16x16x32_bf16(a1, bfr, acc[1][nf], 0, 0, 0);
    }
  }
#pragma unroll
  for (int half = 0; half < 2; ++half)
#pragma unroll
    for (int nf = 0; nf < 4; ++nf)
#pragma unroll
      for (int reg = 0; reg < 4; ++reg) {
        int row = bm + half * 16 + kg * 4 + reg;
        if (row < M) C[(size_t)row * Nc + bn + nf * 16 + r] = f2b(acc[half][nf][reg]);
      }
}

// ---------------------------------------------------------------------------
// a_s / a_d from bf16 h
// ---------------------------------------------------------------------------
__global__ void asd_kernel(const ushort* __restrict__ h, const float* __restrict__ atts,
                           const float* __restrict__ attd, float* __restrict__ a_s,
                           float* __restrict__ a_d, int H, int C) {
  int t = blockIdx.x * blockDim.x + threadIdx.x;
  if (t >= NN * H) return;
  int n = t / H, hh = t % H;
  const ushort* row = h + (size_t)n * H * C + (size_t)hh * C;
  float s = 0.f, d = 0.f;
  for (int c = 0; c < C; c += 2) {
    unsigned u = *(const unsigned*)(row + c);
    float v0 = blo(u), v1 = bhi(u);
    s += v0 * atts[hh * C + c] + v1 * atts[hh * C + c + 1];
    d += v0 * attd[hh * C + c] + v1 * attd[hh * C + c + 1];
  }
  a_s[t] = s;
  a_d[t] = d;
}

// alpha[j,h] = leaky_relu(a_e(j) + a_s[src(j)] + a_d[dst(j)]), CSR order
__global__ void ase_kernel(const int* __restrict__ csr_eid, const int* __restrict__ csr_src,
                           const int* __restrict__ csr_dst,
                           const float* __restrict__ edge_attr, const float* __restrict__ mean_ea,
                           const float* __restrict__ wec, const float* __restrict__ a_s,
                           const float* __restrict__ a_d, float* __restrict__ alpha, int H) {
  int t = blockIdx.x * blockDim.x + threadIdx.x;
  if (t >= EF * H) return;
  int j = t / H, hh = t % H;
  int eid = csr_eid[j];
  const float* ea = (eid < EE) ? &edge_attr[(size_t)eid * EDIM]
                               : &mean_ea[(size_t)(eid - EE) * EDIM];
  float v = 0.f;
#pragma unroll
  for (int d = 0; d < EDIM; ++d) v += ea[d] * wec[d * H + hh];
  v += a_s[csr_src[j] * H + hh] + a_d[csr_dst[j] * H + hh];
  alpha[t] = lrelu(v);
}

// ---------------------------------------------------------------------------
// Single-pass fused aggregation (round-9, frozen): wave = (node, 256-chunk).
// ---------------------------------------------------------------------------
template <int H, int C, int NCH>
__global__ __launch_bounds__(256) void aggregate_kernel(
    const float* __restrict__ alpha, const ushort* __restrict__ hb,
    const int* __restrict__ off, const int* __restrict__ csr_src,
    const float* __restrict__ bias, ushort* __restrict__ xb) {
  constexpr int HC = H * C;
  constexpr int CHUNK = HC / NCH;   // 256
  constexpr int HPC = H / NCH;      // heads per chunk (8 or 4)
  constexpr int FPL = CHUNK / 64;   // 4 features per lane (divides C)
  __shared__ float wlds_all[4][64 * HPC];
  const int t = (int)((blockIdx.x * blockDim.x + threadIdx.x) >> 6);
  const int wv = threadIdx.x >> 6;
  const int lane = threadIdx.x & 63;
  const int n = t / NCH, ch = t - n * NCH;
  if (n >= NN) return;
  float* wl = wlds_all[wv];
  const int start = off[n], end = off[n + 1];
  const int h0 = ch * HPC;

  const int q = (lane * FPL) / C;
  const int f0 = ch * CHUNK + lane * FPL;
  const ushort* hrow = hb + f0;
  float acc[FPL] = {};
  float dn[HPC];
#pragma unroll
  for (int qq = 0; qq < HPC; ++qq) dn[qq] = 0.f;

  for (int t0 = start; t0 < end; t0 += 64) {
    const int m = min(64, end - t0);
    if (lane < m) {
      const float* ap = alpha + (size_t)(t0 + lane) * H + h0;
#pragma unroll
      for (int v = 0; v < HPC / 4; ++v) {
        float4 a4 = *(const float4*)(ap + v * 4);
        float4 w4;
        w4.x = __expf(a4.x);
        w4.y = __expf(a4.y);
        w4.z = __expf(a4.z);
        w4.w = __expf(a4.w);
        dn[v * 4 + 0] += w4.x;
        dn[v * 4 + 1] += w4.y;
        dn[v * 4 + 2] += w4.z;
        dn[v * 4 + 3] += w4.w;
        *(float4*)(wl + lane * HPC + v * 4) = w4;
      }
    }
    int e = 0;
    for (; e + 4 <= m; e += 4) {
      const int j = t0 + e;
      int s0 = csr_src[j], s1 = csr_src[j + 1], s2 = csr_src[j + 2], s3 = csr_src[j + 3];
      float w0 = wl[(e + 0) * HPC + q];
      float w1 = wl[(e + 1) * HPC + q];
      float w2 = wl[(e + 2) * HPC + q];
      float w3 = wl[(e + 3) * HPC + q];
      uint2 u0 = *(const uint2*)(hrow + (size_t)s0 * HC);
      uint2 u1 = *(const uint2*)(hrow + (size_t)s1 * HC);
      uint2 u2 = *(const uint2*)(hrow + (size_t)s2 * HC);
      uint2 u3 = *(const uint2*)(hrow + (size_t)s3 * HC);
      acc[0] += w0 * blo(u0.x) + w1 * blo(u1.x) + w2 * blo(u2.x) + w3 * blo(u3.x);
      acc[1] += w0 * bhi(u0.x) + w1 * bhi(u1.x) + w2 * bhi(u2.x) + w3 * bhi(u3.x);
      acc[2] += w0 * blo(u0.y) + w1 * blo(u1.y) + w2 * blo(u2.y) + w3 * blo(u3.y);
      acc[3] += w0 * bhi(u0.y) + w1 * bhi(u1.y) + w2 * bhi(u2.y) + w3 * bhi(u3.y);
    }
    for (; e < m; ++e) {
      const int j = t0 + e;
      int s0 = csr_src[j];
      float w0 = wl[e * HPC + q];
      uint2 u0 = *(const uint2*)(hrow + (size_t)s0 * HC);
      acc[0] += w0 * blo(u0.x);
      acc[1] += w0 * bhi(u0.x);
      acc[2] += w0 * blo(u0.y);
      acc[3] += w0 * bhi(u0.y);
    }
  }

#pragma unroll
  for (int s = 32; s > 0; s >>= 1)
#pragma unroll
    for (int qq = 0; qq < HPC; ++qq) dn[qq] += __shfl_xor(dn[qq], s);
  const float my_rd = 1.f / dn[q];

  ushort o[FPL];
#pragma unroll
  for (int i = 0; i < FPL; ++i) o[i] = f2b(fmaxf(acc[i] * my_rd + bias[f0 + i], 0.f));
  uint2 pk;
  pk.x = (unsigned)o[0] | ((unsigned)o[1] << 16);
  pk.y = (unsigned)o[2] | ((unsigned)o[3] << 16);
  *(uint2*)(xb + (size_t)n * HC + f0) = pk;
}

// ---------------------------------------------------------------------------
// Final head: sigmoid(concat(x1,x2,x3) @ Wf + bf), bf16 inputs. 1 wave/node.
// ---------------------------------------------------------------------------
__global__ void final_kernel(const ushort* __restrict__ x1b, const ushort* __restrict__ x2b,
                             const ushort* __restrict__ x3b, const float* __restrict__ Wf,
                             const float* __restrict__ bf, float* __restrict__ out) {
  const int wave = (int)((blockIdx.x * blockDim.x + threadIdx.x) >> 6);
  const int lane = threadIdx.x & 63;
  if (wave >= NN) return;
  float acc = 0.f;
#pragma unroll
  for (int q = 0; q < 5; ++q) {
    int f0 = (q * 64 + lane) * 4;
    const ushort* sp;
    if (f0 < 256)      sp = x1b + (size_t)wave * 256 + f0;
    else if (f0 < 512) sp = x2b + (size_t)wave * 256 + (f0 - 256);
    else               sp = x3b + (size_t)wave * 768 + (f0 - 512);
    uint2 u = *(const uint2*)sp;
    float4 wv = *(const float4*)(Wf + f0);
    acc += blo(u.x) * wv.x + bhi(u.x) * wv.y + blo(u.y) * wv.z + bhi(u.y) * wv.w;
  }
#pragma unroll
  for (int s = 32; s > 0; s >>= 1) acc += __shfl_xor(acc, s);
  if (lane == 0) out[wave] = 1.f / (1.f + __expf(-(acc + bf[0])));
}

// ---------------------------------------------------------------------------

extern "C" void kernel_launch(void* const* d_in, const int* in_sizes, int n_in,
                              void* d_out, int out_size, void* d_ws, size_t ws_size,
                              hipStream_t stream) {
  const float* x     = (const float*)d_in[0];
  const int*   eidx  = (const int*)d_in[1];
  const float* eattr = (const float*)d_in[2];
  const float* W[3]   = {(const float*)d_in[3],  (const float*)d_in[9],  (const float*)d_in[15]};
  const float* ats[3] = {(const float*)d_in[4],  (const float*)d_in[10], (const float*)d_in[16]};
  const float* atd[3] = {(const float*)d_in[5],  (const float*)d_in[11], (const float*)d_in[17]};
  const float* We[3]  = {(const float*)d_in[6],  (const float*)d_in[12], (const float*)d_in[18]};
  const float* ate[3] = {(const float*)d_in[7],  (const float*)d_in[13], (const float*)d_in[19]};
  const float* bb[3]  = {(const float*)d_in[8],  (const float*)d_in[14], (const float*)d_in[20]};
  const float* Wf = (const float*)d_in[21];
  const float* bf = (const float*)d_in[22];
  float* out = (float*)d_out;

  const int* src = eidx;
  const int* dst = eidx + EE;

  char* p = (char*)d_ws;
  auto carve = [&](size_t bytes) -> char* {
    char* q = p;
    p += (bytes + 255) & ~(size_t)255;
    return q;
  };
  ushort* x1b   = (ushort*)carve((size_t)NN * 256 * 2);
  ushort* x2b   = (ushort*)carve((size_t)NN * 256 * 2);
  ushort* x3b   = (ushort*)carve((size_t)NN * 768 * 2);
  ushort* hbuf  = (ushort*)carve((size_t)NN * 768 * 2);
  ushort* abf1  = (ushort*)carve((size_t)NN * 32 * 2);
  ushort* wt1   = (ushort*)carve((size_t)256 * 32 * 2);
  ushort* wt2   = (ushort*)carve((size_t)256 * 256 * 2);
  ushort* wt3   = (ushort*)carve((size_t)768 * 256 * 2);
  float*  a_s   = (float*)carve((size_t)NN * 12 * 4);
  float*  a_d   = (float*)carve((size_t)NN * 12 * 4);
  float*  alpha = (float*)carve((size_t)EF * 12 * 4);
  float*  mea   = (float*)carve((size_t)NN * EDIM * 4);
  float*  wec1  = (float*)carve((size_t)EDIM * 8 * 4);
  float*  wec2  = (float*)carve((size_t)EDIM * 8 * 4);
  float*  wec3  = (float*)carve((size_t)EDIM * 12 * 4);
  int* cnt      = (int*)carve((size_t)NN * 4);
  int* off      = (int*)carve((size_t)(NN + 1) * 4);
  int* btot     = (int*)carve((size_t)NBLK * 4);
  int* cursor   = (int*)carve((size_t)NN * 4);
  int* csr_src  = (int*)carve((size_t)EF * 4);
  int* csr_dst  = (int*)carve((size_t)EF * 4);
  int* csr_eid  = (int*)carve((size_t)EF * 4);

  // ---- graph structure ----
  hipMemsetAsync(cnt, 0, (size_t)NN * 4, stream);
  count_deg_kernel<<<(EE + 255) / 256, 256, 0, stream>>>(dst, cnt);
  scan1_kernel<<<NBLK, 256, 0, stream>>>(cnt, off, btot);
  scan2_kernel<<<1, 128, 0, stream>>>(btot);
  scan3_kernel<<<NBLK, 256, 0, stream>>>(off, btot, cursor);
  scatter_kernel<<<(EF + 255) / 256, 256, 0, stream>>>(src, dst, cursor, csr_src, csr_dst,
                                                       csr_eid);
  mean_ea_kernel<<<(NN * 64 + 255) / 256, 256, 0, stream>>>(off, csr_eid, eattr, mea);

  // ---- dtype prep (fused) ----
  cvt_x_kernel<<<(NN * 32 + 255) / 256, 256, 0, stream>>>(x, abf1);
  {
    const int total = 256 * 32 + 256 * 256 + 768 * 256 + EDIM * 8 + EDIM * 8 + EDIM * 12;
    prep_weights_kernel<<<(total + 255) / 256, 256, 0, stream>>>(
        W[0], W[1], W[2], wt1, wt2, wt3,
        We[0], ate[0], wec1, We[1], ate[1], wec2, We[2], ate[2], wec3);
  }

  const int Hs[3] = {8, 8, 12};
  const int Cs[3] = {32, 32, 64};
  const ushort* Ain[3] = {abf1, x1b, x2b};
  const ushort* Wt[3] = {wt1, wt2, wt3};
  float* wecL[3] = {wec1, wec2, wec3};
  ushort* xoutb[3] = {x1b, x2b, x3b};

  for (int L = 0; L < 3; ++L) {
    const int H = Hs[L], C = Cs[L], HC = H * C;
    // h = A @ Wt^T : LDS-panel MFMA GEMM, BM=128, BN=64, full-K LDS
    dim3 g(HC / 64, (NN + 127) / 128);
    if (L == 0)
      gemm_lds_kernel<32><<<g, 256, 0, stream>>>(Ain[L], Wt[L], hbuf, NN, HC);
    else
      gemm_lds_kernel<256><<<g, 256, 0, stream>>>(Ain[L], Wt[L], hbuf, NN, HC);
    asd_kernel<<<(NN * H + 255) / 256, 256, 0, stream>>>(hbuf, ats[L], atd[L], a_s, a_d, H, C);
    ase_kernel<<<(EF * H + 255) / 256, 256, 0, stream>>>(csr_eid, csr_src, csr_dst, eattr,
                                                         mea, wecL[L], a_s, a_d, alpha, H);
    if (H == 8) {
      int blocks = (NN * 1 + 3) / 4;
      aggregate_kernel<8, 32, 1><<<blocks, 256, 0, stream>>>(alpha, hbuf, off, csr_src,
                                                             bb[L], xoutb[L]);
    } else {
      int blocks = (NN * 3 + 3) / 4;
      aggregate_kernel<12, 64, 3><<<blocks, 256, 0, stream>>>(alpha, hbuf, off, csr_src,
                                                              bb[L], xoutb[L]);
    }
  }

  final_kernel<<<(NN * 64 + 255) / 256, 256, 0, stream>>>(x1b, x2b, x3b, Wf, bf, out);
}

// Round 11
// 347.635 us; speedup vs baseline: 1.5792x; 1.2150x over previous
//
#include <hip/hip_runtime.h>

#define NN 20000
#define EE 320000
#define EF 340000   /* EE + NN self loops */
#define EDIM 22
#define NBLK ((NN + 255) / 256)   /* 79 scan blocks */

typedef short bf16x8 __attribute__((ext_vector_type(8)));
typedef float f32x4 __attribute__((ext_vector_type(4)));

__device__ __forceinline__ float blo(unsigned u) {
  union { unsigned x; float f; } v; v.x = u << 16; return v.f;
}
__device__ __forceinline__ float bhi(unsigned u) {
  union { unsigned x; float f; } v; v.x = u & 0xffff0000u; return v.f;
}
__device__ __forceinline__ ushort f2b(float f) {
  union { float f; unsigned u; } v;
  v.f = f;
  unsigned u = v.u;
  return (ushort)((u + 0x7fffu + ((u >> 16) & 1u)) >> 16);  // RNE
}
__device__ __forceinline__ float lrelu(float a) { return a > 0.f ? a : 0.2f * a; }

// ---------------------------------------------------------------------------
// Graph setup: CSR by dst (counting sort), mean edge_attr for self loops
// ---------------------------------------------------------------------------

__global__ void count_deg_kernel(const int* __restrict__ dst, int* __restrict__ cnt) {
  int e = blockIdx.x * blockDim.x + threadIdx.x;
  if (e < EE) atomicAdd(&cnt[dst[e]], 1);
}

__global__ void scan1_kernel(const int* __restrict__ cnt, int* __restrict__ off,
                             int* __restrict__ btot) {
  __shared__ int wsum[4];
  const int b = blockIdx.x, tid = threadIdx.x;
  const int lane = tid & 63, w = tid >> 6;
  const int i = b * 256 + tid;
  int v = (i < NN) ? (cnt[i] + 1) : 0;
  int x = v;
#pragma unroll
  for (int s = 1; s < 64; s <<= 1) {
    int t = __shfl_up(x, s);
    if (lane >= s) x += t;
  }
  if (lane == 63) wsum[w] = x;
  __syncthreads();
  if (tid == 0) {
    int a = 0;
#pragma unroll
    for (int k = 0; k < 4; ++k) { int t = wsum[k]; wsum[k] = a; a += t; }
  }
  __syncthreads();
  int excl = wsum[w] + x - v;
  if (i < NN) off[i] = excl;
  if (tid == 255) btot[b] = wsum[3] + x;
}

__global__ void scan2_kernel(int* __restrict__ btot) {
  __shared__ int s0;
  const int tid = threadIdx.x, lane = tid & 63, w = tid >> 6;
  int v = (tid < NBLK) ? btot[tid] : 0;
  int x = v;
#pragma unroll
  for (int s = 1; s < 64; s <<= 1) {
    int t = __shfl_up(x, s);
    if (lane >= s) x += t;
  }
  if (w == 0 && lane == 63) s0 = x;
  __syncthreads();
  int excl = x - v + (w ? s0 : 0);
  if (tid < NBLK) btot[tid] = excl;
}

__global__ void scan3_kernel(int* __restrict__ off, const int* __restrict__ btot,
                             int* __restrict__ cursor) {
  const int i = blockIdx.x * blockDim.x + threadIdx.x;
  if (i < NN) {
    int o = off[i] + btot[i >> 8];
    off[i] = o;
    cursor[i] = o;
  }
  if (i == 0) off[NN] = EF;
}

__global__ void scatter_kernel(const int* __restrict__ src, const int* __restrict__ dst,
                               int* __restrict__ cursor, int* __restrict__ csr_src,
                               int* __restrict__ csr_dst, int* __restrict__ csr_eid) {
  int e = blockIdx.x * blockDim.x + threadIdx.x;
  if (e >= EF) return;
  int s, d;
  if (e < EE) { s = src[e]; d = dst[e]; } else { s = e - EE; d = s; }
  int pos = atomicAdd(&cursor[d], 1);
  csr_src[pos] = s;
  csr_dst[pos] = d;
  csr_eid[pos] = e;
}

__global__ __launch_bounds__(256) void mean_ea_kernel(
    const int* __restrict__ off, const int* __restrict__ csr_eid,
    const float* __restrict__ edge_attr, float* __restrict__ mean_ea) {
  const int n = (int)((blockIdx.x * blockDim.x + threadIdx.x) >> 6);
  const int lane = threadIdx.x & 63;
  if (n >= NN) return;
  const int start = off[n], end = off[n + 1];
  float a[24];
#pragma unroll
  for (int d = 0; d < 24; ++d) a[d] = 0.f;
  for (int j = start + lane; j < end; j += 64) {
    int eid = csr_eid[j];
    if (eid < EE) {
      const float* ea = edge_attr + (size_t)eid * EDIM;
      float4 q0 = *(const float4*)(ea + 0);
      float4 q1 = *(const float4*)(ea + 4);
      float4 q2 = *(const float4*)(ea + 8);
      float4 q3 = *(const float4*)(ea + 12);
      float4 q4 = *(const float4*)(ea + 16);
      float2 q5 = *(const float2*)(ea + 20);
      a[0] += q0.x; a[1] += q0.y; a[2] += q0.z; a[3] += q0.w;
      a[4] += q1.x; a[5] += q1.y; a[6] += q1.z; a[7] += q1.w;
      a[8] += q2.x; a[9] += q2.y; a[10] += q2.z; a[11] += q2.w;
      a[12] += q3.x; a[13] += q3.y; a[14] += q3.z; a[15] += q3.w;
      a[16] += q4.x; a[17] += q4.y; a[18] += q4.z; a[19] += q4.w;
      a[20] += q5.x; a[21] += q5.y;
    }
  }
#pragma unroll
  for (int s = 32; s > 0; s >>= 1)
#pragma unroll
    for (int d = 0; d < EDIM; ++d) a[d] += __shfl_xor(a[d], s);
  if (lane == 0) {
    const float den = 1.f / fmaxf((float)(end - start - 1), 1.f);
    float* mp = mean_ea + (size_t)n * EDIM;
#pragma unroll
    for (int d = 0; d < EDIM; ++d) mp[d] = a[d] * den;
  }
}

// ---------------------------------------------------------------------------
// dtype conversions
// ---------------------------------------------------------------------------

__global__ void cvt_x_kernel(const float* __restrict__ x, ushort* __restrict__ ab) {
  int t = blockIdx.x * blockDim.x + threadIdx.x;
  if (t >= NN * 32) return;
  int n = t >> 5, c = t & 31;
  ab[t] = (c < 16) ? f2b(x[n * 16 + c]) : (ushort)0;
}

__global__ void prep_weights_kernel(
    const float* __restrict__ W1, const float* __restrict__ W2, const float* __restrict__ W3,
    ushort* __restrict__ wt1, ushort* __restrict__ wt2, ushort* __restrict__ wt3,
    const float* __restrict__ We1, const float* __restrict__ ate1, float* __restrict__ wec1,
    const float* __restrict__ We2, const float* __restrict__ ate2, float* __restrict__ wec2,
    const float* __restrict__ We3, const float* __restrict__ ate3, float* __restrict__ wec3) {
  int t = blockIdx.x * blockDim.x + threadIdx.x;
  const int S0 = 256 * 32, S1 = 256 * 256, S2 = 768 * 256;
  const int S3 = EDIM * 8, S4 = EDIM * 8, S5 = EDIM * 12;
  if (t < S0) {
    int nc = t >> 5, k = t & 31;
    wt1[t] = (k < 16) ? f2b(W1[(size_t)k * 256 + nc]) : (ushort)0;
    return;
  }
  t -= S0;
  if (t < S1) {
    int nc = t >> 8, k = t & 255;
    wt2[t] = f2b(W2[(size_t)k * 256 + nc]);
    return;
  }
  t -= S1;
  if (t < S2) {
    int nc = t >> 8, k = t & 255;
    wt3[t] = f2b(W3[(size_t)k * 768 + nc]);
    return;
  }
  t -= S2;
  if (t < S3) {
    int d = t / 8, h = t % 8;
    float v = 0.f;
    for (int c = 0; c < 32; ++c) v += We1[(size_t)d * 256 + h * 32 + c] * ate1[h * 32 + c];
    wec1[t] = v;
    return;
  }
  t -= S3;
  if (t < S4) {
    int d = t / 8, h = t % 8;
    float v = 0.f;
    for (int c = 0; c < 32; ++c) v += We2[(size_t)d * 256 + h * 32 + c] * ate2[h * 32 + c];
    wec2[t] = v;
    return;
  }
  t -= S4;
  if (t < S5) {
    int d = t / 12, h = t % 12;
    float v = 0.f;
    for (int c = 0; c < 64; ++c) v += We3[(size_t)d * 768 + h * 64 + c] * ate3[h * 64 + c];
    wec3[t] = v;
  }
}

// ---------------------------------------------------------------------------
// bf16 MFMA GEMM with LDS-resident B panel + fused a_s/a_d epilogue.
// Block = 4 waves, BM=128 (wave: 32 rows), BN=64, full K in LDS.
// Each 64-col panel holds whole heads (CDIM=32 -> 2, CDIM=64 -> 1), so the
// a_s/a_d head-dots reduce within the wave (shfl over 16-lane groups) and
// lane r==0 writes them race-free (each (row,head) owned by exactly 1 wave).
// ---------------------------------------------------------------------------
template <int K, int CDIM>
__global__ __launch_bounds__(256) void gemm_lds_kernel(
    const ushort* __restrict__ A, const ushort* __restrict__ Bt,
    ushort* __restrict__ C, const float* __restrict__ atts,
    const float* __restrict__ attd, float* __restrict__ a_s,
    float* __restrict__ a_d, int M, int Nc, int H) {
  constexpr int CPC = K / 8;                       // 16B chunks per column
  constexpr int SWZ = (CPC - 1) < 7 ? (CPC - 1) : 7;
  __shared__ __align__(16) ushort Blds[64 * K];
  const int tid = threadIdx.x;
  const int lane = tid & 63;
  const int wid = tid >> 6;
  const int bn = blockIdx.x * 64;
  const int bm = blockIdx.y * 128 + wid * 32;
  const int r = lane & 15;
  const int kg = lane >> 4;

  // ---- stage B panel (reads coalesced; LDS writes swizzled) ----
#pragma unroll
  for (int it = 0; it < (64 * CPC) / 256; ++it) {
    int idx = it * 256 + tid;
    int col = idx / CPC;
    int c = idx % CPC;
    const uint4 v = *(const uint4*)(Bt + (size_t)(bn + col) * K + c * 8);
    *(uint4*)(&Blds[(col * CPC + (c ^ (col & SWZ))) * 8]) = v;
  }
  __syncthreads();

  const int row0 = bm + r, row1 = bm + 16 + r;
  const bool v0 = row0 < M, v1 = row1 < M;
  const ushort* ap0 = A + (size_t)row0 * K + kg * 8;
  const ushort* ap1 = A + (size_t)row1 * K + kg * 8;

  f32x4 acc[2][4] = {};
#pragma unroll
  for (int k0 = 0; k0 < K; k0 += 32) {
    bf16x8 a0 = {}, a1 = {};
    if (v0) a0 = *(const bf16x8*)(ap0 + k0);
    if (v1) a1 = *(const bf16x8*)(ap1 + k0);
    const int cbase = k0 / 8 + kg;
#pragma unroll
    for (int nf = 0; nf < 4; ++nf) {
      const int col = nf * 16 + r;
      bf16x8 bfr = *(const bf16x8*)(&Blds[(col * CPC + (cbase ^ (col & SWZ))) * 8]);
      acc[0][nf] = __builtin_amdgcn_mfma_f32_16x16x32_bf16(a0, bfr, acc[0][nf], 0, 0, 0);
      acc[1][nf] = __builtin_amdgcn_mfma_f32_16x16x32_bf16(a1, bfr, acc[1][nf], 0, 0, 0);
    }
  }
  // ---- C write ----
#pragma unroll
  for (int half = 0; half < 2; ++half)
#pragma unroll
    for (int nf = 0; nf < 4; ++nf)
#pragma unroll
      for (int reg = 0; reg < 4; ++reg) {
        int row = bm + half * 16 + kg * 4 + reg;
        if (row < M) C[(size_t)row * Nc + bn + nf * 16 + r] = f2b(acc[half][nf][reg]);
      }

  // ---- fused a_s/a_d (head dot + 16-lane reduce; lane r==0 writes) ----
  float as_v[4], ad_v[4];
#pragma unroll
  for (int nf = 0; nf < 4; ++nf) {
    int cg = bn + nf * 16 + r;
    as_v[nf] = atts[cg];
    ad_v[nf] = attd[cg];
  }
  const int h0g = bn / CDIM;
#pragma unroll
  for (int half = 0; half < 2; ++half) {
#pragma unroll
    for (int reg = 0; reg < 4; ++reg) {
      float sA, dA, sB = 0.f, dB = 0.f;
      if (CDIM == 32) {
        sA = acc[half][0][reg] * as_v[0] + acc[half][1][reg] * as_v[1];
        dA = acc[half][0][reg] * ad_v[0] + acc[half][1][reg] * ad_v[1];
        sB = acc[half][2][reg] * as_v[2] + acc[half][3][reg] * as_v[3];
        dB = acc[half][2][reg] * ad_v[2] + acc[half][3][reg] * ad_v[3];
      } else {
        sA = acc[half][0][reg] * as_v[0] + acc[half][1][reg] * as_v[1] +
             acc[half][2][reg] * as_v[2] + acc[half][3][reg] * as_v[3];
        dA = acc[half][0][reg] * ad_v[0] + acc[half][1][reg] * ad_v[1] +
             acc[half][2][reg] * ad_v[2] + acc[half][3][reg] * ad_v[3];
      }
#pragma unroll
      for (int s = 8; s >= 1; s >>= 1) {
        sA += __shfl_xor(sA, s);
        dA += __shfl_xor(dA, s);
        if (CDIM == 32) { sB += __shfl_xor(sB, s); dB += __shfl_xor(dB, s); }
      }
      if (r == 0) {
        int row = bm + half * 16 + kg * 4 + reg;
        if (row < M) {
          a_s[row * H + h0g] = sA;
          a_d[row * H + h0g] = dA;
          if (CDIM == 32) {
            a_s[row * H + h0g + 1] = sB;
            a_d[row * H + h0g + 1] = dB;
          }
        }
      }
    }
  }
}

// wexp[j,h] = exp(leaky_relu(a_e(j) + a_s[src(j)] + a_d[dst(j)])), CSR order.
// exp hoisted here (edge-parallel) so the aggregate needs no exp/LDS/shuffles.
__global__ void ase_kernel(const int* __restrict__ csr_eid, const int* __restrict__ csr_src,
                           const int* __restrict__ csr_dst,
                           const float* __restrict__ edge_attr, const float* __restrict__ mean_ea,
                           const float* __restrict__ wec, const float* __restrict__ a_s,
                           const float* __restrict__ a_d, float* __restrict__ wexp, int H) {
  int t = blockIdx.x * blockDim.x + threadIdx.x;
  if (t >= EF * H) return;
  int j = t / H, hh = t % H;
  int eid = csr_eid[j];
  const float* ea = (eid < EE) ? &edge_attr[(size_t)eid * EDIM]
                               : &mean_ea[(size_t)(eid - EE) * EDIM];
  float v = 0.f;
#pragma unroll
  for (int d = 0; d < EDIM; ++d) v += ea[d] * wec[d * H + hh];
  v += a_s[csr_src[j] * H + hh] + a_d[csr_dst[j] * H + hh];
  wexp[t] = __expf(lrelu(v));
}

// ---------------------------------------------------------------------------
// Single-pass aggregation on precomputed wexp: wave = (node, 256-chunk).
// Lane's head weight is a broadcast load; each lane sees ALL edges, so its
// private dn is the complete denominator — no LDS, no shuffles, no exp.
// Depth-4 pipelined: 4x {csr_src, w, uint2 h} loads in flight.
// ---------------------------------------------------------------------------
template <int H, int C, int NCH>
__global__ __launch_bounds__(256) void aggregate_kernel(
    const float* __restrict__ wexp, const ushort* __restrict__ hb,
    const int* __restrict__ off, const int* __restrict__ csr_src,
    const float* __restrict__ bias, ushort* __restrict__ xb) {
  constexpr int HC = H * C;
  constexpr int CHUNK = HC / NCH;   // 256
  constexpr int FPL = CHUNK / 64;   // 4 features per lane (divides C)
  const int t = (int)((blockIdx.x * blockDim.x + threadIdx.x) >> 6);
  const int lane = threadIdx.x & 63;
  const int n = t / NCH, ch = t - n * NCH;
  if (n >= NN) return;
  const int start = off[n], end = off[n + 1];
  const int f0 = ch * CHUNK + lane * FPL;
  const int qh = f0 / C;                 // lane's (global) head
  const ushort* hrow = hb + f0;
  const float* wp = wexp + qh;

  float acc[FPL] = {};
  float dn = 0.f;
  int j = start;
  for (; j + 4 <= end; j += 4) {
    int s0 = csr_src[j], s1 = csr_src[j + 1], s2 = csr_src[j + 2], s3 = csr_src[j + 3];
    float w0 = wp[(size_t)j * H];
    float w1 = wp[(size_t)(j + 1) * H];
    float w2 = wp[(size_t)(j + 2) * H];
    float w3 = wp[(size_t)(j + 3) * H];
    uint2 u0 = *(const uint2*)(hrow + (size_t)s0 * HC);
    uint2 u1 = *(const uint2*)(hrow + (size_t)s1 * HC);
    uint2 u2 = *(const uint2*)(hrow + (size_t)s2 * HC);
    uint2 u3 = *(const uint2*)(hrow + (size_t)s3 * HC);
    dn += (w0 + w1) + (w2 + w3);
    acc[0] += w0 * blo(u0.x) + w1 * blo(u1.x) + w2 * blo(u2.x) + w3 * blo(u3.x);
    acc[1] += w0 * bhi(u0.x) + w1 * bhi(u1.x) + w2 * bhi(u2.x) + w3 * bhi(u3.x);
    acc[2] += w0 * blo(u0.y) + w1 * blo(u1.y) + w2 * blo(u2.y) + w3 * blo(u3.y);
    acc[3] += w0 * bhi(u0.y) + w1 * bhi(u1.y) + w2 * bhi(u2.y) + w3 * bhi(u3.y);
  }
  for (; j < end; ++j) {
    int s0 = csr_src[j];
    float w0 = wp[(size_t)j * H];
    uint2 u0 = *(const uint2*)(hrow + (size_t)s0 * HC);
    dn += w0;
    acc[0] += w0 * blo(u0.x);
    acc[1] += w0 * bhi(u0.x);
    acc[2] += w0 * blo(u0.y);
    acc[3] += w0 * bhi(u0.y);
  }

  const float my_rd = 1.f / dn;
  ushort o[FPL];
#pragma unroll
  for (int i = 0; i < FPL; ++i) o[i] = f2b(fmaxf(acc[i] * my_rd + bias[f0 + i], 0.f));
  uint2 pk;
  pk.x = (unsigned)o[0] | ((unsigned)o[1] << 16);
  pk.y = (unsigned)o[2] | ((unsigned)o[3] << 16);
  *(uint2*)(xb + (size_t)n * HC + f0) = pk;
}

// ---------------------------------------------------------------------------
// Final head: sigmoid(concat(x1,x2,x3) @ Wf + bf), bf16 inputs. 1 wave/node.
// ---------------------------------------------------------------------------
__global__ void final_kernel(const ushort* __restrict__ x1b, const ushort* __restrict__ x2b,
                             const ushort* __restrict__ x3b, const float* __restrict__ Wf,
                             const float* __restrict__ bf, float* __restrict__ out) {
  const int wave = (int)((blockIdx.x * blockDim.x + threadIdx.x) >> 6);
  const int lane = threadIdx.x & 63;
  if (wave >= NN) return;
  float acc = 0.f;
#pragma unroll
  for (int q = 0; q < 5; ++q) {
    int f0 = (q * 64 + lane) * 4;
    const ushort* sp;
    if (f0 < 256)      sp = x1b + (size_t)wave * 256 + f0;
    else if (f0 < 512) sp = x2b + (size_t)wave * 256 + (f0 - 256);
    else               sp = x3b + (size_t)wave * 768 + (f0 - 512);
    uint2 u = *(const uint2*)sp;
    float4 wv = *(const float4*)(Wf + f0);
    acc += blo(u.x) * wv.x + bhi(u.x) * wv.y + blo(u.y) * wv.z + bhi(u.y) * wv.w;
  }
#pragma unroll
  for (int s = 32; s > 0; s >>= 1) acc += __shfl_xor(acc, s);
  if (lane == 0) out[wave] = 1.f / (1.f + __expf(-(acc + bf[0])));
}

// ---------------------------------------------------------------------------

extern "C" void kernel_launch(void* const* d_in, const int* in_sizes, int n_in,
                              void* d_out, int out_size, void* d_ws, size_t ws_size,
                              hipStream_t stream) {
  const float* x     = (const float*)d_in[0];
  const int*   eidx  = (const int*)d_in[1];
  const float* eattr = (const float*)d_in[2];
  const float* W[3]   = {(const float*)d_in[3],  (const float*)d_in[9],  (const float*)d_in[15]};
  const float* ats[3] = {(const float*)d_in[4],  (const float*)d_in[10], (const float*)d_in[16]};
  const float* atd[3] = {(const float*)d_in[5],  (const float*)d_in[11], (const float*)d_in[17]};
  const float* We[3]  = {(const float*)d_in[6],  (const float*)d_in[12], (const float*)d_in[18]};
  const float* ate[3] = {(const float*)d_in[7],  (const float*)d_in[13], (const float*)d_in[19]};
  const float* bb[3]  = {(const float*)d_in[8],  (const float*)d_in[14], (const float*)d_in[20]};
  const float* Wf = (const float*)d_in[21];
  const float* bf = (const float*)d_in[22];
  float* out = (float*)d_out;

  const int* src = eidx;
  const int* dst = eidx + EE;

  char* p = (char*)d_ws;
  auto carve = [&](size_t bytes) -> char* {
    char* q = p;
    p += (bytes + 255) & ~(size_t)255;
    return q;
  };
  ushort* x1b   = (ushort*)carve((size_t)NN * 256 * 2);
  ushort* x2b   = (ushort*)carve((size_t)NN * 256 * 2);
  ushort* x3b   = (ushort*)carve((size_t)NN * 768 * 2);
  ushort* hbuf  = (ushort*)carve((size_t)NN * 768 * 2);
  ushort* abf1  = (ushort*)carve((size_t)NN * 32 * 2);
  ushort* wt1   = (ushort*)carve((size_t)256 * 32 * 2);
  ushort* wt2   = (ushort*)carve((size_t)256 * 256 * 2);
  ushort* wt3   = (ushort*)carve((size_t)768 * 256 * 2);
  float*  a_s   = (float*)carve((size_t)NN * 12 * 4);
  float*  a_d   = (float*)carve((size_t)NN * 12 * 4);
  float*  wexp  = (float*)carve((size_t)EF * 12 * 4);
  float*  mea   = (float*)carve((size_t)NN * EDIM * 4);
  float*  wec1  = (float*)carve((size_t)EDIM * 8 * 4);
  float*  wec2  = (float*)carve((size_t)EDIM * 8 * 4);
  float*  wec3  = (float*)carve((size_t)EDIM * 12 * 4);
  int* cnt      = (int*)carve((size_t)NN * 4);
  int* off      = (int*)carve((size_t)(NN + 1) * 4);
  int* btot     = (int*)carve((size_t)NBLK * 4);
  int* cursor   = (int*)carve((size_t)NN * 4);
  int* csr_src  = (int*)carve((size_t)EF * 4);
  int* csr_dst  = (int*)carve((size_t)EF * 4);
  int* csr_eid  = (int*)carve((size_t)EF * 4);

  // ---- graph structure ----
  hipMemsetAsync(cnt, 0, (size_t)NN * 4, stream);
  count_deg_kernel<<<(EE + 255) / 256, 256, 0, stream>>>(dst, cnt);
  scan1_kernel<<<NBLK, 256, 0, stream>>>(cnt, off, btot);
  scan2_kernel<<<1, 128, 0, stream>>>(btot);
  scan3_kernel<<<NBLK, 256, 0, stream>>>(off, btot, cursor);
  scatter_kernel<<<(EF + 255) / 256, 256, 0, stream>>>(src, dst, cursor, csr_src, csr_dst,
                                                       csr_eid);
  mean_ea_kernel<<<(NN * 64 + 255) / 256, 256, 0, stream>>>(off, csr_eid, eattr, mea);

  // ---- dtype prep (fused) ----
  cvt_x_kernel<<<(NN * 32 + 255) / 256, 256, 0, stream>>>(x, abf1);
  {
    const int total = 256 * 32 + 256 * 256 + 768 * 256 + EDIM * 8 + EDIM * 8 + EDIM * 12;
    prep_weights_kernel<<<(total + 255) / 256, 256, 0, stream>>>(
        W[0], W[1], W[2], wt1, wt2, wt3,
        We[0], ate[0], wec1, We[1], ate[1], wec2, We[2], ate[2], wec3);
  }

  const int Hs[3] = {8, 8, 12};
  const ushort* Ain[3] = {abf1, x1b, x2b};
  const ushort* Wt[3] = {wt1, wt2, wt3};
  float* wecL[3] = {wec1, wec2, wec3};
  ushort* xoutb[3] = {x1b, x2b, x3b};

  for (int L = 0; L < 3; ++L) {
    const int H = Hs[L];
    const int HC = (L < 2) ? 256 : 768;
    // h = A @ Wt^T + fused a_s/a_d epilogue
    dim3 g(HC / 64, (NN + 127) / 128);
    if (L == 0)
      gemm_lds_kernel<32, 32><<<g, 256, 0, stream>>>(Ain[L], Wt[L], hbuf, ats[L], atd[L],
                                                     a_s, a_d, NN, HC, H);
    else if (L == 1)
      gemm_lds_kernel<256, 32><<<g, 256, 0, stream>>>(Ain[L], Wt[L], hbuf, ats[L], atd[L],
                                                      a_s, a_d, NN, HC, H);
    else
      gemm_lds_kernel<256, 64><<<g, 256, 0, stream>>>(Ain[L], Wt[L], hbuf, ats[L], atd[L],
                                                      a_s, a_d, NN, HC, H);
    // per-edge exp(leaky(alpha)) — exp hoisted out of the aggregate
    ase_kernel<<<(EF * H + 255) / 256, 256, 0, stream>>>(csr_eid, csr_src, csr_dst, eattr,
                                                         mea, wecL[L], a_s, a_d, wexp, H);
    // single-pass gather (no LDS / no shuffles / no exp)
    if (H == 8) {
      int blocks = (NN * 1 + 3) / 4;
      aggregate_kernel<8, 32, 1><<<blocks, 256, 0, stream>>>(wexp, hbuf, off, csr_src,
                                                             bb[L], xoutb[L]);
    } else {
      int blocks = (NN * 3 + 3) / 4;
      aggregate_kernel<12, 64, 3><<<blocks, 256, 0, stream>>>(wexp, hbuf, off, csr_src,
                                                              bb[L], xoutb[L]);
    }
  }

  final_kernel<<<(NN * 64 + 255) / 256, 256, 0, stream>>>(x1b, x2b, x3b, Wf, bf, out);
}

// Round 12
// 342.096 us; speedup vs baseline: 1.6048x; 1.0162x over previous
//
#include <hip/hip_runtime.h>

#define NN 20000
#define EE 320000
#define EF 340000   /* EE + NN self loops */
#define EDIM 22
#define NBLK ((NN + 255) / 256)   /* 79 scan blocks */

typedef short bf16x8 __attribute__((ext_vector_type(8)));
typedef float f32x4 __attribute__((ext_vector_type(4)));

__device__ __forceinline__ float blo(unsigned u) {
  union { unsigned x; float f; } v; v.x = u << 16; return v.f;
}
__device__ __forceinline__ float bhi(unsigned u) {
  union { unsigned x; float f; } v; v.x = u & 0xffff0000u; return v.f;
}
__device__ __forceinline__ ushort f2b(float f) {
  union { float f; unsigned u; } v;
  v.f = f;
  unsigned u = v.u;
  return (ushort)((u + 0x7fffu + ((u >> 16) & 1u)) >> 16);  // RNE
}
__device__ __forceinline__ float lrelu(float a) { return a > 0.f ? a : 0.2f * a; }

// ---------------------------------------------------------------------------
// Graph setup: CSR by dst (counting sort), mean edge_attr for self loops
// ---------------------------------------------------------------------------

__global__ void count_deg_kernel(const int* __restrict__ dst, int* __restrict__ cnt) {
  int e = blockIdx.x * blockDim.x + threadIdx.x;
  if (e < EE) atomicAdd(&cnt[dst[e]], 1);
}

__global__ void scan1_kernel(const int* __restrict__ cnt, int* __restrict__ off,
                             int* __restrict__ btot) {
  __shared__ int wsum[4];
  const int b = blockIdx.x, tid = threadIdx.x;
  const int lane = tid & 63, w = tid >> 6;
  const int i = b * 256 + tid;
  int v = (i < NN) ? (cnt[i] + 1) : 0;
  int x = v;
#pragma unroll
  for (int s = 1; s < 64; s <<= 1) {
    int t = __shfl_up(x, s);
    if (lane >= s) x += t;
  }
  if (lane == 63) wsum[w] = x;
  __syncthreads();
  if (tid == 0) {
    int a = 0;
#pragma unroll
    for (int k = 0; k < 4; ++k) { int t = wsum[k]; wsum[k] = a; a += t; }
  }
  __syncthreads();
  int excl = wsum[w] + x - v;
  if (i < NN) off[i] = excl;
  if (tid == 255) btot[b] = wsum[3] + x;
}

__global__ void scan2_kernel(int* __restrict__ btot) {
  __shared__ int s0;
  const int tid = threadIdx.x, lane = tid & 63, w = tid >> 6;
  int v = (tid < NBLK) ? btot[tid] : 0;
  int x = v;
#pragma unroll
  for (int s = 1; s < 64; s <<= 1) {
    int t = __shfl_up(x, s);
    if (lane >= s) x += t;
  }
  if (w == 0 && lane == 63) s0 = x;
  __syncthreads();
  int excl = x - v + (w ? s0 : 0);
  if (tid < NBLK) btot[tid] = excl;
}

__global__ void scan3_kernel(int* __restrict__ off, const int* __restrict__ btot,
                             int* __restrict__ cursor) {
  const int i = blockIdx.x * blockDim.x + threadIdx.x;
  if (i < NN) {
    int o = off[i] + btot[i >> 8];
    off[i] = o;
    cursor[i] = o;
  }
  if (i == 0) off[NN] = EF;
}

__global__ void scatter_kernel(const int* __restrict__ src, const int* __restrict__ dst,
                               int* __restrict__ cursor, int* __restrict__ csr_src,
                               int* __restrict__ csr_dst, int* __restrict__ csr_eid) {
  int e = blockIdx.x * blockDim.x + threadIdx.x;
  if (e >= EF) return;
  int s, d;
  if (e < EE) { s = src[e]; d = dst[e]; } else { s = e - EE; d = s; }
  int pos = atomicAdd(&cursor[d], 1);
  csr_src[pos] = s;
  csr_dst[pos] = d;
  csr_eid[pos] = e;
}

__global__ __launch_bounds__(256) void mean_ea_kernel(
    const int* __restrict__ off, const int* __restrict__ csr_eid,
    const float* __restrict__ edge_attr, float* __restrict__ mean_ea) {
  const int n = (int)((blockIdx.x * blockDim.x + threadIdx.x) >> 6);
  const int lane = threadIdx.x & 63;
  if (n >= NN) return;
  const int start = off[n], end = off[n + 1];
  float a[24];
#pragma unroll
  for (int d = 0; d < 24; ++d) a[d] = 0.f;
  for (int j = start + lane; j < end; j += 64) {
    int eid = csr_eid[j];
    if (eid < EE) {
      const float* ea = edge_attr + (size_t)eid * EDIM;
      float4 q0 = *(const float4*)(ea + 0);
      float4 q1 = *(const float4*)(ea + 4);
      float4 q2 = *(const float4*)(ea + 8);
      float4 q3 = *(const float4*)(ea + 12);
      float4 q4 = *(const float4*)(ea + 16);
      float2 q5 = *(const float2*)(ea + 20);
      a[0] += q0.x; a[1] += q0.y; a[2] += q0.z; a[3] += q0.w;
      a[4] += q1.x; a[5] += q1.y; a[6] += q1.z; a[7] += q1.w;
      a[8] += q2.x; a[9] += q2.y; a[10] += q2.z; a[11] += q2.w;
      a[12] += q3.x; a[13] += q3.y; a[14] += q3.z; a[15] += q3.w;
      a[16] += q4.x; a[17] += q4.y; a[18] += q4.z; a[19] += q4.w;
      a[20] += q5.x; a[21] += q5.y;
    }
  }
#pragma unroll
  for (int s = 32; s > 0; s >>= 1)
#pragma unroll
    for (int d = 0; d < EDIM; ++d) a[d] += __shfl_xor(a[d], s);
  if (lane == 0) {
    const float den = 1.f / fmaxf((float)(end - start - 1), 1.f);
    float* mp = mean_ea + (size_t)n * EDIM;
#pragma unroll
    for (int d = 0; d < EDIM; ++d) mp[d] = a[d] * den;
  }
}

// ea_csr[j][22] (bf16) = edge_attr row (or self-loop mean) in CSR order.
// Removes the csr_eid indirection + f32 reads from all three ase passes.
__global__ void ea_csr_kernel(const int* __restrict__ csr_eid,
                              const float* __restrict__ edge_attr,
                              const float* __restrict__ mean_ea,
                              ushort* __restrict__ ea_csr) {
  int t = blockIdx.x * blockDim.x + threadIdx.x;
  if (t >= EF * 11) return;
  int j = t / 11, dp = t % 11;
  int eid = csr_eid[j];
  const float* ea = (eid < EE) ? edge_attr + (size_t)eid * EDIM
                               : mean_ea + (size_t)(eid - EE) * EDIM;
  float2 v = *(const float2*)(ea + dp * 2);
  unsigned u = (unsigned)f2b(v.x) | ((unsigned)f2b(v.y) << 16);
  *(unsigned*)(ea_csr + (size_t)j * EDIM + dp * 2) = u;
}

// ---------------------------------------------------------------------------
// dtype conversions
// ---------------------------------------------------------------------------

__global__ void cvt_x_kernel(const float* __restrict__ x, ushort* __restrict__ ab) {
  int t = blockIdx.x * blockDim.x + threadIdx.x;
  if (t >= NN * 32) return;
  int n = t >> 5, c = t & 31;
  ab[t] = (c < 16) ? f2b(x[n * 16 + c]) : (ushort)0;
}

__global__ void prep_weights_kernel(
    const float* __restrict__ W1, const float* __restrict__ W2, const float* __restrict__ W3,
    ushort* __restrict__ wt1, ushort* __restrict__ wt2, ushort* __restrict__ wt3,
    const float* __restrict__ We1, const float* __restrict__ ate1, float* __restrict__ wec1,
    const float* __restrict__ We2, const float* __restrict__ ate2, float* __restrict__ wec2,
    const float* __restrict__ We3, const float* __restrict__ ate3, float* __restrict__ wec3) {
  int t = blockIdx.x * blockDim.x + threadIdx.x;
  const int S0 = 256 * 32, S1 = 256 * 256, S2 = 768 * 256;
  const int S3 = EDIM * 8, S4 = EDIM * 8, S5 = EDIM * 12;
  if (t < S0) {
    int nc = t >> 5, k = t & 31;
    wt1[t] = (k < 16) ? f2b(W1[(size_t)k * 256 + nc]) : (ushort)0;
    return;
  }
  t -= S0;
  if (t < S1) {
    int nc = t >> 8, k = t & 255;
    wt2[t] = f2b(W2[(size_t)k * 256 + nc]);
    return;
  }
  t -= S1;
  if (t < S2) {
    int nc = t >> 8, k = t & 255;
    wt3[t] = f2b(W3[(size_t)k * 768 + nc]);
    return;
  }
  t -= S2;
  if (t < S3) {
    int d = t / 8, h = t % 8;
    float v = 0.f;
    for (int c = 0; c < 32; ++c) v += We1[(size_t)d * 256 + h * 32 + c] * ate1[h * 32 + c];
    wec1[t] = v;
    return;
  }
  t -= S3;
  if (t < S4) {
    int d = t / 8, h = t % 8;
    float v = 0.f;
    for (int c = 0; c < 32; ++c) v += We2[(size_t)d * 256 + h * 32 + c] * ate2[h * 32 + c];
    wec2[t] = v;
    return;
  }
  t -= S4;
  if (t < S5) {
    int d = t / 12, h = t % 12;
    float v = 0.f;
    for (int c = 0; c < 64; ++c) v += We3[(size_t)d * 768 + h * 64 + c] * ate3[h * 64 + c];
    wec3[t] = v;
  }
}

// ---------------------------------------------------------------------------
// bf16 MFMA GEMM with LDS-resident B panel + fused a_s/a_d epilogue (frozen).
// ---------------------------------------------------------------------------
template <int K, int CDIM>
__global__ __launch_bounds__(256) void gemm_lds_kernel(
    const ushort* __restrict__ A, const ushort* __restrict__ Bt,
    ushort* __restrict__ C, const float* __restrict__ atts,
    const float* __restrict__ attd, float* __restrict__ a_s,
    float* __restrict__ a_d, int M, int Nc, int H) {
  constexpr int CPC = K / 8;                       // 16B chunks per column
  constexpr int SWZ = (CPC - 1) < 7 ? (CPC - 1) : 7;
  __shared__ __align__(16) ushort Blds[64 * K];
  const int tid = threadIdx.x;
  const int lane = tid & 63;
  const int wid = tid >> 6;
  const int bn = blockIdx.x * 64;
  const int bm = blockIdx.y * 128 + wid * 32;
  const int r = lane & 15;
  const int kg = lane >> 4;

#pragma unroll
  for (int it = 0; it < (64 * CPC) / 256; ++it) {
    int idx = it * 256 + tid;
    int col = idx / CPC;
    int c = idx % CPC;
    const uint4 v = *(const uint4*)(Bt + (size_t)(bn + col) * K + c * 8);
    *(uint4*)(&Blds[(col * CPC + (c ^ (col & SWZ))) * 8]) = v;
  }
  __syncthreads();

  const int row0 = bm + r, row1 = bm + 16 + r;
  const bool v0 = row0 < M, v1 = row1 < M;
  const ushort* ap0 = A + (size_t)row0 * K + kg * 8;
  const ushort* ap1 = A + (size_t)row1 * K + kg * 8;

  f32x4 acc[2][4] = {};
#pragma unroll
  for (int k0 = 0; k0 < K; k0 += 32) {
    bf16x8 a0 = {}, a1 = {};
    if (v0) a0 = *(const bf16x8*)(ap0 + k0);
    if (v1) a1 = *(const bf16x8*)(ap1 + k0);
    const int cbase = k0 / 8 + kg;
#pragma unroll
    for (int nf = 0; nf < 4; ++nf) {
      const int col = nf * 16 + r;
      bf16x8 bfr = *(const bf16x8*)(&Blds[(col * CPC + (cbase ^ (col & SWZ))) * 8]);
      acc[0][nf] = __builtin_amdgcn_mfma_f32_16x16x32_bf16(a0, bfr, acc[0][nf], 0, 0, 0);
      acc[1][nf] = __builtin_amdgcn_mfma_f32_16x16x32_bf16(a1, bfr, acc[1][nf], 0, 0, 0);
    }
  }
#pragma unroll
  for (int half = 0; half < 2; ++half)
#pragma unroll
    for (int nf = 0; nf < 4; ++nf)
#pragma unroll
      for (int reg = 0; reg < 4; ++reg) {
        int row = bm + half * 16 + kg * 4 + reg;
        if (row < M) C[(size_t)row * Nc + bn + nf * 16 + r] = f2b(acc[half][nf][reg]);
      }

  float as_v[4], ad_v[4];
#pragma unroll
  for (int nf = 0; nf < 4; ++nf) {
    int cg = bn + nf * 16 + r;
    as_v[nf] = atts[cg];
    ad_v[nf] = attd[cg];
  }
  const int h0g = bn / CDIM;
#pragma unroll
  for (int half = 0; half < 2; ++half) {
#pragma unroll
    for (int reg = 0; reg < 4; ++reg) {
      float sA, dA, sB = 0.f, dB = 0.f;
      if (CDIM == 32) {
        sA = acc[half][0][reg] * as_v[0] + acc[half][1][reg] * as_v[1];
        dA = acc[half][0][reg] * ad_v[0] + acc[half][1][reg] * ad_v[1];
        sB = acc[half][2][reg] * as_v[2] + acc[half][3][reg] * as_v[3];
        dB = acc[half][2][reg] * ad_v[2] + acc[half][3][reg] * ad_v[3];
      } else {
        sA = acc[half][0][reg] * as_v[0] + acc[half][1][reg] * as_v[1] +
             acc[half][2][reg] * as_v[2] + acc[half][3][reg] * as_v[3];
        dA = acc[half][0][reg] * ad_v[0] + acc[half][1][reg] * ad_v[1] +
             acc[half][2][reg] * ad_v[2] + acc[half][3][reg] * ad_v[3];
      }
#pragma unroll
      for (int s = 8; s >= 1; s >>= 1) {
        sA += __shfl_xor(sA, s);
        dA += __shfl_xor(dA, s);
        if (CDIM == 32) { sB += __shfl_xor(sB, s); dB += __shfl_xor(dB, s); }
      }
      if (r == 0) {
        int row = bm + half * 16 + kg * 4 + reg;
        if (row < M) {
          a_s[row * H + h0g] = sA;
          a_d[row * H + h0g] = dA;
          if (CDIM == 32) {
            a_s[row * H + h0g + 1] = sB;
            a_d[row * H + h0g + 1] = dB;
          }
        }
      }
    }
  }
}

// wexp[j,h] = exp(leaky_relu(a_e(j) + a_s[src(j)] + a_d[dst(j)])); ea from
// bf16 CSR-ordered ea_csr (sequential, no indirection, no mean branch).
__global__ void ase_kernel(const int* __restrict__ csr_src, const int* __restrict__ csr_dst,
                           const ushort* __restrict__ ea_csr, const float* __restrict__ wec,
                           const float* __restrict__ a_s, const float* __restrict__ a_d,
                           float* __restrict__ wexp, int H) {
  int t = blockIdx.x * blockDim.x + threadIdx.x;
  if (t >= EF * H) return;
  int j = t / H, hh = t % H;
  const ushort* ea = ea_csr + (size_t)j * EDIM;
  float v = 0.f;
#pragma unroll
  for (int d = 0; d < 11; ++d) {
    unsigned u = *(const unsigned*)(ea + 2 * d);
    v += blo(u) * wec[(2 * d) * H + hh] + bhi(u) * wec[(2 * d + 1) * H + hh];
  }
  v += a_s[csr_src[j] * H + hh] + a_d[csr_dst[j] * H + hh];
  wexp[t] = __expf(lrelu(v));
}

// ---------------------------------------------------------------------------
// Single-pass aggregation on precomputed wexp + fused final-head partial dot.
// Wave = (node, 256-chunk). Lane's head weight is a broadcast load; private
// dn is the complete denominator. After normalize+bias+relu, each wave dots
// its 256 features with the matching Wf slice and writes logitpart[n*5+slot]
// (deterministic, no atomics). WRITE_X=false skips the x store (layer 3:
// x3 only feeds the final head, now fused).
// ---------------------------------------------------------------------------
template <int H, int C, int NCH, bool WRITE_X>
__global__ __launch_bounds__(256) void aggregate_kernel(
    const float* __restrict__ wexp, const ushort* __restrict__ hb,
    const int* __restrict__ off, const int* __restrict__ csr_src,
    const float* __restrict__ bias, ushort* __restrict__ xb,
    const float* __restrict__ WfL, float* __restrict__ logitpart, int slotbase) {
  constexpr int HC = H * C;
  constexpr int CHUNK = HC / NCH;   // 256
  constexpr int FPL = CHUNK / 64;   // 4 features per lane (divides C)
  const int t = (int)((blockIdx.x * blockDim.x + threadIdx.x) >> 6);
  const int lane = threadIdx.x & 63;
  const int n = t / NCH, ch = t - n * NCH;
  if (n >= NN) return;
  const int start = off[n], end = off[n + 1];
  const int f0 = ch * CHUNK + lane * FPL;
  const int qh = f0 / C;                 // lane's (global) head
  const ushort* hrow = hb + f0;
  const float* wp = wexp + qh;

  float acc[FPL] = {};
  float dn = 0.f;
  int j = start;
  for (; j + 4 <= end; j += 4) {
    int s0 = csr_src[j], s1 = csr_src[j + 1], s2 = csr_src[j + 2], s3 = csr_src[j + 3];
    float w0 = wp[(size_t)j * H];
    float w1 = wp[(size_t)(j + 1) * H];
    float w2 = wp[(size_t)(j + 2) * H];
    float w3 = wp[(size_t)(j + 3) * H];
    uint2 u0 = *(const uint2*)(hrow + (size_t)s0 * HC);
    uint2 u1 = *(const uint2*)(hrow + (size_t)s1 * HC);
    uint2 u2 = *(const uint2*)(hrow + (size_t)s2 * HC);
    uint2 u3 = *(const uint2*)(hrow + (size_t)s3 * HC);
    dn += (w0 + w1) + (w2 + w3);
    acc[0] += w0 * blo(u0.x) + w1 * blo(u1.x) + w2 * blo(u2.x) + w3 * blo(u3.x);
    acc[1] += w0 * bhi(u0.x) + w1 * bhi(u1.x) + w2 * bhi(u2.x) + w3 * bhi(u3.x);
    acc[2] += w0 * blo(u0.y) + w1 * blo(u1.y) + w2 * blo(u2.y) + w3 * blo(u3.y);
    acc[3] += w0 * bhi(u0.y) + w1 * bhi(u1.y) + w2 * bhi(u2.y) + w3 * bhi(u3.y);
  }
  for (; j < end; ++j) {
    int s0 = csr_src[j];
    float w0 = wp[(size_t)j * H];
    uint2 u0 = *(const uint2*)(hrow + (size_t)s0 * HC);
    dn += w0;
    acc[0] += w0 * blo(u0.x);
    acc[1] += w0 * bhi(u0.x);
    acc[2] += w0 * blo(u0.y);
    acc[3] += w0 * bhi(u0.y);
  }

  const float my_rd = 1.f / dn;
  const float4 wf4 = *(const float4*)(WfL + f0);
  const float wfv[4] = {wf4.x, wf4.y, wf4.z, wf4.w};
  float o[FPL];
  float partial = 0.f;
#pragma unroll
  for (int i = 0; i < FPL; ++i) {
    o[i] = fmaxf(acc[i] * my_rd + bias[f0 + i], 0.f);
    partial += o[i] * wfv[i];
  }
  if (WRITE_X) {
    uint2 pk;
    pk.x = (unsigned)f2b(o[0]) | ((unsigned)f2b(o[1]) << 16);
    pk.y = (unsigned)f2b(o[2]) | ((unsigned)f2b(o[3]) << 16);
    *(uint2*)(xb + (size_t)n * HC + f0) = pk;
  }
#pragma unroll
  for (int s = 32; s > 0; s >>= 1) partial += __shfl_xor(partial, s);
  if (lane == 0) logitpart[n * 5 + slotbase + ch] = partial;
}

// sigmoid over the 5 per-node logit partials
__global__ void final_sigmoid_kernel(const float* __restrict__ logitpart,
                                     const float* __restrict__ bf,
                                     float* __restrict__ out) {
  int n = blockIdx.x * blockDim.x + threadIdx.x;
  if (n >= NN) return;
  const float* lp = logitpart + n * 5;
  float s = lp[0] + lp[1] + lp[2] + lp[3] + lp[4] + bf[0];
  out[n] = 1.f / (1.f + __expf(-s));
}

// ---------------------------------------------------------------------------

extern "C" void kernel_launch(void* const* d_in, const int* in_sizes, int n_in,
                              void* d_out, int out_size, void* d_ws, size_t ws_size,
                              hipStream_t stream) {
  const float* x     = (const float*)d_in[0];
  const int*   eidx  = (const int*)d_in[1];
  const float* eattr = (const float*)d_in[2];
  const float* W[3]   = {(const float*)d_in[3],  (const float*)d_in[9],  (const float*)d_in[15]};
  const float* ats[3] = {(const float*)d_in[4],  (const float*)d_in[10], (const float*)d_in[16]};
  const float* atd[3] = {(const float*)d_in[5],  (const float*)d_in[11], (const float*)d_in[17]};
  const float* We[3]  = {(const float*)d_in[6],  (const float*)d_in[12], (const float*)d_in[18]};
  const float* ate[3] = {(const float*)d_in[7],  (const float*)d_in[13], (const float*)d_in[19]};
  const float* bb[3]  = {(const float*)d_in[8],  (const float*)d_in[14], (const float*)d_in[20]};
  const float* Wf = (const float*)d_in[21];
  const float* bf = (const float*)d_in[22];
  float* out = (float*)d_out;

  const int* src = eidx;
  const int* dst = eidx + EE;

  char* p = (char*)d_ws;
  auto carve = [&](size_t bytes) -> char* {
    char* q = p;
    p += (bytes + 255) & ~(size_t)255;
    return q;
  };
  ushort* x1b    = (ushort*)carve((size_t)NN * 256 * 2);
  ushort* x2b    = (ushort*)carve((size_t)NN * 256 * 2);
  ushort* hbuf   = (ushort*)carve((size_t)NN * 768 * 2);
  ushort* abf1   = (ushort*)carve((size_t)NN * 32 * 2);
  ushort* wt1    = (ushort*)carve((size_t)256 * 32 * 2);
  ushort* wt2    = (ushort*)carve((size_t)256 * 256 * 2);
  ushort* wt3    = (ushort*)carve((size_t)768 * 256 * 2);
  ushort* ea_csr = (ushort*)carve((size_t)EF * EDIM * 2);
  float*  a_s    = (float*)carve((size_t)NN * 12 * 4);
  float*  a_d    = (float*)carve((size_t)NN * 12 * 4);
  float*  wexp   = (float*)carve((size_t)EF * 12 * 4);
  float*  mea    = (float*)carve((size_t)NN * EDIM * 4);
  float*  wec1   = (float*)carve((size_t)EDIM * 8 * 4);
  float*  wec2   = (float*)carve((size_t)EDIM * 8 * 4);
  float*  wec3   = (float*)carve((size_t)EDIM * 12 * 4);
  float*  lpart  = (float*)carve((size_t)NN * 5 * 4);
  int* cnt       = (int*)carve((size_t)NN * 4);
  int* off       = (int*)carve((size_t)(NN + 1) * 4);
  int* btot      = (int*)carve((size_t)NBLK * 4);
  int* cursor    = (int*)carve((size_t)NN * 4);
  int* csr_src   = (int*)carve((size_t)EF * 4);
  int* csr_dst   = (int*)carve((size_t)EF * 4);
  int* csr_eid   = (int*)carve((size_t)EF * 4);

  // ---- graph structure ----
  hipMemsetAsync(cnt, 0, (size_t)NN * 4, stream);
  count_deg_kernel<<<(EE + 255) / 256, 256, 0, stream>>>(dst, cnt);
  scan1_kernel<<<NBLK, 256, 0, stream>>>(cnt, off, btot);
  scan2_kernel<<<1, 128, 0, stream>>>(btot);
  scan3_kernel<<<NBLK, 256, 0, stream>>>(off, btot, cursor);
  scatter_kernel<<<(EF + 255) / 256, 256, 0, stream>>>(src, dst, cursor, csr_src, csr_dst,
                                                       csr_eid);
  mean_ea_kernel<<<(NN * 64 + 255) / 256, 256, 0, stream>>>(off, csr_eid, eattr, mea);
  ea_csr_kernel<<<(EF * 11 + 255) / 256, 256, 0, stream>>>(csr_eid, eattr, mea, ea_csr);

  // ---- dtype prep ----
  cvt_x_kernel<<<(NN * 32 + 255) / 256, 256, 0, stream>>>(x, abf1);
  {
    const int total = 256 * 32 + 256 * 256 + 768 * 256 + EDIM * 8 + EDIM * 8 + EDIM * 12;
    prep_weights_kernel<<<(total + 255) / 256, 256, 0, stream>>>(
        W[0], W[1], W[2], wt1, wt2, wt3,
        We[0], ate[0], wec1, We[1], ate[1], wec2, We[2], ate[2], wec3);
  }

  const int Hs[3] = {8, 8, 12};
  const ushort* Ain[3] = {abf1, x1b, x2b};
  const ushort* Wt[3] = {wt1, wt2, wt3};
  float* wecL[3] = {wec1, wec2, wec3};
  ushort* xoutb[3] = {x1b, x2b, nullptr};
  const float* WfL[3] = {Wf, Wf + 256, Wf + 512};
  const int slotb[3] = {0, 1, 2};

  for (int L = 0; L < 3; ++L) {
    const int H = Hs[L];
    const int HC = (L < 2) ? 256 : 768;
    // h = A @ Wt^T + fused a_s/a_d epilogue
    dim3 g(HC / 64, (NN + 127) / 128);
    if (L == 0)
      gemm_lds_kernel<32, 32><<<g, 256, 0, stream>>>(Ain[L], Wt[L], hbuf, ats[L], atd[L],
                                                     a_s, a_d, NN, HC, H);
    else if (L == 1)
      gemm_lds_kernel<256, 32><<<g, 256, 0, stream>>>(Ain[L], Wt[L], hbuf, ats[L], atd[L],
                                                      a_s, a_d, NN, HC, H);
    else
      gemm_lds_kernel<256, 64><<<g, 256, 0, stream>>>(Ain[L], Wt[L], hbuf, ats[L], atd[L],
                                                      a_s, a_d, NN, HC, H);
    // per-edge exp(leaky(alpha)) from bf16 ea_csr
    ase_kernel<<<(EF * H + 255) / 256, 256, 0, stream>>>(csr_src, csr_dst, ea_csr, wecL[L],
                                                         a_s, a_d, wexp, H);
    // single-pass gather + fused final-head partial
    if (H == 8) {
      int blocks = (NN * 1 + 3) / 4;
      aggregate_kernel<8, 32, 1, true><<<blocks, 256, 0, stream>>>(
          wexp, hbuf, off, csr_src, bb[L], xoutb[L], WfL[L], lpart, slotb[L]);
    } else {
      int blocks = (NN * 3 + 3) / 4;
      aggregate_kernel<12, 64, 3, false><<<blocks, 256, 0, stream>>>(
          wexp, hbuf, off, csr_src, bb[L], xoutb[L], WfL[L], lpart, slotb[L]);
    }
  }

  final_sigmoid_kernel<<<(NN + 255) / 256, 256, 0, stream>>>(lpart, bf, out);
}

// Round 13
// 308.369 us; speedup vs baseline: 1.7803x; 1.1094x over previous
//
#include <hip/hip_runtime.h>

#define NN 20000
#define EE 320000
#define EF 340000   /* EE + NN self loops */
#define EDIM 22
#define NBLK ((NN + 255) / 256)   /* 79 scan blocks */

typedef short bf16x8 __attribute__((ext_vector_type(8)));
typedef float f32x4 __attribute__((ext_vector_type(4)));

__device__ __forceinline__ float blo(unsigned u) {
  union { unsigned x; float f; } v; v.x = u << 16; return v.f;
}
__device__ __forceinline__ float bhi(unsigned u) {
  union { unsigned x; float f; } v; v.x = u & 0xffff0000u; return v.f;
}
__device__ __forceinline__ ushort f2b(float f) {
  union { float f; unsigned u; } v;
  v.f = f;
  unsigned u = v.u;
  return (ushort)((u + 0x7fffu + ((u >> 16) & 1u)) >> 16);  // RNE
}
__device__ __forceinline__ float lrelu(float a) { return a > 0.f ? a : 0.2f * a; }

// ---------------------------------------------------------------------------
// Graph setup: CSR by dst (counting sort)
// ---------------------------------------------------------------------------

__global__ void count_deg_kernel(const int* __restrict__ dst, int* __restrict__ cnt) {
  int e = blockIdx.x * blockDim.x + threadIdx.x;
  if (e < EE) atomicAdd(&cnt[dst[e]], 1);
}

__global__ void scan1_kernel(const int* __restrict__ cnt, int* __restrict__ off,
                             int* __restrict__ btot) {
  __shared__ int wsum[4];
  const int b = blockIdx.x, tid = threadIdx.x;
  const int lane = tid & 63, w = tid >> 6;
  const int i = b * 256 + tid;
  int v = (i < NN) ? (cnt[i] + 1) : 0;
  int x = v;
#pragma unroll
  for (int s = 1; s < 64; s <<= 1) {
    int t = __shfl_up(x, s);
    if (lane >= s) x += t;
  }
  if (lane == 63) wsum[w] = x;
  __syncthreads();
  if (tid == 0) {
    int a = 0;
#pragma unroll
    for (int k = 0; k < 4; ++k) { int t = wsum[k]; wsum[k] = a; a += t; }
  }
  __syncthreads();
  int excl = wsum[w] + x - v;
  if (i < NN) off[i] = excl;
  if (tid == 255) btot[b] = wsum[3] + x;
}

__global__ void scan2_kernel(int* __restrict__ btot) {
  __shared__ int s0;
  const int tid = threadIdx.x, lane = tid & 63, w = tid >> 6;
  int v = (tid < NBLK) ? btot[tid] : 0;
  int x = v;
#pragma unroll
  for (int s = 1; s < 64; s <<= 1) {
    int t = __shfl_up(x, s);
    if (lane >= s) x += t;
  }
  if (w == 0 && lane == 63) s0 = x;
  __syncthreads();
  int excl = x - v + (w ? s0 : 0);
  if (tid < NBLK) btot[tid] = excl;
}

__global__ void scan3_kernel(int* __restrict__ off, const int* __restrict__ btot,
                             int* __restrict__ cursor) {
  const int i = blockIdx.x * blockDim.x + threadIdx.x;
  if (i < NN) {
    int o = off[i] + btot[i >> 8];
    off[i] = o;
    cursor[i] = o;
  }
  if (i == 0) off[NN] = EF;
}

__global__ void scatter_kernel(const int* __restrict__ src, const int* __restrict__ dst,
                               int* __restrict__ cursor, int* __restrict__ csr_src,
                               int* __restrict__ csr_dst, int* __restrict__ csr_eid) {
  int e = blockIdx.x * blockDim.x + threadIdx.x;
  if (e >= EF) return;
  int s, d;
  if (e < EE) { s = src[e]; d = dst[e]; } else { s = e - EE; d = s; }
  int pos = atomicAdd(&cursor[d], 1);
  csr_src[pos] = s;
  csr_dst[pos] = d;
  csr_eid[pos] = e;
}

// Fused mean_ea + ea_csr: wave per node. While accumulating the mean over
// non-self edges, each lane converts+writes its edges' bf16 rows directly
// (edge rows don't need the mean). After the xor-reduce (full sum in ALL
// lanes), the lane holding the self-loop edge writes the mean row.
__global__ __launch_bounds__(256) void ea_build_kernel(
    const int* __restrict__ off, const int* __restrict__ csr_eid,
    const float* __restrict__ edge_attr, ushort* __restrict__ ea_csr) {
  const int n = (int)((blockIdx.x * blockDim.x + threadIdx.x) >> 6);
  const int lane = threadIdx.x & 63;
  if (n >= NN) return;
  const int start = off[n], end = off[n + 1];
  float a[24];
#pragma unroll
  for (int d = 0; d < 24; ++d) a[d] = 0.f;
  int selfj = -1;
  for (int j = start + lane; j < end; j += 64) {
    int eid = csr_eid[j];
    if (eid < EE) {
      const float* ea = edge_attr + (size_t)eid * EDIM;
      float r[22];
      float4 q0 = *(const float4*)(ea + 0);
      float4 q1 = *(const float4*)(ea + 4);
      float4 q2 = *(const float4*)(ea + 8);
      float4 q3 = *(const float4*)(ea + 12);
      float4 q4 = *(const float4*)(ea + 16);
      float2 q5 = *(const float2*)(ea + 20);
      r[0] = q0.x; r[1] = q0.y; r[2] = q0.z; r[3] = q0.w;
      r[4] = q1.x; r[5] = q1.y; r[6] = q1.z; r[7] = q1.w;
      r[8] = q2.x; r[9] = q2.y; r[10] = q2.z; r[11] = q2.w;
      r[12] = q3.x; r[13] = q3.y; r[14] = q3.z; r[15] = q3.w;
      r[16] = q4.x; r[17] = q4.y; r[18] = q4.z; r[19] = q4.w;
      r[20] = q5.x; r[21] = q5.y;
#pragma unroll
      for (int d = 0; d < EDIM; ++d) a[d] += r[d];
      ushort* op = ea_csr + (size_t)j * EDIM;
#pragma unroll
      for (int d = 0; d < 11; ++d) {
        unsigned u = (unsigned)f2b(r[2 * d]) | ((unsigned)f2b(r[2 * d + 1]) << 16);
        *(unsigned*)(op + 2 * d) = u;
      }
    } else {
      selfj = j;
    }
  }
#pragma unroll
  for (int s = 32; s > 0; s >>= 1)
#pragma unroll
    for (int d = 0; d < EDIM; ++d) a[d] += __shfl_xor(a[d], s);
  if (selfj >= 0) {
    const float den = 1.f / fmaxf((float)(end - start - 1), 1.f);
    ushort* op = ea_csr + (size_t)selfj * EDIM;
#pragma unroll
    for (int d = 0; d < 11; ++d) {
      unsigned u = (unsigned)f2b(a[2 * d] * den) | ((unsigned)f2b(a[2 * d + 1] * den) << 16);
      *(unsigned*)(op + 2 * d) = u;
    }
  }
}

// ---------------------------------------------------------------------------
// prep: x->bf16(pad) + W1/W2/W3 transpose->bf16 + wecomb x3 (one launch)
// ---------------------------------------------------------------------------
__global__ void prep_weights_kernel(
    const float* __restrict__ x, ushort* __restrict__ ab,
    const float* __restrict__ W1, const float* __restrict__ W2, const float* __restrict__ W3,
    ushort* __restrict__ wt1, ushort* __restrict__ wt2, ushort* __restrict__ wt3,
    const float* __restrict__ We1, const float* __restrict__ ate1, float* __restrict__ wec1,
    const float* __restrict__ We2, const float* __restrict__ ate2, float* __restrict__ wec2,
    const float* __restrict__ We3, const float* __restrict__ ate3, float* __restrict__ wec3) {
  int t = blockIdx.x * blockDim.x + threadIdx.x;
  const int SX = NN * 32;
  const int S0 = 256 * 32, S1 = 256 * 256, S2 = 768 * 256;
  const int S3 = EDIM * 8, S4 = EDIM * 8, S5 = EDIM * 12;
  if (t < SX) {
    int n = t >> 5, c = t & 31;
    ab[t] = (c < 16) ? f2b(x[n * 16 + c]) : (ushort)0;
    return;
  }
  t -= SX;
  if (t < S0) {
    int nc = t >> 5, k = t & 31;
    wt1[t] = (k < 16) ? f2b(W1[(size_t)k * 256 + nc]) : (ushort)0;
    return;
  }
  t -= S0;
  if (t < S1) {
    int nc = t >> 8, k = t & 255;
    wt2[t] = f2b(W2[(size_t)k * 256 + nc]);
    return;
  }
  t -= S1;
  if (t < S2) {
    int nc = t >> 8, k = t & 255;
    wt3[t] = f2b(W3[(size_t)k * 768 + nc]);
    return;
  }
  t -= S2;
  if (t < S3) {
    int d = t / 8, h = t % 8;
    float v = 0.f;
    for (int c = 0; c < 32; ++c) v += We1[(size_t)d * 256 + h * 32 + c] * ate1[h * 32 + c];
    wec1[t] = v;
    return;
  }
  t -= S3;
  if (t < S4) {
    int d = t / 8, h = t % 8;
    float v = 0.f;
    for (int c = 0; c < 32; ++c) v += We2[(size_t)d * 256 + h * 32 + c] * ate2[h * 32 + c];
    wec2[t] = v;
    return;
  }
  t -= S4;
  if (t < S5) {
    int d = t / 12, h = t % 12;
    float v = 0.f;
    for (int c = 0; c < 64; ++c) v += We3[(size_t)d * 768 + h * 64 + c] * ate3[h * 64 + c];
    wec3[t] = v;
  }
}

// ---------------------------------------------------------------------------
// bf16 MFMA GEMM with LDS-resident B panel + fused a_s/a_d epilogue (frozen).
// ---------------------------------------------------------------------------
template <int K, int CDIM>
__global__ __launch_bounds__(256) void gemm_lds_kernel(
    const ushort* __restrict__ A, const ushort* __restrict__ Bt,
    ushort* __restrict__ C, const float* __restrict__ atts,
    const float* __restrict__ attd, float* __restrict__ a_s,
    float* __restrict__ a_d, int M, int Nc, int H) {
  constexpr int CPC = K / 8;                       // 16B chunks per column
  constexpr int SWZ = (CPC - 1) < 7 ? (CPC - 1) : 7;
  __shared__ __align__(16) ushort Blds[64 * K];
  const int tid = threadIdx.x;
  const int lane = tid & 63;
  const int wid = tid >> 6;
  const int bn = blockIdx.x * 64;
  const int bm = blockIdx.y * 128 + wid * 32;
  const int r = lane & 15;
  const int kg = lane >> 4;

#pragma unroll
  for (int it = 0; it < (64 * CPC) / 256; ++it) {
    int idx = it * 256 + tid;
    int col = idx / CPC;
    int c = idx % CPC;
    const uint4 v = *(const uint4*)(Bt + (size_t)(bn + col) * K + c * 8);
    *(uint4*)(&Blds[(col * CPC + (c ^ (col & SWZ))) * 8]) = v;
  }
  __syncthreads();

  const int row0 = bm + r, row1 = bm + 16 + r;
  const bool v0 = row0 < M, v1 = row1 < M;
  const ushort* ap0 = A + (size_t)row0 * K + kg * 8;
  const ushort* ap1 = A + (size_t)row1 * K + kg * 8;

  f32x4 acc[2][4] = {};
#pragma unroll
  for (int k0 = 0; k0 < K; k0 += 32) {
    bf16x8 a0 = {}, a1 = {};
    if (v0) a0 = *(const bf16x8*)(ap0 + k0);
    if (v1) a1 = *(const bf16x8*)(ap1 + k0);
    const int cbase = k0 / 8 + kg;
#pragma unroll
    for (int nf = 0; nf < 4; ++nf) {
      const int col = nf * 16 + r;
      bf16x8 bfr = *(const bf16x8*)(&Blds[(col * CPC + (cbase ^ (col & SWZ))) * 8]);
      acc[0][nf] = __builtin_amdgcn_mfma_f32_16x16x32_bf16(a0, bfr, acc[0][nf], 0, 0, 0);
      acc[1][nf] = __builtin_amdgcn_mfma_f32_16x16x32_bf16(a1, bfr, acc[1][nf], 0, 0, 0);
    }
  }
#pragma unroll
  for (int half = 0; half < 2; ++half)
#pragma unroll
    for (int nf = 0; nf < 4; ++nf)
#pragma unroll
      for (int reg = 0; reg < 4; ++reg) {
        int row = bm + half * 16 + kg * 4 + reg;
        if (row < M) C[(size_t)row * Nc + bn + nf * 16 + r] = f2b(acc[half][nf][reg]);
      }

  float as_v[4], ad_v[4];
#pragma unroll
  for (int nf = 0; nf < 4; ++nf) {
    int cg = bn + nf * 16 + r;
    as_v[nf] = atts[cg];
    ad_v[nf] = attd[cg];
  }
  const int h0g = bn / CDIM;
#pragma unroll
  for (int half = 0; half < 2; ++half) {
#pragma unroll
    for (int reg = 0; reg < 4; ++reg) {
      float sA, dA, sB = 0.f, dB = 0.f;
      if (CDIM == 32) {
        sA = acc[half][0][reg] * as_v[0] + acc[half][1][reg] * as_v[1];
        dA = acc[half][0][reg] * ad_v[0] + acc[half][1][reg] * ad_v[1];
        sB = acc[half][2][reg] * as_v[2] + acc[half][3][reg] * as_v[3];
        dB = acc[half][2][reg] * ad_v[2] + acc[half][3][reg] * ad_v[3];
      } else {
        sA = acc[half][0][reg] * as_v[0] + acc[half][1][reg] * as_v[1] +
             acc[half][2][reg] * as_v[2] + acc[half][3][reg] * as_v[3];
        dA = acc[half][0][reg] * ad_v[0] + acc[half][1][reg] * ad_v[1] +
             acc[half][2][reg] * ad_v[2] + acc[half][3][reg] * ad_v[3];
      }
#pragma unroll
      for (int s = 8; s >= 1; s >>= 1) {
        sA += __shfl_xor(sA, s);
        dA += __shfl_xor(dA, s);
        if (CDIM == 32) { sB += __shfl_xor(sB, s); dB += __shfl_xor(dB, s); }
      }
      if (r == 0) {
        int row = bm + half * 16 + kg * 4 + reg;
        if (row < M) {
          a_s[row * H + h0g] = sA;
          a_d[row * H + h0g] = dA;
          if (CDIM == 32) {
            a_s[row * H + h0g + 1] = sB;
            a_d[row * H + h0g + 1] = dB;
          }
        }
      }
    }
  }
}

// ---------------------------------------------------------------------------
// Per-edge ase: one thread per edge computes all H heads.
// ea row loaded ONCE (vs H times), a_s/a_d rows contiguous float4 gathers,
// wexp row written with vector stores.
// ---------------------------------------------------------------------------
template <int H>
__global__ void ase_kernel(const int* __restrict__ csr_src, const int* __restrict__ csr_dst,
                           const ushort* __restrict__ ea_csr, const float* __restrict__ wec,
                           const float* __restrict__ a_s, const float* __restrict__ a_d,
                           float* __restrict__ wexp) {
  int j = blockIdx.x * blockDim.x + threadIdx.x;
  if (j >= EF) return;
  const ushort* eap = ea_csr + (size_t)j * EDIM;
  float ea[22];
#pragma unroll
  for (int d = 0; d < 11; ++d) {
    unsigned u = *(const unsigned*)(eap + 2 * d);
    ea[2 * d] = blo(u);
    ea[2 * d + 1] = bhi(u);
  }
  const float* asp = a_s + (size_t)csr_src[j] * H;
  const float* adp = a_d + (size_t)csr_dst[j] * H;
  float v[H];
#pragma unroll
  for (int q = 0; q < H / 4; ++q) {
    float4 s4 = *(const float4*)(asp + q * 4);
    float4 d4 = *(const float4*)(adp + q * 4);
    v[q * 4 + 0] = s4.x + d4.x;
    v[q * 4 + 1] = s4.y + d4.y;
    v[q * 4 + 2] = s4.z + d4.z;
    v[q * 4 + 3] = s4.w + d4.w;
  }
#pragma unroll
  for (int d = 0; d < EDIM; ++d) {
    const float* wr = wec + d * H;
#pragma unroll
    for (int h = 0; h < H; ++h) v[h] += ea[d] * wr[h];
  }
  float* op = wexp + (size_t)j * H;
#pragma unroll
  for (int q = 0; q < H / 4; ++q) {
    float4 o;
    o.x = __expf(lrelu(v[q * 4 + 0]));
    o.y = __expf(lrelu(v[q * 4 + 1]));
    o.z = __expf(lrelu(v[q * 4 + 2]));
    o.w = __expf(lrelu(v[q * 4 + 3]));
    *(float4*)(op + q * 4) = o;
  }
}

// ---------------------------------------------------------------------------
// Single-pass aggregation on precomputed wexp + fused final-head partial
// (frozen, round-12 form).
// ---------------------------------------------------------------------------
template <int H, int C, int NCH, bool WRITE_X>
__global__ __launch_bounds__(256) void aggregate_kernel(
    const float* __restrict__ wexp, const ushort* __restrict__ hb,
    const int* __restrict__ off, const int* __restrict__ csr_src,
    const float* __restrict__ bias, ushort* __restrict__ xb,
    const float* __restrict__ WfL, float* __restrict__ logitpart, int slotbase) {
  constexpr int HC = H * C;
  constexpr int CHUNK = HC / NCH;   // 256
  constexpr int FPL = CHUNK / 64;   // 4 features per lane (divides C)
  const int t = (int)((blockIdx.x * blockDim.x + threadIdx.x) >> 6);
  const int lane = threadIdx.x & 63;
  const int n = t / NCH, ch = t - n * NCH;
  if (n >= NN) return;
  const int start = off[n], end = off[n + 1];
  const int f0 = ch * CHUNK + lane * FPL;
  const int qh = f0 / C;                 // lane's (global) head
  const ushort* hrow = hb + f0;
  const float* wp = wexp + qh;

  float acc[FPL] = {};
  float dn = 0.f;
  int j = start;
  for (; j + 4 <= end; j += 4) {
    int s0 = csr_src[j], s1 = csr_src[j + 1], s2 = csr_src[j + 2], s3 = csr_src[j + 3];
    float w0 = wp[(size_t)j * H];
    float w1 = wp[(size_t)(j + 1) * H];
    float w2 = wp[(size_t)(j + 2) * H];
    float w3 = wp[(size_t)(j + 3) * H];
    uint2 u0 = *(const uint2*)(hrow + (size_t)s0 * HC);
    uint2 u1 = *(const uint2*)(hrow + (size_t)s1 * HC);
    uint2 u2 = *(const uint2*)(hrow + (size_t)s2 * HC);
    uint2 u3 = *(const uint2*)(hrow + (size_t)s3 * HC);
    dn += (w0 + w1) + (w2 + w3);
    acc[0] += w0 * blo(u0.x) + w1 * blo(u1.x) + w2 * blo(u2.x) + w3 * blo(u3.x);
    acc[1] += w0 * bhi(u0.x) + w1 * bhi(u1.x) + w2 * bhi(u2.x) + w3 * bhi(u3.x);
    acc[2] += w0 * blo(u0.y) + w1 * blo(u1.y) + w2 * blo(u2.y) + w3 * blo(u3.y);
    acc[3] += w0 * bhi(u0.y) + w1 * bhi(u1.y) + w2 * bhi(u2.y) + w3 * bhi(u3.y);
  }
  for (; j < end; ++j) {
    int s0 = csr_src[j];
    float w0 = wp[(size_t)j * H];
    uint2 u0 = *(const uint2*)(hrow + (size_t)s0 * HC);
    dn += w0;
    acc[0] += w0 * blo(u0.x);
    acc[1] += w0 * bhi(u0.x);
    acc[2] += w0 * blo(u0.y);
    acc[3] += w0 * bhi(u0.y);
  }

  const float my_rd = 1.f / dn;
  const float4 wf4 = *(const float4*)(WfL + f0);
  const float wfv[4] = {wf4.x, wf4.y, wf4.z, wf4.w};
  float o[FPL];
  float partial = 0.f;
#pragma unroll
  for (int i = 0; i < FPL; ++i) {
    o[i] = fmaxf(acc[i] * my_rd + bias[f0 + i], 0.f);
    partial += o[i] * wfv[i];
  }
  if (WRITE_X) {
    uint2 pk;
    pk.x = (unsigned)f2b(o[0]) | ((unsigned)f2b(o[1]) << 16);
    pk.y = (unsigned)f2b(o[2]) | ((unsigned)f2b(o[3]) << 16);
    *(uint2*)(xb + (size_t)n * HC + f0) = pk;
  }
#pragma unroll
  for (int s = 32; s > 0; s >>= 1) partial += __shfl_xor(partial, s);
  if (lane == 0) logitpart[n * 5 + slotbase + ch] = partial;
}

// sigmoid over the 5 per-node logit partials
__global__ void final_sigmoid_kernel(const float* __restrict__ logitpart,
                                     const float* __restrict__ bf,
                                     float* __restrict__ out) {
  int n = blockIdx.x * blockDim.x + threadIdx.x;
  if (n >= NN) return;
  const float* lp = logitpart + n * 5;
  float s = lp[0] + lp[1] + lp[2] + lp[3] + lp[4] + bf[0];
  out[n] = 1.f / (1.f + __expf(-s));
}

// ---------------------------------------------------------------------------

extern "C" void kernel_launch(void* const* d_in, const int* in_sizes, int n_in,
                              void* d_out, int out_size, void* d_ws, size_t ws_size,
                              hipStream_t stream) {
  const float* x     = (const float*)d_in[0];
  const int*   eidx  = (const int*)d_in[1];
  const float* eattr = (const float*)d_in[2];
  const float* W[3]   = {(const float*)d_in[3],  (const float*)d_in[9],  (const float*)d_in[15]};
  const float* ats[3] = {(const float*)d_in[4],  (const float*)d_in[10], (const float*)d_in[16]};
  const float* atd[3] = {(const float*)d_in[5],  (const float*)d_in[11], (const float*)d_in[17]};
  const float* We[3]  = {(const float*)d_in[6],  (const float*)d_in[12], (const float*)d_in[18]};
  const float* ate[3] = {(const float*)d_in[7],  (const float*)d_in[13], (const float*)d_in[19]};
  const float* bb[3]  = {(const float*)d_in[8],  (const float*)d_in[14], (const float*)d_in[20]};
  const float* Wf = (const float*)d_in[21];
  const float* bf = (const float*)d_in[22];
  float* out = (float*)d_out;

  const int* src = eidx;
  const int* dst = eidx + EE;

  char* p = (char*)d_ws;
  auto carve = [&](size_t bytes) -> char* {
    char* q = p;
    p += (bytes + 255) & ~(size_t)255;
    return q;
  };
  ushort* x1b    = (ushort*)carve((size_t)NN * 256 * 2);
  ushort* x2b    = (ushort*)carve((size_t)NN * 256 * 2);
  ushort* hbuf   = (ushort*)carve((size_t)NN * 768 * 2);
  ushort* abf1   = (ushort*)carve((size_t)NN * 32 * 2);
  ushort* wt1    = (ushort*)carve((size_t)256 * 32 * 2);
  ushort* wt2    = (ushort*)carve((size_t)256 * 256 * 2);
  ushort* wt3    = (ushort*)carve((size_t)768 * 256 * 2);
  ushort* ea_csr = (ushort*)carve((size_t)EF * EDIM * 2);
  float*  a_s    = (float*)carve((size_t)NN * 12 * 4);
  float*  a_d    = (float*)carve((size_t)NN * 12 * 4);
  float*  wexp   = (float*)carve((size_t)EF * 12 * 4);
  float*  wec1   = (float*)carve((size_t)EDIM * 8 * 4);
  float*  wec2   = (float*)carve((size_t)EDIM * 8 * 4);
  float*  wec3   = (float*)carve((size_t)EDIM * 12 * 4);
  float*  lpart  = (float*)carve((size_t)NN * 5 * 4);
  int* cnt       = (int*)carve((size_t)NN * 4);
  int* off       = (int*)carve((size_t)(NN + 1) * 4);
  int* btot      = (int*)carve((size_t)NBLK * 4);
  int* cursor    = (int*)carve((size_t)NN * 4);
  int* csr_src   = (int*)carve((size_t)EF * 4);
  int* csr_dst   = (int*)carve((size_t)EF * 4);
  int* csr_eid   = (int*)carve((size_t)EF * 4);

  // ---- graph structure ----
  hipMemsetAsync(cnt, 0, (size_t)NN * 4, stream);
  count_deg_kernel<<<(EE + 255) / 256, 256, 0, stream>>>(dst, cnt);
  scan1_kernel<<<NBLK, 256, 0, stream>>>(cnt, off, btot);
  scan2_kernel<<<1, 128, 0, stream>>>(btot);
  scan3_kernel<<<NBLK, 256, 0, stream>>>(off, btot, cursor);
  scatter_kernel<<<(EF + 255) / 256, 256, 0, stream>>>(src, dst, cursor, csr_src, csr_dst,
                                                       csr_eid);
  // fused mean + bf16 CSR edge_attr build (single pass over edge_attr)
  ea_build_kernel<<<(NN * 64 + 255) / 256, 256, 0, stream>>>(off, csr_eid, eattr, ea_csr);

  // ---- dtype prep (single launch: x + W1/2/3 + wecomb x3) ----
  {
    const int total = NN * 32 + 256 * 32 + 256 * 256 + 768 * 256 +
                      EDIM * 8 + EDIM * 8 + EDIM * 12;
    prep_weights_kernel<<<(total + 255) / 256, 256, 0, stream>>>(
        x, abf1, W[0], W[1], W[2], wt1, wt2, wt3,
        We[0], ate[0], wec1, We[1], ate[1], wec2, We[2], ate[2], wec3);
  }

  const ushort* Ain[3] = {abf1, x1b, x2b};
  const ushort* Wt[3] = {wt1, wt2, wt3};
  float* wecL[3] = {wec1, wec2, wec3};
  ushort* xoutb[3] = {x1b, x2b, nullptr};
  const float* WfL[3] = {Wf, Wf + 256, Wf + 512};
  const int slotb[3] = {0, 1, 2};

  for (int L = 0; L < 3; ++L) {
    const int H = (L < 2) ? 8 : 12;
    const int HC = (L < 2) ? 256 : 768;
    // h = A @ Wt^T + fused a_s/a_d epilogue
    dim3 g(HC / 64, (NN + 127) / 128);
    if (L == 0)
      gemm_lds_kernel<32, 32><<<g, 256, 0, stream>>>(Ain[L], Wt[L], hbuf, ats[L], atd[L],
                                                     a_s, a_d, NN, HC, H);
    else if (L == 1)
      gemm_lds_kernel<256, 32><<<g, 256, 0, stream>>>(Ain[L], Wt[L], hbuf, ats[L], atd[L],
                                                      a_s, a_d, NN, HC, H);
    else
      gemm_lds_kernel<256, 64><<<g, 256, 0, stream>>>(Ain[L], Wt[L], hbuf, ats[L], atd[L],
                                                      a_s, a_d, NN, HC, H);
    // per-edge wexp (all heads per thread)
    if (H == 8)
      ase_kernel<8><<<(EF + 255) / 256, 256, 0, stream>>>(csr_src, csr_dst, ea_csr,
                                                          wecL[L], a_s, a_d, wexp);
    else
      ase_kernel<12><<<(EF + 255) / 256, 256, 0, stream>>>(csr_src, csr_dst, ea_csr,
                                                           wecL[L], a_s, a_d, wexp);
    // single-pass gather + fused final-head partial (frozen)
    if (H == 8) {
      int blocks = (NN * 1 + 3) / 4;
      aggregate_kernel<8, 32, 1, true><<<blocks, 256, 0, stream>>>(
          wexp, hbuf, off, csr_src, bb[L], xoutb[L], WfL[L], lpart, slotb[L]);
    } else {
      int blocks = (NN * 3 + 3) / 4;
      aggregate_kernel<12, 64, 3, false><<<blocks, 256, 0, stream>>>(
          wexp, hbuf, off, csr_src, bb[L], xoutb[L], WfL[L], lpart, slotb[L]);
    }
  }

  final_sigmoid_kernel<<<(NN + 255) / 256, 256, 0, stream>>>(lpart, bf, out);
}

// Round 14
// 299.306 us; speedup vs baseline: 1.8342x; 1.0303x over previous
//
#include <hip/hip_runtime.h>

#define NN 20000
#define EE 320000
#define EF 340000   /* EE + NN self loops */
#define EDIM 22
#define NBLK ((NN + 255) / 256)   /* 79 scan blocks */

typedef short bf16x8 __attribute__((ext_vector_type(8)));
typedef float f32x4 __attribute__((ext_vector_type(4)));

__device__ __forceinline__ float b2f(ushort u) {
  union { unsigned x; float f; } v; v.x = ((unsigned)u) << 16; return v.f;
}
__device__ __forceinline__ float blo(unsigned u) {
  union { unsigned x; float f; } v; v.x = u << 16; return v.f;
}
__device__ __forceinline__ float bhi(unsigned u) {
  union { unsigned x; float f; } v; v.x = u & 0xffff0000u; return v.f;
}
__device__ __forceinline__ ushort f2b(float f) {
  union { float f; unsigned u; } v;
  v.f = f;
  unsigned u = v.u;
  return (ushort)((u + 0x7fffu + ((u >> 16) & 1u)) >> 16);  // RNE
}
__device__ __forceinline__ float lrelu(float a) { return a > 0.f ? a : 0.2f * a; }

// ---------------------------------------------------------------------------
// Graph setup: CSR by dst (counting sort)
// ---------------------------------------------------------------------------

__global__ void count_deg_kernel(const int* __restrict__ dst, int* __restrict__ cnt) {
  int e = blockIdx.x * blockDim.x + threadIdx.x;
  if (e < EE) atomicAdd(&cnt[dst[e]], 1);
}

__global__ void scan1_kernel(const int* __restrict__ cnt, int* __restrict__ off,
                             int* __restrict__ btot) {
  __shared__ int wsum[4];
  const int b = blockIdx.x, tid = threadIdx.x;
  const int lane = tid & 63, w = tid >> 6;
  const int i = b * 256 + tid;
  int v = (i < NN) ? (cnt[i] + 1) : 0;
  int x = v;
#pragma unroll
  for (int s = 1; s < 64; s <<= 1) {
    int t = __shfl_up(x, s);
    if (lane >= s) x += t;
  }
  if (lane == 63) wsum[w] = x;
  __syncthreads();
  if (tid == 0) {
    int a = 0;
#pragma unroll
    for (int k = 0; k < 4; ++k) { int t = wsum[k]; wsum[k] = a; a += t; }
  }
  __syncthreads();
  int excl = wsum[w] + x - v;
  if (i < NN) off[i] = excl;
  if (tid == 255) btot[b] = wsum[3] + x;
}

__global__ void scan2_kernel(int* __restrict__ btot) {
  __shared__ int s0;
  const int tid = threadIdx.x, lane = tid & 63, w = tid >> 6;
  int v = (tid < NBLK) ? btot[tid] : 0;
  int x = v;
#pragma unroll
  for (int s = 1; s < 64; s <<= 1) {
    int t = __shfl_up(x, s);
    if (lane >= s) x += t;
  }
  if (w == 0 && lane == 63) s0 = x;
  __syncthreads();
  int excl = x - v + (w ? s0 : 0);
  if (tid < NBLK) btot[tid] = excl;
}

__global__ void scan3_kernel(int* __restrict__ off, const int* __restrict__ btot,
                             int* __restrict__ cursor) {
  const int i = blockIdx.x * blockDim.x + threadIdx.x;
  if (i < NN) {
    int o = off[i] + btot[i >> 8];
    off[i] = o;
    cursor[i] = o;
  }
  if (i == 0) off[NN] = EF;
}

__global__ void scatter_kernel(const int* __restrict__ src, const int* __restrict__ dst,
                               int* __restrict__ cursor, int* __restrict__ csr_src,
                               int* __restrict__ csr_dst, int* __restrict__ csr_eid) {
  int e = blockIdx.x * blockDim.x + threadIdx.x;
  if (e >= EF) return;
  int s, d;
  if (e < EE) { s = src[e]; d = dst[e]; } else { s = e - EE; d = s; }
  int pos = atomicAdd(&cursor[d], 1);
  csr_src[pos] = s;
  csr_dst[pos] = d;
  csr_eid[pos] = e;
}

// Fused mean_ea + ea_csr build (frozen, round-13)
__global__ __launch_bounds__(256) void ea_build_kernel(
    const int* __restrict__ off, const int* __restrict__ csr_eid,
    const float* __restrict__ edge_attr, ushort* __restrict__ ea_csr) {
  const int n = (int)((blockIdx.x * blockDim.x + threadIdx.x) >> 6);
  const int lane = threadIdx.x & 63;
  if (n >= NN) return;
  const int start = off[n], end = off[n + 1];
  float a[24];
#pragma unroll
  for (int d = 0; d < 24; ++d) a[d] = 0.f;
  int selfj = -1;
  for (int j = start + lane; j < end; j += 64) {
    int eid = csr_eid[j];
    if (eid < EE) {
      const float* ea = edge_attr + (size_t)eid * EDIM;
      float r[22];
      float4 q0 = *(const float4*)(ea + 0);
      float4 q1 = *(const float4*)(ea + 4);
      float4 q2 = *(const float4*)(ea + 8);
      float4 q3 = *(const float4*)(ea + 12);
      float4 q4 = *(const float4*)(ea + 16);
      float2 q5 = *(const float2*)(ea + 20);
      r[0] = q0.x; r[1] = q0.y; r[2] = q0.z; r[3] = q0.w;
      r[4] = q1.x; r[5] = q1.y; r[6] = q1.z; r[7] = q1.w;
      r[8] = q2.x; r[9] = q2.y; r[10] = q2.z; r[11] = q2.w;
      r[12] = q3.x; r[13] = q3.y; r[14] = q3.z; r[15] = q3.w;
      r[16] = q4.x; r[17] = q4.y; r[18] = q4.z; r[19] = q4.w;
      r[20] = q5.x; r[21] = q5.y;
#pragma unroll
      for (int d = 0; d < EDIM; ++d) a[d] += r[d];
      ushort* op = ea_csr + (size_t)j * EDIM;
#pragma unroll
      for (int d = 0; d < 11; ++d) {
        unsigned u = (unsigned)f2b(r[2 * d]) | ((unsigned)f2b(r[2 * d + 1]) << 16);
        *(unsigned*)(op + 2 * d) = u;
      }
    } else {
      selfj = j;
    }
  }
#pragma unroll
  for (int s = 32; s > 0; s >>= 1)
#pragma unroll
    for (int d = 0; d < EDIM; ++d) a[d] += __shfl_xor(a[d], s);
  if (selfj >= 0) {
    const float den = 1.f / fmaxf((float)(end - start - 1), 1.f);
    ushort* op = ea_csr + (size_t)selfj * EDIM;
#pragma unroll
    for (int d = 0; d < 11; ++d) {
      unsigned u = (unsigned)f2b(a[2 * d] * den) | ((unsigned)f2b(a[2 * d + 1] * den) << 16);
      *(unsigned*)(op + 2 * d) = u;
    }
  }
}

// ---------------------------------------------------------------------------
// prep: x->bf16(pad) + W1/W2/W3 transpose->bf16 + wecomb x3 (one launch)
// ---------------------------------------------------------------------------
__global__ void prep_weights_kernel(
    const float* __restrict__ x, ushort* __restrict__ ab,
    const float* __restrict__ W1, const float* __restrict__ W2, const float* __restrict__ W3,
    ushort* __restrict__ wt1, ushort* __restrict__ wt2, ushort* __restrict__ wt3,
    const float* __restrict__ We1, const float* __restrict__ ate1, float* __restrict__ wec1,
    const float* __restrict__ We2, const float* __restrict__ ate2, float* __restrict__ wec2,
    const float* __restrict__ We3, const float* __restrict__ ate3, float* __restrict__ wec3) {
  int t = blockIdx.x * blockDim.x + threadIdx.x;
  const int SX = NN * 32;
  const int S0 = 256 * 32, S1 = 256 * 256, S2 = 768 * 256;
  const int S3 = EDIM * 8, S4 = EDIM * 8, S5 = EDIM * 12;
  if (t < SX) {
    int n = t >> 5, c = t & 31;
    ab[t] = (c < 16) ? f2b(x[n * 16 + c]) : (ushort)0;
    return;
  }
  t -= SX;
  if (t < S0) {
    int nc = t >> 5, k = t & 31;
    wt1[t] = (k < 16) ? f2b(W1[(size_t)k * 256 + nc]) : (ushort)0;
    return;
  }
  t -= S0;
  if (t < S1) {
    int nc = t >> 8, k = t & 255;
    wt2[t] = f2b(W2[(size_t)k * 256 + nc]);
    return;
  }
  t -= S1;
  if (t < S2) {
    int nc = t >> 8, k = t & 255;
    wt3[t] = f2b(W3[(size_t)k * 768 + nc]);
    return;
  }
  t -= S2;
  if (t < S3) {
    int d = t / 8, h = t % 8;
    float v = 0.f;
    for (int c = 0; c < 32; ++c) v += We1[(size_t)d * 256 + h * 32 + c] * ate1[h * 32 + c];
    wec1[t] = v;
    return;
  }
  t -= S3;
  if (t < S4) {
    int d = t / 8, h = t % 8;
    float v = 0.f;
    for (int c = 0; c < 32; ++c) v += We2[(size_t)d * 256 + h * 32 + c] * ate2[h * 32 + c];
    wec2[t] = v;
    return;
  }
  t -= S4;
  if (t < S5) {
    int d = t / 12, h = t % 12;
    float v = 0.f;
    for (int c = 0; c < 64; ++c) v += We3[(size_t)d * 768 + h * 64 + c] * ate3[h * 64 + c];
    wec3[t] = v;
  }
}

// ---------------------------------------------------------------------------
// bf16 MFMA GEMM, LDS-resident B panel (BN cols x K), fused a_s/a_d epilogue.
// BN=64 (L1/L2) or BN=128 (L3: halves A re-reads 12x -> 6x; 64KB LDS,
// 2 blocks/CU). Panel holds whole heads: NH = BN/CDIM, HPP = CDIM/16.
// ---------------------------------------------------------------------------
template <int K, int BN, int CDIM>
__global__ __launch_bounds__(256) void gemm_lds_kernel(
    const ushort* __restrict__ A, const ushort* __restrict__ Bt,
    ushort* __restrict__ C, const float* __restrict__ atts,
    const float* __restrict__ attd, float* __restrict__ a_s,
    float* __restrict__ a_d, int M, int Nc, int H) {
  constexpr int CPC = K / 8;                       // 16B chunks per column
  constexpr int SWZ = (CPC - 1) < 7 ? (CPC - 1) : 7;
  constexpr int NF = BN / 16;                      // 16-col fragments per panel
  constexpr int NH = BN / CDIM;                    // heads per panel
  constexpr int HPP = CDIM / 16;                   // fragments per head
  __shared__ __align__(16) ushort Blds[BN * K];
  const int tid = threadIdx.x;
  const int lane = tid & 63;
  const int wid = tid >> 6;
  const int bn = blockIdx.x * BN;
  const int bm = blockIdx.y * 128 + wid * 32;
  const int r = lane & 15;
  const int kg = lane >> 4;

#pragma unroll
  for (int it = 0; it < (BN * CPC) / 256; ++it) {
    int idx = it * 256 + tid;
    int col = idx / CPC;
    int c = idx % CPC;
    const uint4 v = *(const uint4*)(Bt + (size_t)(bn + col) * K + c * 8);
    *(uint4*)(&Blds[(col * CPC + (c ^ (col & SWZ))) * 8]) = v;
  }
  __syncthreads();

  const int row0 = bm + r, row1 = bm + 16 + r;
  const bool v0 = row0 < M, v1 = row1 < M;
  const ushort* ap0 = A + (size_t)row0 * K + kg * 8;
  const ushort* ap1 = A + (size_t)row1 * K + kg * 8;

  f32x4 acc[2][NF] = {};
#pragma unroll
  for (int k0 = 0; k0 < K; k0 += 32) {
    bf16x8 a0 = {}, a1 = {};
    if (v0) a0 = *(const bf16x8*)(ap0 + k0);
    if (v1) a1 = *(const bf16x8*)(ap1 + k0);
    const int cbase = k0 / 8 + kg;
#pragma unroll
    for (int nf = 0; nf < NF; ++nf) {
      const int col = nf * 16 + r;
      bf16x8 bfr = *(const bf16x8*)(&Blds[(col * CPC + (cbase ^ (col & SWZ))) * 8]);
      acc[0][nf] = __builtin_amdgcn_mfma_f32_16x16x32_bf16(a0, bfr, acc[0][nf], 0, 0, 0);
      acc[1][nf] = __builtin_amdgcn_mfma_f32_16x16x32_bf16(a1, bfr, acc[1][nf], 0, 0, 0);
    }
  }
#pragma unroll
  for (int half = 0; half < 2; ++half)
#pragma unroll
    for (int nf = 0; nf < NF; ++nf)
#pragma unroll
      for (int reg = 0; reg < 4; ++reg) {
        int row = bm + half * 16 + kg * 4 + reg;
        if (row < M) C[(size_t)row * Nc + bn + nf * 16 + r] = f2b(acc[half][nf][reg]);
      }

  // fused a_s/a_d epilogue: per head, dot + 16-lane reduce, lane r==0 writes
  float as_v[NF], ad_v[NF];
#pragma unroll
  for (int nf = 0; nf < NF; ++nf) {
    int cg = bn + nf * 16 + r;
    as_v[nf] = atts[cg];
    ad_v[nf] = attd[cg];
  }
  const int h0g = bn / CDIM;
#pragma unroll
  for (int half = 0; half < 2; ++half) {
#pragma unroll
    for (int reg = 0; reg < 4; ++reg) {
      float sv[NH], dv[NH];
#pragma unroll
      for (int hh = 0; hh < NH; ++hh) {
        float s = 0.f, d = 0.f;
#pragma unroll
        for (int q = 0; q < HPP; ++q) {
          int nf = hh * HPP + q;
          s += acc[half][nf][reg] * as_v[nf];
          d += acc[half][nf][reg] * ad_v[nf];
        }
        sv[hh] = s;
        dv[hh] = d;
      }
#pragma unroll
      for (int s = 8; s >= 1; s >>= 1)
#pragma unroll
        for (int hh = 0; hh < NH; ++hh) {
          sv[hh] += __shfl_xor(sv[hh], s);
          dv[hh] += __shfl_xor(dv[hh], s);
        }
      if (r == 0) {
        int row = bm + half * 16 + kg * 4 + reg;
        if (row < M) {
#pragma unroll
          for (int hh = 0; hh < NH; ++hh) {
            a_s[row * H + h0g + hh] = sv[hh];
            a_d[row * H + h0g + hh] = dv[hh];
          }
        }
      }
    }
  }
}

// ---------------------------------------------------------------------------
// Per-edge ase -> bf16 wexp (halved traffic vs f32)
// ---------------------------------------------------------------------------
template <int H>
__global__ void ase_kernel(const int* __restrict__ csr_src, const int* __restrict__ csr_dst,
                           const ushort* __restrict__ ea_csr, const float* __restrict__ wec,
                           const float* __restrict__ a_s, const float* __restrict__ a_d,
                           ushort* __restrict__ wexp) {
  int j = blockIdx.x * blockDim.x + threadIdx.x;
  if (j >= EF) return;
  const ushort* eap = ea_csr + (size_t)j * EDIM;
  float ea[22];
#pragma unroll
  for (int d = 0; d < 11; ++d) {
    unsigned u = *(const unsigned*)(eap + 2 * d);
    ea[2 * d] = blo(u);
    ea[2 * d + 1] = bhi(u);
  }
  const float* asp = a_s + (size_t)csr_src[j] * H;
  const float* adp = a_d + (size_t)csr_dst[j] * H;
  float v[H];
#pragma unroll
  for (int q = 0; q < H / 4; ++q) {
    float4 s4 = *(const float4*)(asp + q * 4);
    float4 d4 = *(const float4*)(adp + q * 4);
    v[q * 4 + 0] = s4.x + d4.x;
    v[q * 4 + 1] = s4.y + d4.y;
    v[q * 4 + 2] = s4.z + d4.z;
    v[q * 4 + 3] = s4.w + d4.w;
  }
#pragma unroll
  for (int d = 0; d < EDIM; ++d) {
    const float* wr = wec + d * H;
#pragma unroll
    for (int h = 0; h < H; ++h) v[h] += ea[d] * wr[h];
  }
  ushort* op = wexp + (size_t)j * H;
#pragma unroll
  for (int q = 0; q < H / 2; ++q) {
    float w0 = __expf(lrelu(v[q * 2 + 0]));
    float w1 = __expf(lrelu(v[q * 2 + 1]));
    unsigned u = (unsigned)f2b(w0) | ((unsigned)f2b(w1) << 16);
    *(unsigned*)(op + 2 * q) = u;
  }
}

// ---------------------------------------------------------------------------
// Single-pass aggregation on bf16 wexp + fused final-head partial (frozen
// structure; wexp loads now 2B broadcast).
// ---------------------------------------------------------------------------
template <int H, int C, int NCH, bool WRITE_X>
__global__ __launch_bounds__(256) void aggregate_kernel(
    const ushort* __restrict__ wexp, const ushort* __restrict__ hb,
    const int* __restrict__ off, const int* __restrict__ csr_src,
    const float* __restrict__ bias, ushort* __restrict__ xb,
    const float* __restrict__ WfL, float* __restrict__ logitpart, int slotbase) {
  constexpr int HC = H * C;
  constexpr int CHUNK = HC / NCH;   // 256
  constexpr int FPL = CHUNK / 64;   // 4 features per lane (divides C)
  const int t = (int)((blockIdx.x * blockDim.x + threadIdx.x) >> 6);
  const int lane = threadIdx.x & 63;
  const int n = t / NCH, ch = t - n * NCH;
  if (n >= NN) return;
  const int start = off[n], end = off[n + 1];
  const int f0 = ch * CHUNK + lane * FPL;
  const int qh = f0 / C;                 // lane's (global) head
  const ushort* hrow = hb + f0;
  const ushort* wp = wexp + qh;

  float acc[FPL] = {};
  float dn = 0.f;
  int j = start;
  for (; j + 4 <= end; j += 4) {
    int s0 = csr_src[j], s1 = csr_src[j + 1], s2 = csr_src[j + 2], s3 = csr_src[j + 3];
    float w0 = b2f(wp[(size_t)j * H]);
    float w1 = b2f(wp[(size_t)(j + 1) * H]);
    float w2 = b2f(wp[(size_t)(j + 2) * H]);
    float w3 = b2f(wp[(size_t)(j + 3) * H]);
    uint2 u0 = *(const uint2*)(hrow + (size_t)s0 * HC);
    uint2 u1 = *(const uint2*)(hrow + (size_t)s1 * HC);
    uint2 u2 = *(const uint2*)(hrow + (size_t)s2 * HC);
    uint2 u3 = *(const uint2*)(hrow + (size_t)s3 * HC);
    dn += (w0 + w1) + (w2 + w3);
    acc[0] += w0 * blo(u0.x) + w1 * blo(u1.x) + w2 * blo(u2.x) + w3 * blo(u3.x);
    acc[1] += w0 * bhi(u0.x) + w1 * bhi(u1.x) + w2 * bhi(u2.x) + w3 * bhi(u3.x);
    acc[2] += w0 * blo(u0.y) + w1 * blo(u1.y) + w2 * blo(u2.y) + w3 * blo(u3.y);
    acc[3] += w0 * bhi(u0.y) + w1 * bhi(u1.y) + w2 * bhi(u2.y) + w3 * bhi(u3.y);
  }
  for (; j < end; ++j) {
    int s0 = csr_src[j];
    float w0 = b2f(wp[(size_t)j * H]);
    uint2 u0 = *(const uint2*)(hrow + (size_t)s0 * HC);
    dn += w0;
    acc[0] += w0 * blo(u0.x);
    acc[1] += w0 * bhi(u0.x);
    acc[2] += w0 * blo(u0.y);
    acc[3] += w0 * bhi(u0.y);
  }

  const float my_rd = 1.f / dn;
  const float4 wf4 = *(const float4*)(WfL + f0);
  const float wfv[4] = {wf4.x, wf4.y, wf4.z, wf4.w};
  float o[FPL];
  float partial = 0.f;
#pragma unroll
  for (int i = 0; i < FPL; ++i) {
    o[i] = fmaxf(acc[i] * my_rd + bias[f0 + i], 0.f);
    partial += o[i] * wfv[i];
  }
  if (WRITE_X) {
    uint2 pk;
    pk.x = (unsigned)f2b(o[0]) | ((unsigned)f2b(o[1]) << 16);
    pk.y = (unsigned)f2b(o[2]) | ((unsigned)f2b(o[3]) << 16);
    *(uint2*)(xb + (size_t)n * HC + f0) = pk;
  }
#pragma unroll
  for (int s = 32; s > 0; s >>= 1) partial += __shfl_xor(partial, s);
  if (lane == 0) logitpart[n * 5 + slotbase + ch] = partial;
}

// sigmoid over the 5 per-node logit partials
__global__ void final_sigmoid_kernel(const float* __restrict__ logitpart,
                                     const float* __restrict__ bf,
                                     float* __restrict__ out) {
  int n = blockIdx.x * blockDim.x + threadIdx.x;
  if (n >= NN) return;
  const float* lp = logitpart + n * 5;
  float s = lp[0] + lp[1] + lp[2] + lp[3] + lp[4] + bf[0];
  out[n] = 1.f / (1.f + __expf(-s));
}

// ---------------------------------------------------------------------------

extern "C" void kernel_launch(void* const* d_in, const int* in_sizes, int n_in,
                              void* d_out, int out_size, void* d_ws, size_t ws_size,
                              hipStream_t stream) {
  const float* x     = (const float*)d_in[0];
  const int*   eidx  = (const int*)d_in[1];
  const float* eattr = (const float*)d_in[2];
  const float* W[3]   = {(const float*)d_in[3],  (const float*)d_in[9],  (const float*)d_in[15]};
  const float* ats[3] = {(const float*)d_in[4],  (const float*)d_in[10], (const float*)d_in[16]};
  const float* atd[3] = {(const float*)d_in[5],  (const float*)d_in[11], (const float*)d_in[17]};
  const float* We[3]  = {(const float*)d_in[6],  (const float*)d_in[12], (const float*)d_in[18]};
  const float* ate[3] = {(const float*)d_in[7],  (const float*)d_in[13], (const float*)d_in[19]};
  const float* bb[3]  = {(const float*)d_in[8],  (const float*)d_in[14], (const float*)d_in[20]};
  const float* Wf = (const float*)d_in[21];
  const float* bf = (const float*)d_in[22];
  float* out = (float*)d_out;

  const int* src = eidx;
  const int* dst = eidx + EE;

  char* p = (char*)d_ws;
  auto carve = [&](size_t bytes) -> char* {
    char* q = p;
    p += (bytes + 255) & ~(size_t)255;
    return q;
  };
  ushort* x1b    = (ushort*)carve((size_t)NN * 256 * 2);
  ushort* x2b    = (ushort*)carve((size_t)NN * 256 * 2);
  ushort* hbuf   = (ushort*)carve((size_t)NN * 768 * 2);
  ushort* abf1   = (ushort*)carve((size_t)NN * 32 * 2);
  ushort* wt1    = (ushort*)carve((size_t)256 * 32 * 2);
  ushort* wt2    = (ushort*)carve((size_t)256 * 256 * 2);
  ushort* wt3    = (ushort*)carve((size_t)768 * 256 * 2);
  ushort* ea_csr = (ushort*)carve((size_t)EF * EDIM * 2);
  ushort* wexp   = (ushort*)carve((size_t)EF * 12 * 2);
  float*  a_s    = (float*)carve((size_t)NN * 12 * 4);
  float*  a_d    = (float*)carve((size_t)NN * 12 * 4);
  float*  wec1   = (float*)carve((size_t)EDIM * 8 * 4);
  float*  wec2   = (float*)carve((size_t)EDIM * 8 * 4);
  float*  wec3   = (float*)carve((size_t)EDIM * 12 * 4);
  float*  lpart  = (float*)carve((size_t)NN * 5 * 4);
  int* cnt       = (int*)carve((size_t)NN * 4);
  int* off       = (int*)carve((size_t)(NN + 1) * 4);
  int* btot      = (int*)carve((size_t)NBLK * 4);
  int* cursor    = (int*)carve((size_t)NN * 4);
  int* csr_src   = (int*)carve((size_t)EF * 4);
  int* csr_dst   = (int*)carve((size_t)EF * 4);
  int* csr_eid   = (int*)carve((size_t)EF * 4);

  // ---- graph structure ----
  hipMemsetAsync(cnt, 0, (size_t)NN * 4, stream);
  count_deg_kernel<<<(EE + 255) / 256, 256, 0, stream>>>(dst, cnt);
  scan1_kernel<<<NBLK, 256, 0, stream>>>(cnt, off, btot);
  scan2_kernel<<<1, 128, 0, stream>>>(btot);
  scan3_kernel<<<NBLK, 256, 0, stream>>>(off, btot, cursor);
  scatter_kernel<<<(EF + 255) / 256, 256, 0, stream>>>(src, dst, cursor, csr_src, csr_dst,
                                                       csr_eid);
  ea_build_kernel<<<(NN * 64 + 255) / 256, 256, 0, stream>>>(off, csr_eid, eattr, ea_csr);

  // ---- dtype prep (single launch) ----
  {
    const int total = NN * 32 + 256 * 32 + 256 * 256 + 768 * 256 +
                      EDIM * 8 + EDIM * 8 + EDIM * 12;
    prep_weights_kernel<<<(total + 255) / 256, 256, 0, stream>>>(
        x, abf1, W[0], W[1], W[2], wt1, wt2, wt3,
        We[0], ate[0], wec1, We[1], ate[1], wec2, We[2], ate[2], wec3);
  }

  const ushort* Ain[3] = {abf1, x1b, x2b};
  const ushort* Wt[3] = {wt1, wt2, wt3};
  float* wecL[3] = {wec1, wec2, wec3};
  ushort* xoutb[3] = {x1b, x2b, nullptr};
  const float* WfL[3] = {Wf, Wf + 256, Wf + 512};
  const int slotb[3] = {0, 1, 2};

  for (int L = 0; L < 3; ++L) {
    const int H = (L < 2) ? 8 : 12;
    const int HC = (L < 2) ? 256 : 768;
    // h = A @ Wt^T + fused a_s/a_d epilogue
    if (L == 0) {
      dim3 g(HC / 64, (NN + 127) / 128);
      gemm_lds_kernel<32, 64, 32><<<g, 256, 0, stream>>>(Ain[L], Wt[L], hbuf, ats[L], atd[L],
                                                         a_s, a_d, NN, HC, H);
    } else if (L == 1) {
      dim3 g(HC / 64, (NN + 127) / 128);
      gemm_lds_kernel<256, 64, 32><<<g, 256, 0, stream>>>(Ain[L], Wt[L], hbuf, ats[L], atd[L],
                                                          a_s, a_d, NN, HC, H);
    } else {
      dim3 g(HC / 128, (NN + 127) / 128);  // BN=128: A re-read 6x (was 12x)
      gemm_lds_kernel<256, 128, 64><<<g, 256, 0, stream>>>(Ain[L], Wt[L], hbuf, ats[L], atd[L],
                                                           a_s, a_d, NN, HC, H);
    }
    // per-edge wexp (bf16)
    if (H == 8)
      ase_kernel<8><<<(EF + 255) / 256, 256, 0, stream>>>(csr_src, csr_dst, ea_csr,
                                                          wecL[L], a_s, a_d, wexp);
    else
      ase_kernel<12><<<(EF + 255) / 256, 256, 0, stream>>>(csr_src, csr_dst, ea_csr,
                                                           wecL[L], a_s, a_d, wexp);
    // single-pass gather + fused final-head partial (frozen)
    if (H == 8) {
      int blocks = (NN * 1 + 3) / 4;
      aggregate_kernel<8, 32, 1, true><<<blocks, 256, 0, stream>>>(
          wexp, hbuf, off, csr_src, bb[L], xoutb[L], WfL[L], lpart, slotb[L]);
    } else {
      int blocks = (NN * 3 + 3) / 4;
      aggregate_kernel<12, 64, 3, false><<<blocks, 256, 0, stream>>>(
          wexp, hbuf, off, csr_src, bb[L], xoutb[L], WfL[L], lpart, slotb[L]);
    }
  }

  final_sigmoid_kernel<<<(NN + 255) / 256, 256, 0, stream>>>(lpart, bf, out);
}